// Round 10
// baseline (294.032 us; speedup 1.0000x reference)
//
#include <hip/hip_runtime.h>

// VMamba mixer forward, MI355X. bf16-MFMA in_proj + x_proj; packed-fp32
// two-phase chunked selective scan (software-pipelined, uniform-offset hinted);
// f32x2 depthwise conv; bf16 x/y streams; transposed-Wo out GEMM.

constexpr int DM   = 96;     // D_MODEL
constexpr int DI   = 192;    // D_INNER
constexpr int RK   = 6;      // DT_RANK
constexpr int NS   = 32;     // D_STATE (== HEAD_D)
constexpr int KD   = 4;      // directions
constexpr int HW   = 56;
constexpr int LT   = 3136;   // L = 56*56
constexpr int NB   = 8;      // batch
constexpr int NPOS = NB * LT;   // 25088
constexpr int NC   = 64;     // chunks per sequence
constexpr int CH   = 49;     // chunk length (64*49 = 3136)
constexpr int SEQ = NB * KD; // 32 sequences
constexpr int ELEM = RK * NS * NS;  // 6144 state elements per sequence
constexpr int NO   = 280;    // x_proj outputs (4*70)
constexpr int NOP  = 288;    // padded to 18 MFMA n-tiles
constexpr int NI   = 384;    // in_proj outputs (2*DI)

typedef __attribute__((ext_vector_type(8))) __bf16 bf16x8;
typedef __attribute__((ext_vector_type(4))) float f32x4;
typedef __attribute__((ext_vector_type(2))) float f32x2;

__device__ __forceinline__ float siluf(float x) { return x / (1.f + __expf(-x)); }

__device__ __forceinline__ unsigned short f2bf(float f) {  // RNE, finite inputs
  unsigned int u = __float_as_uint(f);
  u = (u + 0x7fffu + ((u >> 16) & 1u)) >> 16;
  return (unsigned short)u;
}
__device__ __forceinline__ float bf2f(unsigned short h) {
  return __uint_as_float(((unsigned int)h) << 16);
}
__device__ __forceinline__ unsigned int pack2(float a, float b) {
  return (unsigned int)f2bf(a) | ((unsigned int)f2bf(b) << 16);
}

// sequence index l of direction k  ->  spatial position p (row-major h*56+w)
__device__ __forceinline__ int seq2pos(int k, int l) {
  int m = (k & 2) ? (LT - 1 - l) : l;
  return (k & 1) ? ((m % HW) * HW + m / HW) : m;
}

// Incremental position walker: uniform per-step update, no div/mod.
struct PosWalk {
  int p, cnt, wlim, winc, wstep, wadj, wrst;
  __device__ __forceinline__ void init(int k, int l0) {
    p = seq2pos(k, l0);
    if (k == 0)      { cnt = 0;  wlim = -9; winc = 0;  wstep = 1;   wadj = 0;     wrst = 0;  }
    else if (k == 1) { cnt = l0 % HW; wlim = HW - 1; winc = 1; wstep = HW; wadj = -(LT - HW - 1); wrst = 0; }
    else if (k == 2) { cnt = 0;  wlim = -9; winc = 0;  wstep = -1;  wadj = 0;     wrst = 0;  }
    else             { cnt = (LT - 1 - l0) % HW; wlim = 0; winc = -1; wstep = -HW; wadj = LT - HW - 1; wrst = HW - 1; }
  }
  __device__ __forceinline__ void next() {
    bool wrap = (cnt == wlim);
    p += wrap ? wadj : wstep;
    cnt = wrap ? wrst : cnt + winc;
  }
};

// ---------------- Kernel 0a: Wi -> bf16 ----------------
__global__ __launch_bounds__(256) void k_wiprep(const float* __restrict__ Wi,
                                                unsigned short* __restrict__ Wib) {
  int t = blockIdx.x * 256 + threadIdx.x;
  if (t >= NI * DM) return;
  Wib[t] = f2bf(Wi[t]);
}

// ---------------- Kernel 0b: Wp -> bf16, padded to 288 rows ----------------
__global__ __launch_bounds__(256) void k_wprep(const float* __restrict__ Wp,
                                               unsigned short* __restrict__ Wpb) {
  int t = blockIdx.x * 256 + threadIdx.x;
  if (t >= NOP * DI) return;
  int o = t / DI;
  Wpb[t] = (o < NO) ? f2bf(Wp[t]) : (unsigned short)0;
}

// ---------------- Kernel 0c: Wo -> transposed fp32 Wot[DI][DM] ----------------
__global__ __launch_bounds__(256) void k_woprep(const float* __restrict__ Wo,
                                                float* __restrict__ Wot) {
  int t = blockIdx.x * 256 + threadIdx.x;
  if (t >= DM * DI) return;
  int o = t / DI, j = t % DI;
  Wot[j * DM + o] = Wo[t];
}

// ---------------- Kernel 1: in_proj via bf16 MFMA + split + silu(z) ----------
__global__ __launch_bounds__(256) void k_inproj(const float* __restrict__ x,
                                                const unsigned short* __restrict__ Wib,
                                                float* __restrict__ xi,
                                                float* __restrict__ zs) {
  int wid = threadIdx.x >> 6;
  int lane = threadIdx.x & 63;
  int pos0 = blockIdx.x * 64 + wid * 16;
  int lrow = lane & 15;   // A: position-in-tile, B: output-in-tile
  int lgrp = lane >> 4;   // k-group (8 elements each)
  bf16x8 a[3];
  const float* arow = x + (size_t)(pos0 + lrow) * DM + lgrp * 8;
#pragma unroll
  for (int ks = 0; ks < 3; ks++) {
    f32x4 v0 = *reinterpret_cast<const f32x4*>(arow + ks * 32);
    f32x4 v1 = *reinterpret_cast<const f32x4*>(arow + ks * 32 + 4);
    union { unsigned short us[8]; bf16x8 v; } tmp;
#pragma unroll
    for (int j = 0; j < 4; j++) { tmp.us[j] = f2bf(v0[j]); tmp.us[4 + j] = f2bf(v1[j]); }
    a[ks] = tmp.v;
  }
  f32x4 acc[24];
#pragma unroll
  for (int t = 0; t < 24; t++) acc[t] = (f32x4){0.f, 0.f, 0.f, 0.f};
  const unsigned short* brow = Wib + (size_t)lrow * DM + lgrp * 8;
#pragma unroll
  for (int ks = 0; ks < 3; ks++) {
#pragma unroll
    for (int ot = 0; ot < 24; ot++) {
      bf16x8 bf = *reinterpret_cast<const bf16x8*>(brow + (size_t)ot * 16 * DM + ks * 32);
      acc[ot] = __builtin_amdgcn_mfma_f32_16x16x32_bf16(a[ks], bf, acc[ot], 0, 0, 0);
    }
  }
#pragma unroll
  for (int ot = 0; ot < 24; ot++) {
    int o = ot * 16 + lrow;
#pragma unroll
    for (int r = 0; r < 4; r++) {
      int pos = pos0 + lgrp * 4 + r;
      float v = acc[ot][r];
      if (o < DI) xi[(size_t)pos * DI + o] = v;
      else        zs[(size_t)pos * DI + (o - DI)] = siluf(v);
    }
  }
}

// ---------------- Kernel 2: depthwise 3x3 conv (2-channel f32x2) -> bf16 -------
__global__ __launch_bounds__(256) void k_conv(const float* __restrict__ xi,
                                              const float* __restrict__ cw,
                                              const float* __restrict__ cb,
                                              unsigned short* __restrict__ xcb) {
  const int DH = DI / 2;  // 96 channel pairs
  int t = blockIdx.x * 256 + threadIdx.x;
  if (t >= NPOS * DH) return;
  int c2 = t % DH;
  int pos = t / DH;
  int p = pos % LT, b = pos / LT;
  int h = p / HW, w = p % HW;
  f32x2 acc = *reinterpret_cast<const f32x2*>(cb + c2 * 2);
  int base = b * LT * DI + c2 * 2;
#pragma unroll
  for (int dh = 0; dh < 3; dh++) {
    int hh = h + dh - 1;
    if (hh < 0 || hh >= HW) continue;
#pragma unroll
    for (int dw = 0; dw < 3; dw++) {
      int ww = w + dw - 1;
      if (ww < 0 || ww >= HW) continue;
      f32x2 wv = *reinterpret_cast<const f32x2*>(cw + (dh * 3 + dw) * DI + c2 * 2);
      f32x2 xv = *reinterpret_cast<const f32x2*>(xi + base + (hh * HW + ww) * DI);
      acc += wv * xv;
    }
  }
  reinterpret_cast<unsigned int*>(xcb)[t] = pack2(siluf(acc[0]), siluf(acc[1]));
}

// ---------------- Kernel 3: x_proj via bf16 MFMA + softplus/exp ----------------
__global__ __launch_bounds__(128) void k_xproj(const unsigned short* __restrict__ xcb,
                                               const unsigned short* __restrict__ Wpb,
                                               const float* __restrict__ A_logs,
                                               const float* __restrict__ dt_bias,
                                               float* __restrict__ dtb,
                                               float* __restrict__ dAb,
                                               float* __restrict__ Bsb,
                                               float* __restrict__ Csb) {
  int wid = threadIdx.x >> 6;
  int lane = threadIdx.x & 63;
  int pos0 = blockIdx.x * 32 + wid * 16;
  int lrow = lane & 15;   // A: position-in-tile, B: output-in-tile
  int lgrp = lane >> 4;   // k-group (8 bf16 each)
  bf16x8 a[6];
  const unsigned short* arow = xcb + (size_t)(pos0 + lrow) * DI + lgrp * 8;
#pragma unroll
  for (int ks = 0; ks < 6; ks++)
    a[ks] = *reinterpret_cast<const bf16x8*>(arow + ks * 32);
  f32x4 acc[18];
#pragma unroll
  for (int t = 0; t < 18; t++) acc[t] = (f32x4){0.f, 0.f, 0.f, 0.f};
  const unsigned short* brow = Wpb + (size_t)lrow * DI + lgrp * 8;
#pragma unroll
  for (int ks = 0; ks < 6; ks++) {
#pragma unroll
    for (int ot = 0; ot < 18; ot++) {
      bf16x8 bf = *reinterpret_cast<const bf16x8*>(brow + (size_t)ot * 16 * DI + ks * 32);
      acc[ot] = __builtin_amdgcn_mfma_f32_16x16x32_bf16(a[ks], bf, acc[ot], 0, 0, 0);
    }
  }
#pragma unroll
  for (int ot = 0; ot < 18; ot++) {
    int o = ot * 16 + lrow;
    if (o >= NO) continue;
    int k = o / 70, c = o % 70;
#pragma unroll
    for (int r = 0; r < 4; r++) {
      int pos = pos0 + lgrp * 4 + r;
      float v = acc[ot][r];
      int base = pos * KD + k;
      if (c < RK) {
        float bias = dt_bias[k * RK + c];
        float Av = -__expf(A_logs[k * RK + c]);
        float s = v + bias;
        float dtv = (s > 20.f) ? s : log1pf(__expf(s));
        dtb[base * RK + c] = dtv;
        dAb[base * RK + c] = __expf(dtv * Av);
      } else if (c < RK + NS) {
        Bsb[base * NS + (c - RK)] = v;
      } else {
        Csb[base * NS + (c - RK - NS)] = v;
      }
    }
  }
}

// ---------------- Kernel 4: states-only local scan (pipelined) ----------------
__global__ __launch_bounds__(192) void k_scanA(const unsigned short* __restrict__ xcb,
                                               const float* __restrict__ dtb,
                                               const float* __restrict__ dAb,
                                               const float* __restrict__ Bsb,
                                               unsigned short* __restrict__ Send,
                                               float* __restrict__ Pend) {
  int bi = blockIdx.x;
  int chunk = bi % NC;
  int k = (bi / NC) & 3;
  int b = bi / (NC * KD);
  int seq = b * KD + k;
  int tid = threadIdx.x;
  int r = tid >> 5, d = tid & 31;
  f32x2 S2[16];
#pragma unroll
  for (int i = 0; i < 16; i++) S2[i] = (f32x2){0.f, 0.f};
  float cum = 1.f;
  PosWalk pw; pw.init(k, chunk * CH);
  const unsigned short* xp = xcb + b * LT * DI + tid;
  int cb0 = b * LT * KD + k;
  // prologue: step-0 scalars
  int ubase = __builtin_amdgcn_readfirstlane(cb0 + pw.p * KD);
  float dA_c = dAb[ubase * RK + r];
  float dt_c = dtb[ubase * RK + r];
  float xv_c = bf2f(xp[pw.p * DI]);
#pragma unroll 2
  for (int l = 0; l < CH; l++) {
    pw.next();
    // prefetch next-step scalars (tail over-prefetch is harmless: stays in d_ws)
    int ubase_n = __builtin_amdgcn_readfirstlane(cb0 + pw.p * KD);
    float dA_n = dAb[ubase_n * RK + r];
    float dt_n = dtb[ubase_n * RK + r];
    float xv_n = bf2f(xp[pw.p * DI]);
    const f32x4* Bp = reinterpret_cast<const f32x4*>(Bsb + ubase * NS);
    float xdt = xv_c * dt_c;
    f32x2 dA2 = {dA_c, dA_c}, xd2 = {xdt, xdt};
#pragma unroll
    for (int i = 0; i < 8; i++) {
      f32x4 bv = Bp[i];
      f32x2 bl = __builtin_shufflevector(bv, bv, 0, 1);
      f32x2 bh = __builtin_shufflevector(bv, bv, 2, 3);
      S2[2 * i]     = S2[2 * i] * dA2 + xd2 * bl;
      S2[2 * i + 1] = S2[2 * i + 1] * dA2 + xd2 * bh;
    }
    cum *= dA_c;
    ubase = ubase_n; dA_c = dA_n; dt_c = dt_n; xv_c = xv_n;
  }
  unsigned int* dst = (unsigned int*)(Send + (size_t)(seq * NC + chunk) * ELEM + tid * NS);
#pragma unroll
  for (int i = 0; i < 16; i++) dst[i] = pack2(S2[i][0], S2[i][1]);
  if (d == 0) Pend[(seq * NC + chunk) * RK + r] = cum;
}

// ---------------- Kernel 5: chunk-state combine (bf16 in-place excl. prefix) ----
__global__ __launch_bounds__(256) void k_scanB(unsigned int* __restrict__ Send32,
                                               const float* __restrict__ Pend) {
  const int EU = ELEM / 2;           // 3072 uints per (seq,chunk)
  int bi = blockIdx.x;               // 32 seqs * 12 uint-tiles
  int seq = bi / (EU / 256);
  int u = (bi % (EU / 256)) * 256 + threadIdx.x;
  int r = u >> 9;                    // element e = 2u, r = e>>10
  float run0 = 0.f, run1 = 0.f;
  for (int c = 0; c < NC; c++) {
    size_t idx = (size_t)(seq * NC + c) * EU + u;
    unsigned int v = Send32[idx];
    float t0 = bf2f((unsigned short)(v & 0xffff));
    float t1 = bf2f((unsigned short)(v >> 16));
    Send32[idx] = pack2(run0, run1);
    float pe = Pend[(seq * NC + c) * RK + r];
    run0 = run0 * pe + t0;
    run1 = run1 * pe + t1;
  }
}

// ---------------- Kernel 6: full scan recompute (pipelined), bf16 y out --------
__global__ __launch_bounds__(192) void k_scanD(const unsigned short* __restrict__ xcb,
                                               const float* __restrict__ dtb,
                                               const float* __restrict__ dAb,
                                               const float* __restrict__ Bsb,
                                               const float* __restrict__ Csb,
                                               const float* __restrict__ Ds,
                                               const unsigned short* __restrict__ Sinit,
                                               unsigned short* __restrict__ ybh) {
  int bi = blockIdx.x;
  int chunk = bi % NC;
  int k = (bi / NC) & 3;
  int b = bi / (NC * KD);
  int seq = b * KD + k;
  int tid = threadIdx.x;
  int r = tid >> 5, d = tid & 31;
  f32x2 S2[16];
  const unsigned int* sp = (const unsigned int*)(Sinit + (size_t)(seq * NC + chunk) * ELEM + tid * NS);
#pragma unroll
  for (int i = 0; i < 16; i++) {
    unsigned int v = sp[i];
    S2[i] = (f32x2){bf2f((unsigned short)(v & 0xffff)), bf2f((unsigned short)(v >> 16))};
  }
  float Dsv = Ds[(k * RK + r) * NS + d];
  PosWalk pw; pw.init(k, chunk * CH);
  const unsigned short* xp = xcb + b * LT * DI + tid;
  unsigned short* yb = ybh + seq * LT * DI + tid;
  int cb0 = b * LT * KD + k;
  int p_c = pw.p;
  int ubase = __builtin_amdgcn_readfirstlane(cb0 + p_c * KD);
  float dA_c = dAb[ubase * RK + r];
  float dt_c = dtb[ubase * RK + r];
  float xv_c = bf2f(xp[p_c * DI]);
#pragma unroll 2
  for (int l = 0; l < CH; l++) {
    pw.next();
    int p_n = pw.p;
    int ubase_n = __builtin_amdgcn_readfirstlane(cb0 + p_n * KD);
    float dA_n = dAb[ubase_n * RK + r];
    float dt_n = dtb[ubase_n * RK + r];
    float xv_n = bf2f(xp[p_n * DI]);
    const f32x4* Bp = reinterpret_cast<const f32x4*>(Bsb + ubase * NS);
    const f32x4* Cp = reinterpret_cast<const f32x4*>(Csb + ubase * NS);
    float xdt = xv_c * dt_c;
    f32x2 dA2 = {dA_c, dA_c}, xd2 = {xdt, xdt};
    f32x2 y2 = {0.f, 0.f};
#pragma unroll
    for (int i = 0; i < 8; i++) {
      f32x4 bv = Bp[i];
      f32x4 cv = Cp[i];
      f32x2 bl = __builtin_shufflevector(bv, bv, 0, 1);
      f32x2 bh = __builtin_shufflevector(bv, bv, 2, 3);
      f32x2 cl = __builtin_shufflevector(cv, cv, 0, 1);
      f32x2 ch = __builtin_shufflevector(cv, cv, 2, 3);
      S2[2 * i]     = S2[2 * i] * dA2 + xd2 * bl;
      y2 += S2[2 * i] * cl;
      S2[2 * i + 1] = S2[2 * i + 1] * dA2 + xd2 * bh;
      y2 += S2[2 * i + 1] * ch;
    }
    yb[p_c * DI] = f2bf(y2[0] + y2[1] + xv_c * Dsv);
    p_c = p_n; ubase = ubase_n; dA_c = dA_n; dt_c = dt_n; xv_c = xv_n;
  }
}

// ---------------- Kernel 7: merge + LN + gelu + *silu(z) + out_proj ----------------
__global__ __launch_bounds__(192) void k_out(const unsigned short* __restrict__ ybh,
                                             const float* __restrict__ zs,
                                             const float* __restrict__ ln_g,
                                             const float* __restrict__ ln_b,
                                             const float* __restrict__ Wot,
                                             float* __restrict__ out) {
  const int PP = 4;
  int pos0 = blockIdx.x * PP;
  int b = pos0 / LT, p0 = pos0 % LT;
  int tid = threadIdx.x;  // 0..191 = channel
  float v[PP], s1[PP], s2[PP];
#pragma unroll
  for (int q = 0; q < PP; q++) {
    float acc = 0.f;
#pragma unroll
    for (int k = 0; k < KD; k++)
      acc += bf2f(ybh[((size_t)(b * KD + k) * LT + p0 + q) * DI + tid]);
    v[q] = acc; s1[q] = acc; s2[q] = acc * acc;
  }
#pragma unroll
  for (int off = 32; off; off >>= 1) {
#pragma unroll
    for (int q = 0; q < PP; q++) {
      s1[q] += __shfl_down(s1[q], off, 64);
      s2[q] += __shfl_down(s2[q], off, 64);
    }
  }
  __shared__ float rs1[3][PP], rs2[3][PP];
  int wave = tid >> 6, lane = tid & 63;
  if (lane == 0) {
#pragma unroll
    for (int q = 0; q < PP; q++) { rs1[wave][q] = s1[q]; rs2[wave][q] = s2[q]; }
  }
  __syncthreads();
  __shared__ float su[PP][DI];
  float g = ln_g[tid], be = ln_b[tid];
#pragma unroll
  for (int q = 0; q < PP; q++) {
    float mean = (rs1[0][q] + rs1[1][q] + rs1[2][q]) * (1.f / 192.f);
    float var = (rs2[0][q] + rs2[1][q] + rs2[2][q]) * (1.f / 192.f) - mean * mean;
    float rstd = rsqrtf(var + 1e-5f);
    float t = (v[q] - mean) * rstd * g + be;
    float ge = 0.5f * t * (1.f + erff(t * 0.70710678118f));
    su[q][tid] = ge * zs[(pos0 + q) * DI + tid];
  }
  __syncthreads();
  int o = tid % DM, half = tid / DM;  // 2 threads per output column
  const float* wcol = Wot + (size_t)half * DM * DM + o;
  float acc[PP];
#pragma unroll
  for (int q = 0; q < PP; q++) acc[q] = 0.f;
  for (int j = 0; j < DM; j++) {
    float w = wcol[(size_t)j * DM];   // lane-coalesced
#pragma unroll
    for (int q = 0; q < PP; q++) acc[q] += w * su[q][half * DM + j];
  }
  __shared__ float part[PP][DI];
#pragma unroll
  for (int q = 0; q < PP; q++) part[q][tid] = acc[q];
  __syncthreads();
  if (tid < DM) {
#pragma unroll
    for (int q = 0; q < PP; q++)
      out[(pos0 + q) * DM + tid] = part[q][tid] + part[q][tid + DM];
  }
}

extern "C" void kernel_launch(void* const* d_in, const int* in_sizes, int n_in,
                              void* d_out, int out_size, void* d_ws, size_t ws_size,
                              hipStream_t stream) {
  const float* x       = (const float*)d_in[0];
  const float* Wi      = (const float*)d_in[1];
  const float* cw      = (const float*)d_in[2];
  const float* cb      = (const float*)d_in[3];
  const float* Wp      = (const float*)d_in[4];
  const float* Ds      = (const float*)d_in[5];
  const float* A_logs  = (const float*)d_in[6];
  const float* dt_bias = (const float*)d_in[7];
  const float* ln_g    = (const float*)d_in[8];
  const float* ln_b    = (const float*)d_in[9];
  const float* Wo      = (const float*)d_in[10];
  float* out = (float*)d_out;

  float* ws = (float*)d_ws;
  float* xi    = ws;                       // NPOS*DI f32
  float* zs    = xi + (size_t)NPOS * DI;   // NPOS*DI f32
  float* dtb   = zs + (size_t)NPOS * DI;   // NPOS*KD*RK f32
  float* dAb   = dtb + (size_t)NPOS * KD * RK;
  float* Bsb   = dAb + (size_t)NPOS * KD * RK;   // NPOS*KD*NS f32
  float* Csb   = Bsb + (size_t)NPOS * KD * NS;
  unsigned short* xcb  = (unsigned short*)(Csb + (size_t)NPOS * KD * NS); // NPOS*DI bf16
  unsigned short* ybh  = xcb + (size_t)NPOS * DI;                          // NPOS*KD*DI bf16
  unsigned short* Send = ybh + (size_t)NPOS * KD * DI;                     // SEQ*NC*ELEM bf16
  float* Pend  = (float*)(Send + (size_t)SEQ * NC * ELEM);  // SEQ*NC*RK f32
  float* WpbF  = Pend + (size_t)SEQ * NC * RK;
  float* WibF  = WpbF + (size_t)NOP * DI / 2;
  float* Wot   = WibF + (size_t)NI * DM / 2;                // DI*DM f32
  unsigned short* Wpb = (unsigned short*)WpbF;
  unsigned short* Wib = (unsigned short*)WibF;

  k_wiprep<<<(NI * DM + 255) / 256, 256, 0, stream>>>(Wi, Wib);
  k_wprep<<<(NOP * DI + 255) / 256, 256, 0, stream>>>(Wp, Wpb);
  k_woprep<<<(DM * DI + 255) / 256, 256, 0, stream>>>(Wo, Wot);
  k_inproj<<<NPOS / 64, 256, 0, stream>>>(x, Wib, xi, zs);
  k_conv<<<(NPOS * (DI / 2) + 255) / 256, 256, 0, stream>>>(xi, cw, cb, xcb);
  k_xproj<<<NPOS / 32, 128, 0, stream>>>(xcb, Wpb, A_logs, dt_bias, dtb, dAb, Bsb, Csb);
  k_scanA<<<NB * KD * NC, 192, 0, stream>>>(xcb, dtb, dAb, Bsb, Send, Pend);
  k_scanB<<<SEQ * (ELEM / 512), 256, 0, stream>>>((unsigned int*)Send, Pend);
  k_scanD<<<NB * KD * NC, 192, 0, stream>>>(xcb, dtb, dAb, Bsb, Csb, Ds, Send, ybh);
  k_out<<<NPOS / 4, 192, 0, stream>>>(ybh, zs, ln_g, ln_b, Wot, out);
}

// Round 11
// 248.709 us; speedup vs baseline: 1.1822x; 1.1822x over previous
//
#include <hip/hip_runtime.h>

// VMamba mixer forward, MI355X. bf16-MFMA in_proj + x_proj; packed-fp32
// two-phase chunked selective scan reading DIRECTION-ORDERED streams
// (no pointer-chase); f32x2 conv (+transposed copy); transposed-Wo out GEMM.

constexpr int DM   = 96;     // D_MODEL
constexpr int DI   = 192;    // D_INNER
constexpr int RK   = 6;      // DT_RANK
constexpr int NS   = 32;     // D_STATE (== HEAD_D)
constexpr int KD   = 4;      // directions
constexpr int HW   = 56;
constexpr int LT   = 3136;   // L = 56*56
constexpr int NB   = 8;      // batch
constexpr int NPOS = NB * LT;   // 25088
constexpr int NC   = 64;     // chunks per sequence
constexpr int CH   = 49;     // chunk length (64*49 = 3136)
constexpr int SEQ = NB * KD; // 32 sequences
constexpr int ELEM = RK * NS * NS;  // 6144 state elements per sequence
constexpr int NO   = 280;    // x_proj outputs (4*70)
constexpr int NOP  = 288;    // padded to 18 MFMA n-tiles
constexpr int NI   = 384;    // in_proj outputs (2*DI)

typedef __attribute__((ext_vector_type(8))) __bf16 bf16x8;
typedef __attribute__((ext_vector_type(4))) float f32x4;
typedef __attribute__((ext_vector_type(2))) float f32x2;

__device__ __forceinline__ float siluf(float x) { return x / (1.f + __expf(-x)); }

__device__ __forceinline__ unsigned short f2bf(float f) {  // RNE, finite inputs
  unsigned int u = __float_as_uint(f);
  u = (u + 0x7fffu + ((u >> 16) & 1u)) >> 16;
  return (unsigned short)u;
}
__device__ __forceinline__ float bf2f(unsigned short h) {
  return __uint_as_float(((unsigned int)h) << 16);
}
__device__ __forceinline__ unsigned int pack2(float a, float b) {
  return (unsigned int)f2bf(a) | ((unsigned int)f2bf(b) << 16);
}

// sequence index l of direction k  ->  spatial position p (row-major h*56+w)
__device__ __forceinline__ int seq2pos(int k, int l) {
  int m = (k & 2) ? (LT - 1 - l) : l;
  return (k & 1) ? ((m % HW) * HW + m / HW) : m;
}

// Incremental position walker (store-address only in scanD).
struct PosWalk {
  int p, cnt, wlim, winc, wstep, wadj, wrst;
  __device__ __forceinline__ void init(int k, int l0) {
    p = seq2pos(k, l0);
    if (k == 0)      { cnt = 0;  wlim = -9; winc = 0;  wstep = 1;   wadj = 0;     wrst = 0;  }
    else if (k == 1) { cnt = l0 % HW; wlim = HW - 1; winc = 1; wstep = HW; wadj = -(LT - HW - 1); wrst = 0; }
    else if (k == 2) { cnt = 0;  wlim = -9; winc = 0;  wstep = -1;  wadj = 0;     wrst = 0;  }
    else             { cnt = (LT - 1 - l0) % HW; wlim = 0; winc = -1; wstep = -HW; wadj = LT - HW - 1; wrst = HW - 1; }
  }
  __device__ __forceinline__ void next() {
    bool wrap = (cnt == wlim);
    p += wrap ? wadj : wstep;
    cnt = wrap ? wrst : cnt + winc;
  }
};

// ---------------- Kernel 0a: Wi -> bf16 ----------------
__global__ __launch_bounds__(256) void k_wiprep(const float* __restrict__ Wi,
                                                unsigned short* __restrict__ Wib) {
  int t = blockIdx.x * 256 + threadIdx.x;
  if (t >= NI * DM) return;
  Wib[t] = f2bf(Wi[t]);
}

// ---------------- Kernel 0b: Wp -> bf16, padded to 288 rows ----------------
__global__ __launch_bounds__(256) void k_wprep(const float* __restrict__ Wp,
                                               unsigned short* __restrict__ Wpb) {
  int t = blockIdx.x * 256 + threadIdx.x;
  if (t >= NOP * DI) return;
  int o = t / DI;
  Wpb[t] = (o < NO) ? f2bf(Wp[t]) : (unsigned short)0;
}

// ---------------- Kernel 0c: Wo -> transposed fp32 Wot[DI][DM] ----------------
__global__ __launch_bounds__(256) void k_woprep(const float* __restrict__ Wo,
                                                float* __restrict__ Wot) {
  int t = blockIdx.x * 256 + threadIdx.x;
  if (t >= DM * DI) return;
  int o = t / DI, j = t % DI;
  Wot[j * DM + o] = Wo[t];
}

// ---------------- Kernel 1: in_proj via bf16 MFMA + split + silu(z) ----------
__global__ __launch_bounds__(256) void k_inproj(const float* __restrict__ x,
                                                const unsigned short* __restrict__ Wib,
                                                float* __restrict__ xi,
                                                float* __restrict__ zs) {
  int wid = threadIdx.x >> 6;
  int lane = threadIdx.x & 63;
  int pos0 = blockIdx.x * 64 + wid * 16;
  int lrow = lane & 15;   // A: position-in-tile, B: output-in-tile
  int lgrp = lane >> 4;   // k-group (8 elements each)
  bf16x8 a[3];
  const float* arow = x + (size_t)(pos0 + lrow) * DM + lgrp * 8;
#pragma unroll
  for (int ks = 0; ks < 3; ks++) {
    f32x4 v0 = *reinterpret_cast<const f32x4*>(arow + ks * 32);
    f32x4 v1 = *reinterpret_cast<const f32x4*>(arow + ks * 32 + 4);
    union { unsigned short us[8]; bf16x8 v; } tmp;
#pragma unroll
    for (int j = 0; j < 4; j++) { tmp.us[j] = f2bf(v0[j]); tmp.us[4 + j] = f2bf(v1[j]); }
    a[ks] = tmp.v;
  }
  f32x4 acc[24];
#pragma unroll
  for (int t = 0; t < 24; t++) acc[t] = (f32x4){0.f, 0.f, 0.f, 0.f};
  const unsigned short* brow = Wib + (size_t)lrow * DM + lgrp * 8;
#pragma unroll
  for (int ks = 0; ks < 3; ks++) {
#pragma unroll
    for (int ot = 0; ot < 24; ot++) {
      bf16x8 bf = *reinterpret_cast<const bf16x8*>(brow + (size_t)ot * 16 * DM + ks * 32);
      acc[ot] = __builtin_amdgcn_mfma_f32_16x16x32_bf16(a[ks], bf, acc[ot], 0, 0, 0);
    }
  }
#pragma unroll
  for (int ot = 0; ot < 24; ot++) {
    int o = ot * 16 + lrow;
#pragma unroll
    for (int r = 0; r < 4; r++) {
      int pos = pos0 + lgrp * 4 + r;
      float v = acc[ot][r];
      if (o < DI) xi[(size_t)pos * DI + o] = v;
      else        zs[(size_t)pos * DI + (o - DI)] = siluf(v);
    }
  }
}

// ---------------- Kernel 2: depthwise conv -> bf16 (row-major + transposed) ----
__global__ __launch_bounds__(256) void k_conv(const float* __restrict__ xi,
                                              const float* __restrict__ cw,
                                              const float* __restrict__ cb,
                                              unsigned short* __restrict__ xcb,
                                              unsigned short* __restrict__ xcbT) {
  const int DH = DI / 2;  // 96 channel pairs
  int t = blockIdx.x * 256 + threadIdx.x;
  if (t >= NPOS * DH) return;
  int c2 = t % DH;
  int pos = t / DH;
  int p = pos % LT, b = pos / LT;
  int h = p / HW, w = p % HW;
  f32x2 acc = *reinterpret_cast<const f32x2*>(cb + c2 * 2);
  int base = b * LT * DI + c2 * 2;
#pragma unroll
  for (int dh = 0; dh < 3; dh++) {
    int hh = h + dh - 1;
    if (hh < 0 || hh >= HW) continue;
#pragma unroll
    for (int dw = 0; dw < 3; dw++) {
      int ww = w + dw - 1;
      if (ww < 0 || ww >= HW) continue;
      f32x2 wv = *reinterpret_cast<const f32x2*>(cw + (dh * 3 + dw) * DI + c2 * 2);
      f32x2 xv = *reinterpret_cast<const f32x2*>(xi + base + (hh * HW + ww) * DI);
      acc += wv * xv;
    }
  }
  unsigned int v = pack2(siluf(acc[0]), siluf(acc[1]));
  reinterpret_cast<unsigned int*>(xcb)[t] = v;
  int pt = w * HW + h;
  reinterpret_cast<unsigned int*>(xcbT)[(b * LT + pt) * DH + c2] = v;
}

// ---------------- Kernel 3: x_proj via bf16 MFMA -> direction-ordered streams --
__global__ __launch_bounds__(128) void k_xproj(const unsigned short* __restrict__ xcb,
                                               const unsigned short* __restrict__ Wpb,
                                               const float* __restrict__ A_logs,
                                               const float* __restrict__ dt_bias,
                                               float* __restrict__ dtS,
                                               float* __restrict__ dAS,
                                               float* __restrict__ BsS,
                                               float* __restrict__ CsS) {
  int wid = threadIdx.x >> 6;
  int lane = threadIdx.x & 63;
  int pos0 = blockIdx.x * 32 + wid * 16;
  int lrow = lane & 15;   // A: position-in-tile, B: output-in-tile
  int lgrp = lane >> 4;   // k-group (8 bf16 each)
  bf16x8 a[6];
  const unsigned short* arow = xcb + (size_t)(pos0 + lrow) * DI + lgrp * 8;
#pragma unroll
  for (int ks = 0; ks < 6; ks++)
    a[ks] = *reinterpret_cast<const bf16x8*>(arow + ks * 32);
  f32x4 acc[18];
#pragma unroll
  for (int t = 0; t < 18; t++) acc[t] = (f32x4){0.f, 0.f, 0.f, 0.f};
  const unsigned short* brow = Wpb + (size_t)lrow * DI + lgrp * 8;
#pragma unroll
  for (int ks = 0; ks < 6; ks++) {
#pragma unroll
    for (int ot = 0; ot < 18; ot++) {
      bf16x8 bf = *reinterpret_cast<const bf16x8*>(brow + (size_t)ot * 16 * DI + ks * 32);
      acc[ot] = __builtin_amdgcn_mfma_f32_16x16x32_bf16(a[ks], bf, acc[ot], 0, 0, 0);
    }
  }
  // hoist per-r position/stream indices
  int sp[4], spt[4], bb[4];
#pragma unroll
  for (int r = 0; r < 4; r++) {
    int pos = pos0 + lgrp * 4 + r;
    int b = pos / LT, p = pos - b * LT;
    int h = p / HW, w = p - h * HW;
    bb[r] = b; sp[r] = p; spt[r] = w * HW + h;
  }
#pragma unroll
  for (int ot = 0; ot < 18; ot++) {
    int o = ot * 16 + lrow;
    if (o >= NO) continue;
    int k = o / 70, c = o % 70;
#pragma unroll
    for (int r = 0; r < 4; r++) {
      float v = acc[ot][r];
      int sidx = (k * NB + bb[r]) * LT + ((k & 1) ? spt[r] : sp[r]);
      if (c < RK) {
        float bias = dt_bias[k * RK + c];
        float Av = -__expf(A_logs[k * RK + c]);
        float s = v + bias;
        float dtv = (s > 20.f) ? s : log1pf(__expf(s));
        dtS[(size_t)sidx * RK + c] = dtv;
        dAS[(size_t)sidx * RK + c] = __expf(dtv * Av);
      } else if (c < RK + NS) {
        BsS[(size_t)sidx * NS + (c - RK)] = v;
      } else {
        CsS[(size_t)sidx * NS + (c - RK - NS)] = v;
      }
    }
  }
}

// ---------------- Kernel 4: states-only local scan (streaming reads) ----------
__global__ __launch_bounds__(192) void k_scanA(const unsigned short* __restrict__ xcb,
                                               const unsigned short* __restrict__ xcbT,
                                               const float* __restrict__ dtS,
                                               const float* __restrict__ dAS,
                                               const float* __restrict__ BsS,
                                               unsigned short* __restrict__ Send,
                                               float* __restrict__ Pend) {
  int bi = blockIdx.x;
  int chunk = bi % NC;
  int k = (bi / NC) & 3;
  int b = bi / (NC * KD);
  int seq = b * KD + k;
  int tid = threadIdx.x;
  int r = tid >> 5, d = tid & 31;
  f32x2 S2[16];
#pragma unroll
  for (int i = 0; i < 16; i++) S2[i] = (f32x2){0.f, 0.f};
  float cum = 1.f;
  int sb0 = (k * NB + b) * LT;                       // stream base
  const unsigned short* xs = ((k & 1) ? xcbT : xcb) + (size_t)b * LT * DI + tid;
  int j  = (k < 2) ? chunk * CH : (LT - 1 - chunk * CH);
  int dj = (k < 2) ? 1 : -1;
  for (int l = 0; l < CH; l++) {
    int sidx = sb0 + j;
    const f32x4* Bp = reinterpret_cast<const f32x4*>(BsS + (size_t)sidx * NS);
    float dAr = dAS[(size_t)sidx * RK + r];
    float dtr = dtS[(size_t)sidx * RK + r];
    float xv = bf2f(xs[(size_t)j * DI]);
    float xdt = xv * dtr;
    f32x2 dA2 = {dAr, dAr}, xd2 = {xdt, xdt};
#pragma unroll
    for (int i = 0; i < 8; i++) {
      f32x4 bv = Bp[i];
      f32x2 bl = __builtin_shufflevector(bv, bv, 0, 1);
      f32x2 bh = __builtin_shufflevector(bv, bv, 2, 3);
      S2[2 * i]     = S2[2 * i] * dA2 + xd2 * bl;
      S2[2 * i + 1] = S2[2 * i + 1] * dA2 + xd2 * bh;
    }
    cum *= dAr;
    j += dj;
  }
  unsigned int* dst = (unsigned int*)(Send + (size_t)(seq * NC + chunk) * ELEM + tid * NS);
#pragma unroll
  for (int i = 0; i < 16; i++) dst[i] = pack2(S2[i][0], S2[i][1]);
  if (d == 0) Pend[(seq * NC + chunk) * RK + r] = cum;
}

// ---------------- Kernel 5: chunk-state combine (bf16 in-place excl. prefix) ----
__global__ __launch_bounds__(256) void k_scanB(unsigned int* __restrict__ Send32,
                                               const float* __restrict__ Pend) {
  const int EU = ELEM / 2;           // 3072 uints per (seq,chunk)
  int bi = blockIdx.x;               // 32 seqs * 12 uint-tiles
  int seq = bi / (EU / 256);
  int u = (bi % (EU / 256)) * 256 + threadIdx.x;
  int r = u >> 9;                    // element e = 2u, r = e>>10
  float run0 = 0.f, run1 = 0.f;
  for (int c = 0; c < NC; c++) {
    size_t idx = (size_t)(seq * NC + c) * EU + u;
    unsigned int v = Send32[idx];
    float t0 = bf2f((unsigned short)(v & 0xffff));
    float t1 = bf2f((unsigned short)(v >> 16));
    Send32[idx] = pack2(run0, run1);
    float pe = Pend[(seq * NC + c) * RK + r];
    run0 = run0 * pe + t0;
    run1 = run1 * pe + t1;
  }
}

// ---------------- Kernel 6: full scan recompute (streaming reads), bf16 y ------
__global__ __launch_bounds__(192) void k_scanD(const unsigned short* __restrict__ xcb,
                                               const unsigned short* __restrict__ xcbT,
                                               const float* __restrict__ dtS,
                                               const float* __restrict__ dAS,
                                               const float* __restrict__ BsS,
                                               const float* __restrict__ CsS,
                                               const float* __restrict__ Ds,
                                               const unsigned short* __restrict__ Sinit,
                                               unsigned short* __restrict__ ybh) {
  int bi = blockIdx.x;
  int chunk = bi % NC;
  int k = (bi / NC) & 3;
  int b = bi / (NC * KD);
  int seq = b * KD + k;
  int tid = threadIdx.x;
  int r = tid >> 5, d = tid & 31;
  f32x2 S2[16];
  const unsigned int* sp = (const unsigned int*)(Sinit + (size_t)(seq * NC + chunk) * ELEM + tid * NS);
#pragma unroll
  for (int i = 0; i < 16; i++) {
    unsigned int v = sp[i];
    S2[i] = (f32x2){bf2f((unsigned short)(v & 0xffff)), bf2f((unsigned short)(v >> 16))};
  }
  float Dsv = Ds[(k * RK + r) * NS + d];
  int sb0 = (k * NB + b) * LT;
  const unsigned short* xs = ((k & 1) ? xcbT : xcb) + (size_t)b * LT * DI + tid;
  unsigned short* yb = ybh + (size_t)seq * LT * DI + tid;
  int j  = (k < 2) ? chunk * CH : (LT - 1 - chunk * CH);
  int dj = (k < 2) ? 1 : -1;
  PosWalk pw; pw.init(k, chunk * CH);   // store address only
  for (int l = 0; l < CH; l++) {
    int sidx = sb0 + j;
    const f32x4* Bp = reinterpret_cast<const f32x4*>(BsS + (size_t)sidx * NS);
    const f32x4* Cp = reinterpret_cast<const f32x4*>(CsS + (size_t)sidx * NS);
    float dAr = dAS[(size_t)sidx * RK + r];
    float dtr = dtS[(size_t)sidx * RK + r];
    float xv = bf2f(xs[(size_t)j * DI]);
    float xdt = xv * dtr;
    f32x2 dA2 = {dAr, dAr}, xd2 = {xdt, xdt};
    f32x2 y2 = {0.f, 0.f};
#pragma unroll
    for (int i = 0; i < 8; i++) {
      f32x4 bv = Bp[i];
      f32x4 cv = Cp[i];
      f32x2 bl = __builtin_shufflevector(bv, bv, 0, 1);
      f32x2 bh = __builtin_shufflevector(bv, bv, 2, 3);
      f32x2 cl = __builtin_shufflevector(cv, cv, 0, 1);
      f32x2 ch = __builtin_shufflevector(cv, cv, 2, 3);
      S2[2 * i]     = S2[2 * i] * dA2 + xd2 * bl;
      y2 += S2[2 * i] * cl;
      S2[2 * i + 1] = S2[2 * i + 1] * dA2 + xd2 * bh;
      y2 += S2[2 * i + 1] * ch;
    }
    yb[(size_t)pw.p * DI] = f2bf(y2[0] + y2[1] + xv * Dsv);
    pw.next();
    j += dj;
  }
}

// ---------------- Kernel 7: merge + LN + gelu + *silu(z) + out_proj ----------------
__global__ __launch_bounds__(192) void k_out(const unsigned short* __restrict__ ybh,
                                             const float* __restrict__ zs,
                                             const float* __restrict__ ln_g,
                                             const float* __restrict__ ln_b,
                                             const float* __restrict__ Wot,
                                             float* __restrict__ out) {
  const int PP = 4;
  int pos0 = blockIdx.x * PP;
  int b = pos0 / LT, p0 = pos0 % LT;
  int tid = threadIdx.x;  // 0..191 = channel
  float v[PP], s1[PP], s2[PP];
#pragma unroll
  for (int q = 0; q < PP; q++) {
    float acc = 0.f;
#pragma unroll
    for (int k = 0; k < KD; k++)
      acc += bf2f(ybh[((size_t)(b * KD + k) * LT + p0 + q) * DI + tid]);
    v[q] = acc; s1[q] = acc; s2[q] = acc * acc;
  }
#pragma unroll
  for (int off = 32; off; off >>= 1) {
#pragma unroll
    for (int q = 0; q < PP; q++) {
      s1[q] += __shfl_down(s1[q], off, 64);
      s2[q] += __shfl_down(s2[q], off, 64);
    }
  }
  __shared__ float rs1[3][PP], rs2[3][PP];
  int wave = tid >> 6, lane = tid & 63;
  if (lane == 0) {
#pragma unroll
    for (int q = 0; q < PP; q++) { rs1[wave][q] = s1[q]; rs2[wave][q] = s2[q]; }
  }
  __syncthreads();
  __shared__ float su[PP][DI];
  float g = ln_g[tid], be = ln_b[tid];
#pragma unroll
  for (int q = 0; q < PP; q++) {
    float mean = (rs1[0][q] + rs1[1][q] + rs1[2][q]) * (1.f / 192.f);
    float var = (rs2[0][q] + rs2[1][q] + rs2[2][q]) * (1.f / 192.f) - mean * mean;
    float rstd = rsqrtf(var + 1e-5f);
    float t = (v[q] - mean) * rstd * g + be;
    float ge = 0.5f * t * (1.f + erff(t * 0.70710678118f));
    su[q][tid] = ge * zs[(pos0 + q) * DI + tid];
  }
  __syncthreads();
  int o = tid % DM, half = tid / DM;  // 2 threads per output column
  const float* wcol = Wot + (size_t)half * DM * DM + o;
  float acc[PP];
#pragma unroll
  for (int q = 0; q < PP; q++) acc[q] = 0.f;
  for (int j = 0; j < DM; j++) {
    float w = wcol[(size_t)j * DM];   // lane-coalesced
#pragma unroll
    for (int q = 0; q < PP; q++) acc[q] += w * su[q][half * DM + j];
  }
  __shared__ float part[PP][DI];
#pragma unroll
  for (int q = 0; q < PP; q++) part[q][tid] = acc[q];
  __syncthreads();
  if (tid < DM) {
#pragma unroll
    for (int q = 0; q < PP; q++)
      out[(pos0 + q) * DM + tid] = part[q][tid] + part[q][tid + DM];
  }
}

extern "C" void kernel_launch(void* const* d_in, const int* in_sizes, int n_in,
                              void* d_out, int out_size, void* d_ws, size_t ws_size,
                              hipStream_t stream) {
  const float* x       = (const float*)d_in[0];
  const float* Wi      = (const float*)d_in[1];
  const float* cw      = (const float*)d_in[2];
  const float* cb      = (const float*)d_in[3];
  const float* Wp      = (const float*)d_in[4];
  const float* Ds      = (const float*)d_in[5];
  const float* A_logs  = (const float*)d_in[6];
  const float* dt_bias = (const float*)d_in[7];
  const float* ln_g    = (const float*)d_in[8];
  const float* ln_b    = (const float*)d_in[9];
  const float* Wo      = (const float*)d_in[10];
  float* out = (float*)d_out;

  float* ws = (float*)d_ws;
  float* xi    = ws;                       // NPOS*DI f32
  float* zs    = xi + (size_t)NPOS * DI;   // NPOS*DI f32
  float* dtS   = zs + (size_t)NPOS * DI;   // KD*NB*LT*RK f32 (direction-ordered)
  float* dAS   = dtS + (size_t)NPOS * KD * RK;
  float* BsS   = dAS + (size_t)NPOS * KD * RK;   // KD*NB*LT*NS f32
  float* CsS   = BsS + (size_t)NPOS * KD * NS;
  unsigned short* xcb  = (unsigned short*)(CsS + (size_t)NPOS * KD * NS); // NPOS*DI bf16
  unsigned short* xcbT = xcb + (size_t)NPOS * DI;                          // NPOS*DI bf16
  unsigned short* ybh  = xcbT + (size_t)NPOS * DI;                         // NPOS*KD*DI bf16
  unsigned short* Send = ybh + (size_t)NPOS * KD * DI;                     // SEQ*NC*ELEM bf16
  float* Pend  = (float*)(Send + (size_t)SEQ * NC * ELEM);  // SEQ*NC*RK f32
  float* WpbF  = Pend + (size_t)SEQ * NC * RK;
  float* WibF  = WpbF + (size_t)NOP * DI / 2;
  float* Wot   = WibF + (size_t)NI * DM / 2;                // DI*DM f32
  unsigned short* Wpb = (unsigned short*)WpbF;
  unsigned short* Wib = (unsigned short*)WibF;

  k_wiprep<<<(NI * DM + 255) / 256, 256, 0, stream>>>(Wi, Wib);
  k_wprep<<<(NOP * DI + 255) / 256, 256, 0, stream>>>(Wp, Wpb);
  k_woprep<<<(DM * DI + 255) / 256, 256, 0, stream>>>(Wo, Wot);
  k_inproj<<<NPOS / 64, 256, 0, stream>>>(x, Wib, xi, zs);
  k_conv<<<(NPOS * (DI / 2) + 255) / 256, 256, 0, stream>>>(xi, cw, cb, xcb, xcbT);
  k_xproj<<<NPOS / 32, 128, 0, stream>>>(xcb, Wpb, A_logs, dt_bias, dtS, dAS, BsS, CsS);
  k_scanA<<<NB * KD * NC, 192, 0, stream>>>(xcb, xcbT, dtS, dAS, BsS, Send, Pend);
  k_scanB<<<SEQ * (ELEM / 512), 256, 0, stream>>>((unsigned int*)Send, Pend);
  k_scanD<<<NB * KD * NC, 192, 0, stream>>>(xcb, xcbT, dtS, dAS, BsS, CsS, Ds, Send, ybh);
  k_out<<<NPOS / 4, 192, 0, stream>>>(ybh, zs, ln_g, ln_b, Wot, out);
}

// Round 12
// 228.220 us; speedup vs baseline: 1.2884x; 1.0898x over previous
//
#include <hip/hip_runtime.h>

// VMamba mixer forward, MI355X. bf16-MFMA in_proj + x_proj; MFMA chunk-scan
// (Mamba2 SSD form) for the y-pass; scalar states pass + bf16 prefix combine;
// direction-ordered streams; transposed-Wo out GEMM.

constexpr int DM   = 96;     // D_MODEL
constexpr int DI   = 192;    // D_INNER
constexpr int RK   = 6;      // DT_RANK
constexpr int NS   = 32;     // D_STATE (== HEAD_D)
constexpr int KD   = 4;      // directions
constexpr int HW   = 56;
constexpr int LT   = 3136;   // L = 56*56
constexpr int NB   = 8;      // batch
constexpr int NPOS = NB * LT;   // 25088
constexpr int NC   = 49;     // chunks per sequence
constexpr int CH   = 64;     // chunk length (49*64 = 3136)
constexpr int SEQ = NB * KD; // 32 sequences
constexpr int ELEM = RK * NS * NS;  // 6144 state elements per sequence
constexpr int NO   = 280;    // x_proj outputs (4*70)
constexpr int NOP  = 288;    // padded to 18 MFMA n-tiles
constexpr int NI   = 384;    // in_proj outputs (2*DI)

typedef __attribute__((ext_vector_type(8))) __bf16 bf16x8;
typedef __attribute__((ext_vector_type(4))) float f32x4;
typedef __attribute__((ext_vector_type(2))) float f32x2;

__device__ __forceinline__ float siluf(float x) { return x / (1.f + __expf(-x)); }

__device__ __forceinline__ unsigned short f2bf(float f) {  // RNE, finite inputs
  unsigned int u = __float_as_uint(f);
  u = (u + 0x7fffu + ((u >> 16) & 1u)) >> 16;
  return (unsigned short)u;
}
__device__ __forceinline__ float bf2f(unsigned short h) {
  return __uint_as_float(((unsigned int)h) << 16);
}
__device__ __forceinline__ unsigned int pack2(float a, float b) {
  return (unsigned int)f2bf(a) | ((unsigned int)f2bf(b) << 16);
}

// sequence index l of direction k  ->  spatial position p (row-major h*56+w)
__device__ __forceinline__ int seq2pos(int k, int l) {
  int m = (k & 2) ? (LT - 1 - l) : l;
  return (k & 1) ? ((m % HW) * HW + m / HW) : m;
}

// ---------------- Kernel 0a: Wi -> bf16 ----------------
__global__ __launch_bounds__(256) void k_wiprep(const float* __restrict__ Wi,
                                                unsigned short* __restrict__ Wib) {
  int t = blockIdx.x * 256 + threadIdx.x;
  if (t >= NI * DM) return;
  Wib[t] = f2bf(Wi[t]);
}

// ---------------- Kernel 0b: Wp -> bf16, padded to 288 rows ----------------
__global__ __launch_bounds__(256) void k_wprep(const float* __restrict__ Wp,
                                               unsigned short* __restrict__ Wpb) {
  int t = blockIdx.x * 256 + threadIdx.x;
  if (t >= NOP * DI) return;
  int o = t / DI;
  Wpb[t] = (o < NO) ? f2bf(Wp[t]) : (unsigned short)0;
}

// ---------------- Kernel 0c: Wo -> transposed fp32 Wot[DI][DM] ----------------
__global__ __launch_bounds__(256) void k_woprep(const float* __restrict__ Wo,
                                                float* __restrict__ Wot) {
  int t = blockIdx.x * 256 + threadIdx.x;
  if (t >= DM * DI) return;
  int o = t / DI, j = t % DI;
  Wot[j * DM + o] = Wo[t];
}

// ---------------- Kernel 1: in_proj via bf16 MFMA + split + silu(z) ----------
__global__ __launch_bounds__(256) void k_inproj(const float* __restrict__ x,
                                                const unsigned short* __restrict__ Wib,
                                                float* __restrict__ xi,
                                                float* __restrict__ zs) {
  int wid = threadIdx.x >> 6;
  int lane = threadIdx.x & 63;
  int pos0 = blockIdx.x * 64 + wid * 16;
  int lrow = lane & 15;
  int lgrp = lane >> 4;
  bf16x8 a[3];
  const float* arow = x + (size_t)(pos0 + lrow) * DM + lgrp * 8;
#pragma unroll
  for (int ks = 0; ks < 3; ks++) {
    f32x4 v0 = *reinterpret_cast<const f32x4*>(arow + ks * 32);
    f32x4 v1 = *reinterpret_cast<const f32x4*>(arow + ks * 32 + 4);
    union { unsigned short us[8]; bf16x8 v; } tmp;
#pragma unroll
    for (int j = 0; j < 4; j++) { tmp.us[j] = f2bf(v0[j]); tmp.us[4 + j] = f2bf(v1[j]); }
    a[ks] = tmp.v;
  }
  f32x4 acc[24];
#pragma unroll
  for (int t = 0; t < 24; t++) acc[t] = (f32x4){0.f, 0.f, 0.f, 0.f};
  const unsigned short* brow = Wib + (size_t)lrow * DM + lgrp * 8;
#pragma unroll
  for (int ks = 0; ks < 3; ks++) {
#pragma unroll
    for (int ot = 0; ot < 24; ot++) {
      bf16x8 bf = *reinterpret_cast<const bf16x8*>(brow + (size_t)ot * 16 * DM + ks * 32);
      acc[ot] = __builtin_amdgcn_mfma_f32_16x16x32_bf16(a[ks], bf, acc[ot], 0, 0, 0);
    }
  }
#pragma unroll
  for (int ot = 0; ot < 24; ot++) {
    int o = ot * 16 + lrow;
#pragma unroll
    for (int r = 0; r < 4; r++) {
      int pos = pos0 + lgrp * 4 + r;
      float v = acc[ot][r];
      if (o < DI) xi[(size_t)pos * DI + o] = v;
      else        zs[(size_t)pos * DI + (o - DI)] = siluf(v);
    }
  }
}

// ---------------- Kernel 2: depthwise conv -> bf16 (row-major + transposed) ----
__global__ __launch_bounds__(256) void k_conv(const float* __restrict__ xi,
                                              const float* __restrict__ cw,
                                              const float* __restrict__ cb,
                                              unsigned short* __restrict__ xcb,
                                              unsigned short* __restrict__ xcbT) {
  const int DH = DI / 2;
  int t = blockIdx.x * 256 + threadIdx.x;
  if (t >= NPOS * DH) return;
  int c2 = t % DH;
  int pos = t / DH;
  int p = pos % LT, b = pos / LT;
  int h = p / HW, w = p % HW;
  f32x2 acc = *reinterpret_cast<const f32x2*>(cb + c2 * 2);
  int base = b * LT * DI + c2 * 2;
#pragma unroll
  for (int dh = 0; dh < 3; dh++) {
    int hh = h + dh - 1;
    if (hh < 0 || hh >= HW) continue;
#pragma unroll
    for (int dw = 0; dw < 3; dw++) {
      int ww = w + dw - 1;
      if (ww < 0 || ww >= HW) continue;
      f32x2 wv = *reinterpret_cast<const f32x2*>(cw + (dh * 3 + dw) * DI + c2 * 2);
      f32x2 xv = *reinterpret_cast<const f32x2*>(xi + base + (hh * HW + ww) * DI);
      acc += wv * xv;
    }
  }
  unsigned int v = pack2(siluf(acc[0]), siluf(acc[1]));
  reinterpret_cast<unsigned int*>(xcb)[t] = v;
  int pt = w * HW + h;
  reinterpret_cast<unsigned int*>(xcbT)[(b * LT + pt) * DH + c2] = v;
}

// ---------------- Kernel 3: x_proj via bf16 MFMA -> direction-ordered streams --
__global__ __launch_bounds__(128) void k_xproj(const unsigned short* __restrict__ xcb,
                                               const unsigned short* __restrict__ Wpb,
                                               const float* __restrict__ A_logs,
                                               const float* __restrict__ dt_bias,
                                               float* __restrict__ dtS,
                                               float* __restrict__ dAS,
                                               float* __restrict__ BsS,
                                               unsigned short* __restrict__ BsH,
                                               unsigned short* __restrict__ CsH) {
  int wid = threadIdx.x >> 6;
  int lane = threadIdx.x & 63;
  int pos0 = blockIdx.x * 32 + wid * 16;
  int lrow = lane & 15;
  int lgrp = lane >> 4;
  bf16x8 a[6];
  const unsigned short* arow = xcb + (size_t)(pos0 + lrow) * DI + lgrp * 8;
#pragma unroll
  for (int ks = 0; ks < 6; ks++)
    a[ks] = *reinterpret_cast<const bf16x8*>(arow + ks * 32);
  f32x4 acc[18];
#pragma unroll
  for (int t = 0; t < 18; t++) acc[t] = (f32x4){0.f, 0.f, 0.f, 0.f};
  const unsigned short* brow = Wpb + (size_t)lrow * DI + lgrp * 8;
#pragma unroll
  for (int ks = 0; ks < 6; ks++) {
#pragma unroll
    for (int ot = 0; ot < 18; ot++) {
      bf16x8 bf = *reinterpret_cast<const bf16x8*>(brow + (size_t)ot * 16 * DI + ks * 32);
      acc[ot] = __builtin_amdgcn_mfma_f32_16x16x32_bf16(a[ks], bf, acc[ot], 0, 0, 0);
    }
  }
  int sp[4], spt[4], bb[4];
#pragma unroll
  for (int r = 0; r < 4; r++) {
    int pos = pos0 + lgrp * 4 + r;
    int b = pos / LT, p = pos - b * LT;
    int h = p / HW, w = p - h * HW;
    bb[r] = b; sp[r] = p; spt[r] = w * HW + h;
  }
#pragma unroll
  for (int ot = 0; ot < 18; ot++) {
    int o = ot * 16 + lrow;
    if (o >= NO) continue;
    int k = o / 70, c = o % 70;
#pragma unroll
    for (int r = 0; r < 4; r++) {
      float v = acc[ot][r];
      int sidx = (k * NB + bb[r]) * LT + ((k & 1) ? spt[r] : sp[r]);
      if (c < RK) {
        float bias = dt_bias[k * RK + c];
        float Av = -__expf(A_logs[k * RK + c]);
        float s = v + bias;
        float dtv = (s > 20.f) ? s : log1pf(__expf(s));
        dtS[(size_t)sidx * RK + c] = dtv;
        dAS[(size_t)sidx * RK + c] = __expf(dtv * Av);
      } else if (c < RK + NS) {
        BsS[(size_t)sidx * NS + (c - RK)] = v;
        BsH[(size_t)sidx * NS + (c - RK)] = f2bf(v);
      } else {
        CsH[(size_t)sidx * NS + (c - RK - NS)] = f2bf(v);
      }
    }
  }
}

// ---------------- Kernel 4: states-only local scan (scalar, streaming) --------
__global__ __launch_bounds__(192) void k_scanA(const unsigned short* __restrict__ xcb,
                                               const unsigned short* __restrict__ xcbT,
                                               const float* __restrict__ dtS,
                                               const float* __restrict__ dAS,
                                               const float* __restrict__ BsS,
                                               unsigned short* __restrict__ Send,
                                               float* __restrict__ Pend) {
  int bi = blockIdx.x;
  int chunk = bi % NC;
  int k = (bi / NC) & 3;
  int b = bi / (NC * KD);
  int seq = b * KD + k;
  int tid = threadIdx.x;
  int r = tid >> 5, d = tid & 31;
  f32x2 S2[16];
#pragma unroll
  for (int i = 0; i < 16; i++) S2[i] = (f32x2){0.f, 0.f};
  float cum = 1.f;
  int sb0 = (k * NB + b) * LT;
  const unsigned short* xs = ((k & 1) ? xcbT : xcb) + (size_t)b * LT * DI + tid;
  int j  = (k < 2) ? chunk * CH : (LT - 1 - chunk * CH);
  int dj = (k < 2) ? 1 : -1;
  for (int l = 0; l < CH; l++) {
    int sidx = sb0 + j;
    const f32x4* Bp = reinterpret_cast<const f32x4*>(BsS + (size_t)sidx * NS);
    float dAr = dAS[(size_t)sidx * RK + r];
    float dtr = dtS[(size_t)sidx * RK + r];
    float xv = bf2f(xs[(size_t)j * DI]);
    float xdt = xv * dtr;
    f32x2 dA2 = {dAr, dAr}, xd2 = {xdt, xdt};
#pragma unroll
    for (int i = 0; i < 8; i++) {
      f32x4 bv = Bp[i];
      f32x2 bl = __builtin_shufflevector(bv, bv, 0, 1);
      f32x2 bh = __builtin_shufflevector(bv, bv, 2, 3);
      S2[2 * i]     = S2[2 * i] * dA2 + xd2 * bl;
      S2[2 * i + 1] = S2[2 * i + 1] * dA2 + xd2 * bh;
    }
    cum *= dAr;
    j += dj;
  }
  unsigned int* dst = (unsigned int*)(Send + (size_t)(seq * NC + chunk) * ELEM + tid * NS);
#pragma unroll
  for (int i = 0; i < 16; i++) dst[i] = pack2(S2[i][0], S2[i][1]);
  if (d == 0) Pend[(seq * NC + chunk) * RK + r] = cum;
}

// ---------------- Kernel 5: chunk-state combine (bf16 in-place excl. prefix) ----
__global__ __launch_bounds__(256) void k_scanB(unsigned int* __restrict__ Send32,
                                               const float* __restrict__ Pend) {
  const int EU = ELEM / 2;
  int bi = blockIdx.x;
  int seq = bi / (EU / 256);
  int u = (bi % (EU / 256)) * 256 + threadIdx.x;
  int r = u >> 9;
  float run0 = 0.f, run1 = 0.f;
  for (int c = 0; c < NC; c++) {
    size_t idx = (size_t)(seq * NC + c) * EU + u;
    unsigned int v = Send32[idx];
    float t0 = bf2f((unsigned short)(v & 0xffff));
    float t1 = bf2f((unsigned short)(v >> 16));
    Send32[idx] = pack2(run0, run1);
    float pe = Pend[(seq * NC + c) * RK + r];
    run0 = run0 * pe + t0;
    run1 = run1 * pe + t1;
  }
}

// ---------------- Kernel 6: MFMA chunk scan (Y = G'X + e^Λ C·Sinit + D·x) -----
// Block = 384 thr = 6 waves (wave = r). Grid = SEQ*NC.
__global__ __launch_bounds__(384) void k_scanM(const unsigned short* __restrict__ xcb,
                                               const unsigned short* __restrict__ xcbT,
                                               const float* __restrict__ dtS,
                                               const unsigned short* __restrict__ BsH,
                                               const unsigned short* __restrict__ CsH,
                                               const float* __restrict__ A_logs,
                                               const float* __restrict__ Ds,
                                               const unsigned short* __restrict__ Sinit,
                                               unsigned short* __restrict__ ybh) {
  __shared__ unsigned short XT[DI][72];      // x chunk, channel-transposed [c][s]
  __shared__ unsigned short GB[6][32][72];   // per-wave G half [t_local][s]
  int bi = blockIdx.x;
  int chunk = bi % NC;
  int k = (bi / NC) & 3;
  int b = bi / (NC * KD);
  int tid = threadIdx.x;
  int wid = tid >> 6;                        // r
  int lane = tid & 63;
  int lrow = lane & 15, lgrp = lane >> 4;
  int sb0 = (k * NB + b) * LT;
  int j0 = (k < 2) ? chunk * CH : (LT - 1 - chunk * CH);
  int dj = (k < 2) ? 1 : -1;
  // Phase 0: cooperative XT build (64 s-rows x 96 uints)
  const unsigned int* xs32 = reinterpret_cast<const unsigned int*>(
      ((k & 1) ? xcbT : xcb) + (size_t)b * LT * DI);
#pragma unroll
  for (int it = 0; it < 16; ++it) {
    int idx = it * 384 + tid;
    int s = idx / 96, cu = idx - s * 96;
    unsigned int v = xs32[(size_t)(j0 + s * dj) * 96 + cu];
    XT[2 * cu][s] = (unsigned short)(v & 0xffff);
    XT[2 * cu + 1][s] = (unsigned short)(v >> 16);
  }
  __syncthreads();
  int r = wid;
  // Phase 0b: log-decay prefix scan over the 64 steps (lane = step)
  float Ar = -__expf(A_logs[k * RK + r]);
  float dt_l = dtS[(size_t)(sb0 + j0 + lane * dj) * RK + r];
  float Lam = dt_l * Ar;
#pragma unroll
  for (int off = 1; off < 64; off <<= 1) {
    float tv = __shfl_up(Lam, off, 64);
    Lam += (lane >= off) ? tv : 0.f;
  }
  // Phase 1: C/B fragments (A-operand convention: lane&15 = row, lgrp*8 = k)
  bf16x8 ct[4], bt[4];
#pragma unroll
  for (int i = 0; i < 4; i++) {
    int row = j0 + (i * 16 + lrow) * dj;
    ct[i] = *reinterpret_cast<const bf16x8*>(CsH + (size_t)(sb0 + row) * NS + lgrp * 8);
    bt[i] = *reinterpret_cast<const bf16x8*>(BsH + (size_t)(sb0 + row) * NS + lgrp * 8);
  }
  // Yinit = C . Sinit  (B-op rows = d, k = n)
  const unsigned short* sbase = Sinit + (size_t)((b * KD + k) * NC + chunk) * ELEM + r * NS * NS;
  bf16x8 sf[2];
#pragma unroll
  for (int djt = 0; djt < 2; djt++)
    sf[djt] = *reinterpret_cast<const bf16x8*>(sbase + (djt * 16 + lrow) * NS + lgrp * 8);
  f32x4 yi[4][2];
#pragma unroll
  for (int i = 0; i < 4; i++)
#pragma unroll
    for (int djt = 0; djt < 2; djt++)
      yi[i][djt] = __builtin_amdgcn_mfma_f32_16x16x32_bf16(ct[i], sf[djt],
                       (f32x4){0.f, 0.f, 0.f, 0.f}, 0, 0, 0);
  // Precompute Λ/dt lookups
  float dt_s4[4], Lam_s4[4];
#pragma unroll
  for (int j = 0; j < 4; j++) {
    dt_s4[j] = __shfl(dt_l, j * 16 + lrow, 64);
    Lam_s4[j] = __shfl(Lam, j * 16 + lrow, 64);
  }
  float Lam_t[4][4];
#pragma unroll
  for (int i = 0; i < 4; i++)
#pragma unroll
    for (int q = 0; q < 4; q++)
      Lam_t[i][q] = __shfl(Lam, i * 16 + lgrp * 4 + q, 64);
  // Phase 2/3: G tiles -> masked/decayed -> GB; Y MFMAs, two t-halves
  f32x4 y[4][2];
#pragma unroll
  for (int i = 0; i < 4; i++)
#pragma unroll
    for (int djt = 0; djt < 2; djt++) y[i][djt] = (f32x4){0.f, 0.f, 0.f, 0.f};
#pragma unroll
  for (int h = 0; h < 2; h++) {
    int i0 = h * 2;
    int ncol = h ? 4 : 2;
#pragma unroll
    for (int it = 0; it < 2; it++) {
      int i = i0 + it;
#pragma unroll
      for (int j = 0; j < 4; j++) {
        if (j >= ncol) continue;
        f32x4 g = __builtin_amdgcn_mfma_f32_16x16x32_bf16(ct[i], bt[j],
                      (f32x4){0.f, 0.f, 0.f, 0.f}, 0, 0, 0);
        int s = j * 16 + lrow;
#pragma unroll
        for (int q = 0; q < 4; q++) {
          int t = i * 16 + lgrp * 4 + q;
          float w = (t >= s) ? __expf(Lam_t[i][q] - Lam_s4[j]) * dt_s4[j] : 0.f;
          GB[wid][it * 16 + lgrp * 4 + q][s] = f2bf(g[q] * w);
        }
      }
    }
    int nks = h ? 2 : 1;
#pragma unroll
    for (int it = 0; it < 2; it++) {
#pragma unroll
      for (int ks = 0; ks < nks; ks++) {
        bf16x8 ga = *reinterpret_cast<const bf16x8*>(&GB[wid][it * 16 + lrow][ks * 32 + lgrp * 8]);
#pragma unroll
        for (int djt = 0; djt < 2; djt++) {
          bf16x8 xb = *reinterpret_cast<const bf16x8*>(&XT[r * 32 + djt * 16 + lrow][ks * 32 + lgrp * 8]);
          y[i0 + it][djt] = __builtin_amdgcn_mfma_f32_16x16x32_bf16(ga, xb, y[i0 + it][djt], 0, 0, 0);
        }
      }
    }
  }
  // Phase 4: finalize + store (stream-ordered ybh [k][b][j][c])
  float Dv[2];
#pragma unroll
  for (int djt = 0; djt < 2; djt++)
    Dv[djt] = Ds[(k * RK + r) * NS + djt * 16 + lrow];
  unsigned short* yb = ybh + (size_t)(k * NB + b) * LT * DI;
#pragma unroll
  for (int i = 0; i < 4; i++) {
#pragma unroll
    for (int q = 0; q < 4; q++) {
      int t = i * 16 + lgrp * 4 + q;
      float eL = __expf(Lam_t[i][q]);
      int jrow = j0 + t * dj;
#pragma unroll
      for (int djt = 0; djt < 2; djt++) {
        float xv = bf2f(XT[r * 32 + djt * 16 + lrow][t]);
        float val = y[i][djt][q] + eL * yi[i][djt][q] + Dv[djt] * xv;
        yb[(size_t)jrow * DI + r * 32 + djt * 16 + lrow] = f2bf(val);
      }
    }
  }
}

// ---------------- Kernel 7: merge + LN + gelu + *silu(z) + out_proj ----------------
// ybh is stream-ordered: dir 0/2 at raster index p, dir 1/3 at transposed index pt.
__global__ __launch_bounds__(192) void k_out(const unsigned short* __restrict__ ybh,
                                             const float* __restrict__ zs,
                                             const float* __restrict__ ln_g,
                                             const float* __restrict__ ln_b,
                                             const float* __restrict__ Wot,
                                             float* __restrict__ out) {
  const int PP = 4;
  int pos0 = blockIdx.x * PP;
  int b = pos0 / LT, p0 = pos0 % LT;
  int h0 = p0 / HW, w0 = p0 % HW;
  int pt0 = w0 * HW + h0;
  int tid = threadIdx.x;
  float v[PP], s1[PP], s2[PP];
#pragma unroll
  for (int q = 0; q < PP; q++) {
    int p = p0 + q;
    int pt = pt0 + q * HW;
    float acc = bf2f(ybh[((size_t)(0 * NB + b) * LT + p) * DI + tid])
              + bf2f(ybh[((size_t)(1 * NB + b) * LT + pt) * DI + tid])
              + bf2f(ybh[((size_t)(2 * NB + b) * LT + p) * DI + tid])
              + bf2f(ybh[((size_t)(3 * NB + b) * LT + pt) * DI + tid]);
    v[q] = acc; s1[q] = acc; s2[q] = acc * acc;
  }
#pragma unroll
  for (int off = 32; off; off >>= 1) {
#pragma unroll
    for (int q = 0; q < PP; q++) {
      s1[q] += __shfl_down(s1[q], off, 64);
      s2[q] += __shfl_down(s2[q], off, 64);
    }
  }
  __shared__ float rs1[3][PP], rs2[3][PP];
  int wave = tid >> 6, lane = tid & 63;
  if (lane == 0) {
#pragma unroll
    for (int q = 0; q < PP; q++) { rs1[wave][q] = s1[q]; rs2[wave][q] = s2[q]; }
  }
  __syncthreads();
  __shared__ float su[PP][DI];
  float g = ln_g[tid], be = ln_b[tid];
#pragma unroll
  for (int q = 0; q < PP; q++) {
    float mean = (rs1[0][q] + rs1[1][q] + rs1[2][q]) * (1.f / 192.f);
    float var = (rs2[0][q] + rs2[1][q] + rs2[2][q]) * (1.f / 192.f) - mean * mean;
    float rstd = rsqrtf(var + 1e-5f);
    float t = (v[q] - mean) * rstd * g + be;
    float ge = 0.5f * t * (1.f + erff(t * 0.70710678118f));
    su[q][tid] = ge * zs[(pos0 + q) * DI + tid];
  }
  __syncthreads();
  int o = tid % DM, half = tid / DM;
  const float* wcol = Wot + (size_t)half * DM * DM + o;
  float acc[PP];
#pragma unroll
  for (int q = 0; q < PP; q++) acc[q] = 0.f;
  for (int j = 0; j < DM; j++) {
    float w = wcol[(size_t)j * DM];
#pragma unroll
    for (int q = 0; q < PP; q++) acc[q] += w * su[q][half * DM + j];
  }
  __shared__ float part[PP][DI];
#pragma unroll
  for (int q = 0; q < PP; q++) part[q][tid] = acc[q];
  __syncthreads();
  if (tid < DM) {
#pragma unroll
    for (int q = 0; q < PP; q++)
      out[(pos0 + q) * DM + tid] = part[q][tid] + part[q][tid + DM];
  }
}

extern "C" void kernel_launch(void* const* d_in, const int* in_sizes, int n_in,
                              void* d_out, int out_size, void* d_ws, size_t ws_size,
                              hipStream_t stream) {
  const float* x       = (const float*)d_in[0];
  const float* Wi      = (const float*)d_in[1];
  const float* cw      = (const float*)d_in[2];
  const float* cb      = (const float*)d_in[3];
  const float* Wp      = (const float*)d_in[4];
  const float* Ds      = (const float*)d_in[5];
  const float* A_logs  = (const float*)d_in[6];
  const float* dt_bias = (const float*)d_in[7];
  const float* ln_g    = (const float*)d_in[8];
  const float* ln_b    = (const float*)d_in[9];
  const float* Wo      = (const float*)d_in[10];
  float* out = (float*)d_out;

  float* ws = (float*)d_ws;
  float* xi    = ws;                       // NPOS*DI f32
  float* zs    = xi + (size_t)NPOS * DI;   // NPOS*DI f32
  float* dtS   = zs + (size_t)NPOS * DI;   // KD*NB*LT*RK f32 (direction-ordered)
  float* dAS   = dtS + (size_t)NPOS * KD * RK;
  float* BsS   = dAS + (size_t)NPOS * KD * RK;   // KD*NB*LT*NS f32
  unsigned short* BsH  = (unsigned short*)(BsS + (size_t)NPOS * KD * NS);  // bf16
  unsigned short* CsH  = BsH + (size_t)NPOS * KD * NS;                     // bf16
  unsigned short* xcb  = CsH + (size_t)NPOS * KD * NS;                     // NPOS*DI bf16
  unsigned short* xcbT = xcb + (size_t)NPOS * DI;
  unsigned short* ybh  = xcbT + (size_t)NPOS * DI;                         // KD*NPOS*DI bf16
  unsigned short* Send = ybh + (size_t)NPOS * KD * DI;                     // SEQ*NC*ELEM bf16
  float* Pend  = (float*)(Send + (size_t)SEQ * NC * ELEM);  // SEQ*NC*RK f32
  float* WpbF  = Pend + (size_t)SEQ * NC * RK;
  float* WibF  = WpbF + (size_t)NOP * DI / 2;
  float* Wot   = WibF + (size_t)NI * DM / 2;                // DI*DM f32
  unsigned short* Wpb = (unsigned short*)WpbF;
  unsigned short* Wib = (unsigned short*)WibF;

  k_wiprep<<<(NI * DM + 255) / 256, 256, 0, stream>>>(Wi, Wib);
  k_wprep<<<(NOP * DI + 255) / 256, 256, 0, stream>>>(Wp, Wpb);
  k_woprep<<<(DM * DI + 255) / 256, 256, 0, stream>>>(Wo, Wot);
  k_inproj<<<NPOS / 64, 256, 0, stream>>>(x, Wib, xi, zs);
  k_conv<<<(NPOS * (DI / 2) + 255) / 256, 256, 0, stream>>>(xi, cw, cb, xcb, xcbT);
  k_xproj<<<NPOS / 32, 128, 0, stream>>>(xcb, Wpb, A_logs, dt_bias, dtS, dAS, BsS, BsH, CsH);
  k_scanA<<<SEQ * NC, 192, 0, stream>>>(xcb, xcbT, dtS, dAS, BsS, Send, Pend);
  k_scanB<<<SEQ * (ELEM / 512), 256, 0, stream>>>((unsigned int*)Send, Pend);
  k_scanM<<<SEQ * NC, 384, 0, stream>>>(xcb, xcbT, dtS, BsH, CsH, A_logs, Ds, Send, ybh);
  k_out<<<NPOS / 4, 192, 0, stream>>>(ybh, zs, ln_g, ln_b, Wot, out);
}

// Round 13
// 209.268 us; speedup vs baseline: 1.4050x; 1.0906x over previous
//
#include <hip/hip_runtime.h>

// VMamba mixer forward, MI355X. bf16-MFMA in_proj / x_proj / chunk-scan
// (states pass AND y pass both MFMA, Mamba2 SSD form); bf16 prefix combine;
// direction-ordered streams; transposed-Wo out GEMM.

constexpr int DM   = 96;     // D_MODEL
constexpr int DI   = 192;    // D_INNER
constexpr int RK   = 6;      // DT_RANK
constexpr int NS   = 32;     // D_STATE (== HEAD_D)
constexpr int KD   = 4;      // directions
constexpr int HW   = 56;
constexpr int LT   = 3136;   // L = 56*56
constexpr int NB   = 8;      // batch
constexpr int NPOS = NB * LT;   // 25088
constexpr int NC   = 49;     // chunks per sequence
constexpr int CH   = 64;     // chunk length (49*64 = 3136)
constexpr int SEQ = NB * KD; // 32 sequences
constexpr int ELEM = RK * NS * NS;  // 6144 state elements per sequence
constexpr int NO   = 280;    // x_proj outputs (4*70)
constexpr int NOP  = 288;    // padded to 18 MFMA n-tiles
constexpr int NI   = 384;    // in_proj outputs (2*DI)

typedef __attribute__((ext_vector_type(8))) __bf16 bf16x8;
typedef __attribute__((ext_vector_type(4))) float f32x4;
typedef __attribute__((ext_vector_type(2))) float f32x2;

__device__ __forceinline__ float siluf(float x) { return x / (1.f + __expf(-x)); }

__device__ __forceinline__ unsigned short f2bf(float f) {  // RNE, finite inputs
  unsigned int u = __float_as_uint(f);
  u = (u + 0x7fffu + ((u >> 16) & 1u)) >> 16;
  return (unsigned short)u;
}
__device__ __forceinline__ float bf2f(unsigned short h) {
  return __uint_as_float(((unsigned int)h) << 16);
}
__device__ __forceinline__ unsigned int pack2(float a, float b) {
  return (unsigned int)f2bf(a) | ((unsigned int)f2bf(b) << 16);
}

// ---------------- Kernel 0a: Wi -> bf16 ----------------
__global__ __launch_bounds__(256) void k_wiprep(const float* __restrict__ Wi,
                                                unsigned short* __restrict__ Wib) {
  int t = blockIdx.x * 256 + threadIdx.x;
  if (t >= NI * DM) return;
  Wib[t] = f2bf(Wi[t]);
}

// ---------------- Kernel 0b: Wp -> bf16, padded to 288 rows ----------------
__global__ __launch_bounds__(256) void k_wprep(const float* __restrict__ Wp,
                                               unsigned short* __restrict__ Wpb) {
  int t = blockIdx.x * 256 + threadIdx.x;
  if (t >= NOP * DI) return;
  int o = t / DI;
  Wpb[t] = (o < NO) ? f2bf(Wp[t]) : (unsigned short)0;
}

// ---------------- Kernel 0c: Wo -> transposed fp32 Wot[DI][DM] ----------------
__global__ __launch_bounds__(256) void k_woprep(const float* __restrict__ Wo,
                                                float* __restrict__ Wot) {
  int t = blockIdx.x * 256 + threadIdx.x;
  if (t >= DM * DI) return;
  int o = t / DI, j = t % DI;
  Wot[j * DM + o] = Wo[t];
}

// ---------------- Kernel 1: in_proj via bf16 MFMA + split + silu(z) ----------
__global__ __launch_bounds__(256) void k_inproj(const float* __restrict__ x,
                                                const unsigned short* __restrict__ Wib,
                                                float* __restrict__ xi,
                                                float* __restrict__ zs) {
  int wid = threadIdx.x >> 6;
  int lane = threadIdx.x & 63;
  int pos0 = blockIdx.x * 64 + wid * 16;
  int lrow = lane & 15;
  int lgrp = lane >> 4;
  bf16x8 a[3];
  const float* arow = x + (size_t)(pos0 + lrow) * DM + lgrp * 8;
#pragma unroll
  for (int ks = 0; ks < 3; ks++) {
    f32x4 v0 = *reinterpret_cast<const f32x4*>(arow + ks * 32);
    f32x4 v1 = *reinterpret_cast<const f32x4*>(arow + ks * 32 + 4);
    union { unsigned short us[8]; bf16x8 v; } tmp;
#pragma unroll
    for (int j = 0; j < 4; j++) { tmp.us[j] = f2bf(v0[j]); tmp.us[4 + j] = f2bf(v1[j]); }
    a[ks] = tmp.v;
  }
  f32x4 acc[24];
#pragma unroll
  for (int t = 0; t < 24; t++) acc[t] = (f32x4){0.f, 0.f, 0.f, 0.f};
  const unsigned short* brow = Wib + (size_t)lrow * DM + lgrp * 8;
#pragma unroll
  for (int ks = 0; ks < 3; ks++) {
#pragma unroll
    for (int ot = 0; ot < 24; ot++) {
      bf16x8 bf = *reinterpret_cast<const bf16x8*>(brow + (size_t)ot * 16 * DM + ks * 32);
      acc[ot] = __builtin_amdgcn_mfma_f32_16x16x32_bf16(a[ks], bf, acc[ot], 0, 0, 0);
    }
  }
#pragma unroll
  for (int ot = 0; ot < 24; ot++) {
    int o = ot * 16 + lrow;
#pragma unroll
    for (int r = 0; r < 4; r++) {
      int pos = pos0 + lgrp * 4 + r;
      float v = acc[ot][r];
      if (o < DI) xi[(size_t)pos * DI + o] = v;
      else        zs[(size_t)pos * DI + (o - DI)] = siluf(v);
    }
  }
}

// ---------------- Kernel 2: depthwise conv -> bf16 (row-major + transposed) ----
__global__ __launch_bounds__(256) void k_conv(const float* __restrict__ xi,
                                              const float* __restrict__ cw,
                                              const float* __restrict__ cb,
                                              unsigned short* __restrict__ xcb,
                                              unsigned short* __restrict__ xcbT) {
  const int DH = DI / 2;
  int t = blockIdx.x * 256 + threadIdx.x;
  if (t >= NPOS * DH) return;
  int c2 = t % DH;
  int pos = t / DH;
  int p = pos % LT, b = pos / LT;
  int h = p / HW, w = p % HW;
  f32x2 acc = *reinterpret_cast<const f32x2*>(cb + c2 * 2);
  int base = b * LT * DI + c2 * 2;
#pragma unroll
  for (int dh = 0; dh < 3; dh++) {
    int hh = h + dh - 1;
    if (hh < 0 || hh >= HW) continue;
#pragma unroll
    for (int dw = 0; dw < 3; dw++) {
      int ww = w + dw - 1;
      if (ww < 0 || ww >= HW) continue;
      f32x2 wv = *reinterpret_cast<const f32x2*>(cw + (dh * 3 + dw) * DI + c2 * 2);
      f32x2 xv = *reinterpret_cast<const f32x2*>(xi + base + (hh * HW + ww) * DI);
      acc += wv * xv;
    }
  }
  unsigned int v = pack2(siluf(acc[0]), siluf(acc[1]));
  reinterpret_cast<unsigned int*>(xcb)[t] = v;
  int pt = w * HW + h;
  reinterpret_cast<unsigned int*>(xcbT)[(b * LT + pt) * DH + c2] = v;
}

// ---------------- Kernel 3: x_proj via bf16 MFMA -> direction-ordered streams --
// 4 waves/block: waves split {pos half} x {9-tile half} for 2x wave parallelism.
__global__ __launch_bounds__(256) void k_xproj(const unsigned short* __restrict__ xcb,
                                               const unsigned short* __restrict__ Wpb,
                                               const float* __restrict__ A_logs,
                                               const float* __restrict__ dt_bias,
                                               float* __restrict__ dtS,
                                               unsigned short* __restrict__ BsH,
                                               unsigned short* __restrict__ CsH) {
  int tid = threadIdx.x;
  int wid = tid >> 6;
  int lane = tid & 63;
  int pg = wid & 1, oh = wid >> 1;
  int pos0 = blockIdx.x * 32 + pg * 16;
  int lrow = lane & 15;
  int lgrp = lane >> 4;
  bf16x8 a[6];
  const unsigned short* arow = xcb + (size_t)(pos0 + lrow) * DI + lgrp * 8;
#pragma unroll
  for (int ks = 0; ks < 6; ks++)
    a[ks] = *reinterpret_cast<const bf16x8*>(arow + ks * 32);
  f32x4 acc[9];
#pragma unroll
  for (int t = 0; t < 9; t++) acc[t] = (f32x4){0.f, 0.f, 0.f, 0.f};
  const unsigned short* brow = Wpb + (size_t)(oh * 144 + lrow) * DI + lgrp * 8;
#pragma unroll
  for (int ks = 0; ks < 6; ks++) {
#pragma unroll
    for (int ot = 0; ot < 9; ot++) {
      bf16x8 bf = *reinterpret_cast<const bf16x8*>(brow + (size_t)ot * 16 * DI + ks * 32);
      acc[ot] = __builtin_amdgcn_mfma_f32_16x16x32_bf16(a[ks], bf, acc[ot], 0, 0, 0);
    }
  }
  int sp[4], spt[4], bb[4];
#pragma unroll
  for (int r = 0; r < 4; r++) {
    int pos = pos0 + lgrp * 4 + r;
    int b = pos / LT, p = pos - b * LT;
    int h = p / HW, w = p - h * HW;
    bb[r] = b; sp[r] = p; spt[r] = w * HW + h;
  }
#pragma unroll
  for (int ot = 0; ot < 9; ot++) {
    int o = (oh * 9 + ot) * 16 + lrow;
    if (o >= NO) continue;
    int k = o / 70, c = o % 70;
#pragma unroll
    for (int r = 0; r < 4; r++) {
      float v = acc[ot][r];
      int sidx = (k * NB + bb[r]) * LT + ((k & 1) ? spt[r] : sp[r]);
      if (c < RK) {
        float bias = dt_bias[k * RK + c];
        float s = v + bias;
        float dtv = (s > 20.f) ? s : log1pf(__expf(s));
        dtS[(size_t)sidx * RK + c] = dtv;
      } else if (c < RK + NS) {
        BsH[(size_t)sidx * NS + (c - RK)] = f2bf(v);
      } else {
        CsH[(size_t)sidx * NS + (c - RK - NS)] = f2bf(v);
      }
    }
  }
}

// ---------------- Kernel 4: MFMA states pass (S_end = X'.WB per chunk) --------
// Block = 384 thr = 6 waves (wave = r). Grid = SEQ*NC.
__global__ __launch_bounds__(384) void k_scanAm(const unsigned short* __restrict__ xcb,
                                                const unsigned short* __restrict__ xcbT,
                                                const float* __restrict__ dtS,
                                                const unsigned short* __restrict__ BsH,
                                                const float* __restrict__ A_logs,
                                                unsigned short* __restrict__ Send,
                                                float* __restrict__ Pend) {
  __shared__ unsigned short XT[DI][72];      // x chunk, channel-transposed [c][s]
  __shared__ unsigned short WB[6][32][72];   // per-wave: WBT[n][s]; later S[d][n]
  int bi = blockIdx.x;
  int chunk = bi % NC;
  int k = (bi / NC) & 3;
  int b = bi / (NC * KD);
  int seq = b * KD + k;
  int tid = threadIdx.x;
  int wid = tid >> 6;                        // r
  int lane = tid & 63;
  int lrow = lane & 15, lgrp = lane >> 4;
  int sb0 = (k * NB + b) * LT;
  int j0 = (k < 2) ? chunk * CH : (LT - 1 - chunk * CH);
  int dj = (k < 2) ? 1 : -1;
  // Phase 0: cooperative XT build
  const unsigned int* xs32 = reinterpret_cast<const unsigned int*>(
      ((k & 1) ? xcbT : xcb) + (size_t)b * LT * DI);
#pragma unroll
  for (int it = 0; it < 16; ++it) {
    int idx = it * 384 + tid;
    int s = idx / 96, cu = idx - s * 96;
    unsigned int v = xs32[(size_t)(j0 + s * dj) * 96 + cu];
    XT[2 * cu][s] = (unsigned short)(v & 0xffff);
    XT[2 * cu + 1][s] = (unsigned short)(v >> 16);
  }
  int r = wid;
  // Phase 0b: log-decay prefix scan (lane = step s)
  float Ar = -__expf(A_logs[k * RK + r]);
  float dt_l = dtS[(size_t)(sb0 + j0 + lane * dj) * RK + r];
  float Lam = dt_l * Ar;
#pragma unroll
  for (int off = 1; off < 64; off <<= 1) {
    float tv = __shfl_up(Lam, off, 64);
    Lam += (lane >= off) ? tv : 0.f;
  }
  float Lam63 = __shfl(Lam, 63, 64);
  float w = __expf(Lam63 - Lam) * dt_l;     // step-s weight
  // Phase 1: WBT[n][s] = w_s * B[s][n] (per-wave, lane = s)
  const unsigned int* brow32 = reinterpret_cast<const unsigned int*>(
      BsH + (size_t)(sb0 + j0 + lane * dj) * NS);
#pragma unroll
  for (int i = 0; i < 16; i++) {
    unsigned int v = brow32[i];
    WB[wid][2 * i][lane]     = f2bf(w * bf2f((unsigned short)(v & 0xffff)));
    WB[wid][2 * i + 1][lane] = f2bf(w * bf2f((unsigned short)(v >> 16)));
  }
  __syncthreads();   // XT complete (WB per-wave already ordered by lgkmcnt)
  // Phase 2: 8 MFMAs -> S[d][n] quadrants
  f32x4 acc[2][2];
#pragma unroll
  for (int i = 0; i < 2; i++)
#pragma unroll
    for (int j = 0; j < 2; j++) acc[i][j] = (f32x4){0.f, 0.f, 0.f, 0.f};
#pragma unroll
  for (int ks = 0; ks < 2; ks++) {
#pragma unroll
    for (int dtile = 0; dtile < 2; dtile++) {
      bf16x8 av = *reinterpret_cast<const bf16x8*>(&XT[r * 32 + dtile * 16 + lrow][ks * 32 + lgrp * 8]);
#pragma unroll
      for (int ntile = 0; ntile < 2; ntile++) {
        bf16x8 bv = *reinterpret_cast<const bf16x8*>(&WB[wid][ntile * 16 + lrow][ks * 32 + lgrp * 8]);
        acc[dtile][ntile] = __builtin_amdgcn_mfma_f32_16x16x32_bf16(av, bv, acc[dtile][ntile], 0, 0, 0);
      }
    }
  }
  // Phase 3: stage S into own WB region [d][n] (reads done), write Pend
#pragma unroll
  for (int dtile = 0; dtile < 2; dtile++)
#pragma unroll
    for (int ntile = 0; ntile < 2; ntile++)
#pragma unroll
      for (int q = 0; q < 4; q++)
        WB[wid][dtile * 16 + lgrp * 4 + q][ntile * 16 + lrow] = f2bf(acc[dtile][ntile][q]);
  if (lane == 0) Pend[(seq * NC + chunk) * RK + r] = __expf(Lam63);
  __syncthreads();
  // Phase 4: cooperative coalesced Send write (e = r*1024 + d*32 + n)
  unsigned int* dst = reinterpret_cast<unsigned int*>(Send + (size_t)(seq * NC + chunk) * ELEM);
  int e0 = tid * 16;
  int rr = e0 >> 10, dd = (e0 >> 5) & 31, nn = e0 & 31;
  const unsigned int* src = reinterpret_cast<const unsigned int*>(&WB[rr][dd][nn]);
#pragma unroll
  for (int i = 0; i < 8; i++) dst[tid * 8 + i] = src[i];
}

// ---------------- Kernel 5: chunk-state combine (bf16 in-place excl. prefix) ----
__global__ __launch_bounds__(256) void k_scanB(unsigned int* __restrict__ Send32,
                                               const float* __restrict__ Pend) {
  const int EU = ELEM / 2;
  int bi = blockIdx.x;
  int seq = bi / (EU / 256);
  int u = (bi % (EU / 256)) * 256 + threadIdx.x;
  int r = u >> 9;
  float run0 = 0.f, run1 = 0.f;
  for (int c = 0; c < NC; c++) {
    size_t idx = (size_t)(seq * NC + c) * EU + u;
    unsigned int v = Send32[idx];
    float t0 = bf2f((unsigned short)(v & 0xffff));
    float t1 = bf2f((unsigned short)(v >> 16));
    Send32[idx] = pack2(run0, run1);
    float pe = Pend[(seq * NC + c) * RK + r];
    run0 = run0 * pe + t0;
    run1 = run1 * pe + t1;
  }
}

// ---------------- Kernel 6: MFMA chunk scan (Y = G'X + e^Λ C·Sinit + D·x) -----
__global__ __launch_bounds__(384) void k_scanM(const unsigned short* __restrict__ xcb,
                                               const unsigned short* __restrict__ xcbT,
                                               const float* __restrict__ dtS,
                                               const unsigned short* __restrict__ BsH,
                                               const unsigned short* __restrict__ CsH,
                                               const float* __restrict__ A_logs,
                                               const float* __restrict__ Ds,
                                               const unsigned short* __restrict__ Sinit,
                                               unsigned short* __restrict__ ybh) {
  __shared__ unsigned short XT[DI][72];
  __shared__ unsigned short GB[6][32][72];
  int bi = blockIdx.x;
  int chunk = bi % NC;
  int k = (bi / NC) & 3;
  int b = bi / (NC * KD);
  int tid = threadIdx.x;
  int wid = tid >> 6;
  int lane = tid & 63;
  int lrow = lane & 15, lgrp = lane >> 4;
  int sb0 = (k * NB + b) * LT;
  int j0 = (k < 2) ? chunk * CH : (LT - 1 - chunk * CH);
  int dj = (k < 2) ? 1 : -1;
  const unsigned int* xs32 = reinterpret_cast<const unsigned int*>(
      ((k & 1) ? xcbT : xcb) + (size_t)b * LT * DI);
#pragma unroll
  for (int it = 0; it < 16; ++it) {
    int idx = it * 384 + tid;
    int s = idx / 96, cu = idx - s * 96;
    unsigned int v = xs32[(size_t)(j0 + s * dj) * 96 + cu];
    XT[2 * cu][s] = (unsigned short)(v & 0xffff);
    XT[2 * cu + 1][s] = (unsigned short)(v >> 16);
  }
  __syncthreads();
  int r = wid;
  float Ar = -__expf(A_logs[k * RK + r]);
  float dt_l = dtS[(size_t)(sb0 + j0 + lane * dj) * RK + r];
  float Lam = dt_l * Ar;
#pragma unroll
  for (int off = 1; off < 64; off <<= 1) {
    float tv = __shfl_up(Lam, off, 64);
    Lam += (lane >= off) ? tv : 0.f;
  }
  bf16x8 ct[4], bt[4];
#pragma unroll
  for (int i = 0; i < 4; i++) {
    int row = j0 + (i * 16 + lrow) * dj;
    ct[i] = *reinterpret_cast<const bf16x8*>(CsH + (size_t)(sb0 + row) * NS + lgrp * 8);
    bt[i] = *reinterpret_cast<const bf16x8*>(BsH + (size_t)(sb0 + row) * NS + lgrp * 8);
  }
  const unsigned short* sbase = Sinit + (size_t)((b * KD + k) * NC + chunk) * ELEM + r * NS * NS;
  bf16x8 sf[2];
#pragma unroll
  for (int djt = 0; djt < 2; djt++)
    sf[djt] = *reinterpret_cast<const bf16x8*>(sbase + (djt * 16 + lrow) * NS + lgrp * 8);
  f32x4 yi[4][2];
#pragma unroll
  for (int i = 0; i < 4; i++)
#pragma unroll
    for (int djt = 0; djt < 2; djt++)
      yi[i][djt] = __builtin_amdgcn_mfma_f32_16x16x32_bf16(ct[i], sf[djt],
                       (f32x4){0.f, 0.f, 0.f, 0.f}, 0, 0, 0);
  float dt_s4[4], Lam_s4[4];
#pragma unroll
  for (int j = 0; j < 4; j++) {
    dt_s4[j] = __shfl(dt_l, j * 16 + lrow, 64);
    Lam_s4[j] = __shfl(Lam, j * 16 + lrow, 64);
  }
  float Lam_t[4][4];
#pragma unroll
  for (int i = 0; i < 4; i++)
#pragma unroll
    for (int q = 0; q < 4; q++)
      Lam_t[i][q] = __shfl(Lam, i * 16 + lgrp * 4 + q, 64);
  f32x4 y[4][2];
#pragma unroll
  for (int i = 0; i < 4; i++)
#pragma unroll
    for (int djt = 0; djt < 2; djt++) y[i][djt] = (f32x4){0.f, 0.f, 0.f, 0.f};
#pragma unroll
  for (int h = 0; h < 2; h++) {
    int i0 = h * 2;
    int ncol = h ? 4 : 2;
#pragma unroll
    for (int it = 0; it < 2; it++) {
      int i = i0 + it;
#pragma unroll
      for (int j = 0; j < 4; j++) {
        if (j >= ncol) continue;
        f32x4 g = __builtin_amdgcn_mfma_f32_16x16x32_bf16(ct[i], bt[j],
                      (f32x4){0.f, 0.f, 0.f, 0.f}, 0, 0, 0);
        int s = j * 16 + lrow;
#pragma unroll
        for (int q = 0; q < 4; q++) {
          int t = i * 16 + lgrp * 4 + q;
          float wgt = (t >= s) ? __expf(Lam_t[i][q] - Lam_s4[j]) * dt_s4[j] : 0.f;
          GB[wid][it * 16 + lgrp * 4 + q][s] = f2bf(g[q] * wgt);
        }
      }
    }
    int nks = h ? 2 : 1;
#pragma unroll
    for (int it = 0; it < 2; it++) {
#pragma unroll
      for (int ks = 0; ks < nks; ks++) {
        bf16x8 ga = *reinterpret_cast<const bf16x8*>(&GB[wid][it * 16 + lrow][ks * 32 + lgrp * 8]);
#pragma unroll
        for (int djt = 0; djt < 2; djt++) {
          bf16x8 xb = *reinterpret_cast<const bf16x8*>(&XT[r * 32 + djt * 16 + lrow][ks * 32 + lgrp * 8]);
          y[i0 + it][djt] = __builtin_amdgcn_mfma_f32_16x16x32_bf16(ga, xb, y[i0 + it][djt], 0, 0, 0);
        }
      }
    }
  }
  float Dv[2];
#pragma unroll
  for (int djt = 0; djt < 2; djt++)
    Dv[djt] = Ds[(k * RK + r) * NS + djt * 16 + lrow];
  unsigned short* yb = ybh + (size_t)(k * NB + b) * LT * DI;
#pragma unroll
  for (int i = 0; i < 4; i++) {
#pragma unroll
    for (int q = 0; q < 4; q++) {
      int t = i * 16 + lgrp * 4 + q;
      float eL = __expf(Lam_t[i][q]);
      int jrow = j0 + t * dj;
#pragma unroll
      for (int djt = 0; djt < 2; djt++) {
        float xv = bf2f(XT[r * 32 + djt * 16 + lrow][t]);
        float val = y[i][djt][q] + eL * yi[i][djt][q] + Dv[djt] * xv;
        yb[(size_t)jrow * DI + r * 32 + djt * 16 + lrow] = f2bf(val);
      }
    }
  }
}

// ---------------- Kernel 7: merge + LN + gelu + *silu(z) + out_proj ----------------
__global__ __launch_bounds__(192) void k_out(const unsigned short* __restrict__ ybh,
                                             const float* __restrict__ zs,
                                             const float* __restrict__ ln_g,
                                             const float* __restrict__ ln_b,
                                             const float* __restrict__ Wot,
                                             float* __restrict__ out) {
  const int PP = 4;
  int pos0 = blockIdx.x * PP;
  int b = pos0 / LT, p0 = pos0 % LT;
  int h0 = p0 / HW, w0 = p0 % HW;
  int pt0 = w0 * HW + h0;
  int tid = threadIdx.x;
  float v[PP], s1[PP], s2[PP];
#pragma unroll
  for (int q = 0; q < PP; q++) {
    int p = p0 + q;
    int pt = pt0 + q * HW;
    float acc = bf2f(ybh[((size_t)(0 * NB + b) * LT + p) * DI + tid])
              + bf2f(ybh[((size_t)(1 * NB + b) * LT + pt) * DI + tid])
              + bf2f(ybh[((size_t)(2 * NB + b) * LT + p) * DI + tid])
              + bf2f(ybh[((size_t)(3 * NB + b) * LT + pt) * DI + tid]);
    v[q] = acc; s1[q] = acc; s2[q] = acc * acc;
  }
#pragma unroll
  for (int off = 32; off; off >>= 1) {
#pragma unroll
    for (int q = 0; q < PP; q++) {
      s1[q] += __shfl_down(s1[q], off, 64);
      s2[q] += __shfl_down(s2[q], off, 64);
    }
  }
  __shared__ float rs1[3][PP], rs2[3][PP];
  int wave = tid >> 6, lane = tid & 63;
  if (lane == 0) {
#pragma unroll
    for (int q = 0; q < PP; q++) { rs1[wave][q] = s1[q]; rs2[wave][q] = s2[q]; }
  }
  __syncthreads();
  __shared__ float su[PP][DI];
  float g = ln_g[tid], be = ln_b[tid];
#pragma unroll
  for (int q = 0; q < PP; q++) {
    float mean = (rs1[0][q] + rs1[1][q] + rs1[2][q]) * (1.f / 192.f);
    float var = (rs2[0][q] + rs2[1][q] + rs2[2][q]) * (1.f / 192.f) - mean * mean;
    float rstd = rsqrtf(var + 1e-5f);
    float t = (v[q] - mean) * rstd * g + be;
    float ge = 0.5f * t * (1.f + erff(t * 0.70710678118f));
    su[q][tid] = ge * zs[(pos0 + q) * DI + tid];
  }
  __syncthreads();
  int o = tid % DM, half = tid / DM;
  const float* wcol = Wot + (size_t)half * DM * DM + o;
  float acc[PP];
#pragma unroll
  for (int q = 0; q < PP; q++) acc[q] = 0.f;
  for (int j = 0; j < DM; j++) {
    float w = wcol[(size_t)j * DM];
#pragma unroll
    for (int q = 0; q < PP; q++) acc[q] += w * su[q][half * DM + j];
  }
  __shared__ float part[PP][DI];
#pragma unroll
  for (int q = 0; q < PP; q++) part[q][tid] = acc[q];
  __syncthreads();
  if (tid < DM) {
#pragma unroll
    for (int q = 0; q < PP; q++)
      out[(pos0 + q) * DM + tid] = part[q][tid] + part[q][tid + DM];
  }
}

extern "C" void kernel_launch(void* const* d_in, const int* in_sizes, int n_in,
                              void* d_out, int out_size, void* d_ws, size_t ws_size,
                              hipStream_t stream) {
  const float* x       = (const float*)d_in[0];
  const float* Wi      = (const float*)d_in[1];
  const float* cw      = (const float*)d_in[2];
  const float* cb      = (const float*)d_in[3];
  const float* Wp      = (const float*)d_in[4];
  const float* Ds      = (const float*)d_in[5];
  const float* A_logs  = (const float*)d_in[6];
  const float* dt_bias = (const float*)d_in[7];
  const float* ln_g    = (const float*)d_in[8];
  const float* ln_b    = (const float*)d_in[9];
  const float* Wo      = (const float*)d_in[10];
  float* out = (float*)d_out;

  float* ws = (float*)d_ws;
  float* xi    = ws;                         // NPOS*DI f32
  float* zs    = xi + (size_t)NPOS * DI;     // NPOS*DI f32
  float* dtS   = zs + (size_t)NPOS * DI;     // KD*NB*LT*RK f32 (direction-ordered)
  float* Pend  = dtS + (size_t)NPOS * KD * RK;      // SEQ*NC*RK f32
  float* Wot   = Pend + (size_t)SEQ * NC * RK;      // DI*DM f32
  float* WpbF  = Wot + (size_t)DI * DM;
  float* WibF  = WpbF + (size_t)NOP * DI / 2;
  unsigned short* BsH  = (unsigned short*)(WibF + (size_t)NI * DM / 2);  // KD*NPOS*NS bf16
  unsigned short* CsH  = BsH + (size_t)NPOS * KD * NS;
  unsigned short* xcb  = CsH + (size_t)NPOS * KD * NS;   // NPOS*DI bf16
  unsigned short* xcbT = xcb + (size_t)NPOS * DI;
  unsigned short* ybh  = xcbT + (size_t)NPOS * DI;        // KD*NPOS*DI bf16
  unsigned short* Send = ybh + (size_t)NPOS * KD * DI;    // SEQ*NC*ELEM bf16
  unsigned short* Wpb = (unsigned short*)WpbF;
  unsigned short* Wib = (unsigned short*)WibF;

  k_wiprep<<<(NI * DM + 255) / 256, 256, 0, stream>>>(Wi, Wib);
  k_wprep<<<(NOP * DI + 255) / 256, 256, 0, stream>>>(Wp, Wpb);
  k_woprep<<<(DM * DI + 255) / 256, 256, 0, stream>>>(Wo, Wot);
  k_inproj<<<NPOS / 64, 256, 0, stream>>>(x, Wib, xi, zs);
  k_conv<<<(NPOS * (DI / 2) + 255) / 256, 256, 0, stream>>>(xi, cw, cb, xcb, xcbT);
  k_xproj<<<NPOS / 32, 256, 0, stream>>>(xcb, Wpb, A_logs, dt_bias, dtS, BsH, CsH);
  k_scanAm<<<SEQ * NC, 384, 0, stream>>>(xcb, xcbT, dtS, BsH, A_logs, Send, Pend);
  k_scanB<<<SEQ * (ELEM / 512), 256, 0, stream>>>((unsigned int*)Send, Pend);
  k_scanM<<<SEQ * NC, 384, 0, stream>>>(xcb, xcbT, dtS, BsH, CsH, A_logs, Ds, Send, ybh);
  k_out<<<NPOS / 4, 192, 0, stream>>>(ybh, zs, ln_g, ln_b, Wot, out);
}

// Round 14
// 202.491 us; speedup vs baseline: 1.4521x; 1.0335x over previous
//
#include <hip/hip_runtime.h>

// VMamba mixer forward, MI355X. bf16-MFMA in_proj / x_proj / chunk-scan /
// out_proj; bf16 prefix combine; direction-ordered streams.

constexpr int DM   = 96;     // D_MODEL
constexpr int DI   = 192;    // D_INNER
constexpr int RK   = 6;      // DT_RANK
constexpr int NS   = 32;     // D_STATE (== HEAD_D)
constexpr int KD   = 4;      // directions
constexpr int HW   = 56;
constexpr int LT   = 3136;   // L = 56*56
constexpr int NB   = 8;      // batch
constexpr int NPOS = NB * LT;   // 25088
constexpr int NC   = 49;     // chunks per sequence
constexpr int CH   = 64;     // chunk length (49*64 = 3136)
constexpr int SEQ = NB * KD; // 32 sequences
constexpr int ELEM = RK * NS * NS;  // 6144 state elements per sequence
constexpr int NO   = 280;    // x_proj outputs (4*70)
constexpr int NOP  = 288;    // padded to 18 MFMA n-tiles
constexpr int NI   = 384;    // in_proj outputs (2*DI)

typedef __attribute__((ext_vector_type(8))) __bf16 bf16x8;
typedef __attribute__((ext_vector_type(4))) float f32x4;
typedef __attribute__((ext_vector_type(2))) float f32x2;

__device__ __forceinline__ float siluf(float x) { return x / (1.f + __expf(-x)); }

__device__ __forceinline__ unsigned short f2bf(float f) {  // RNE, finite inputs
  unsigned int u = __float_as_uint(f);
  u = (u + 0x7fffu + ((u >> 16) & 1u)) >> 16;
  return (unsigned short)u;
}
__device__ __forceinline__ float bf2f(unsigned short h) {
  return __uint_as_float(((unsigned int)h) << 16);
}
__device__ __forceinline__ unsigned int pack2(float a, float b) {
  return (unsigned int)f2bf(a) | ((unsigned int)f2bf(b) << 16);
}

// ---------------- Kernel 0a: Wi -> bf16 ----------------
__global__ __launch_bounds__(256) void k_wiprep(const float* __restrict__ Wi,
                                                unsigned short* __restrict__ Wib) {
  int t = blockIdx.x * 256 + threadIdx.x;
  if (t >= NI * DM) return;
  Wib[t] = f2bf(Wi[t]);
}

// ---------------- Kernel 0b: Wp -> bf16, padded to 288 rows ----------------
__global__ __launch_bounds__(256) void k_wprep(const float* __restrict__ Wp,
                                               unsigned short* __restrict__ Wpb) {
  int t = blockIdx.x * 256 + threadIdx.x;
  if (t >= NOP * DI) return;
  int o = t / DI;
  Wpb[t] = (o < NO) ? f2bf(Wp[t]) : (unsigned short)0;
}

// ---------------- Kernel 0c: Wo -> bf16 (row-major, rows = outputs) ----------
__global__ __launch_bounds__(256) void k_wob(const float* __restrict__ Wo,
                                             unsigned short* __restrict__ Wob) {
  int t = blockIdx.x * 256 + threadIdx.x;
  if (t >= DM * DI) return;
  Wob[t] = f2bf(Wo[t]);
}

// ---------------- Kernel 1: in_proj via bf16 MFMA + split + silu(z) ----------
__global__ __launch_bounds__(256) void k_inproj(const float* __restrict__ x,
                                                const unsigned short* __restrict__ Wib,
                                                float* __restrict__ xi,
                                                float* __restrict__ zs) {
  int wid = threadIdx.x >> 6;
  int lane = threadIdx.x & 63;
  int pos0 = blockIdx.x * 64 + wid * 16;
  int lrow = lane & 15;
  int lgrp = lane >> 4;
  bf16x8 a[3];
  const float* arow = x + (size_t)(pos0 + lrow) * DM + lgrp * 8;
#pragma unroll
  for (int ks = 0; ks < 3; ks++) {
    f32x4 v0 = *reinterpret_cast<const f32x4*>(arow + ks * 32);
    f32x4 v1 = *reinterpret_cast<const f32x4*>(arow + ks * 32 + 4);
    union { unsigned short us[8]; bf16x8 v; } tmp;
#pragma unroll
    for (int j = 0; j < 4; j++) { tmp.us[j] = f2bf(v0[j]); tmp.us[4 + j] = f2bf(v1[j]); }
    a[ks] = tmp.v;
  }
  f32x4 acc[24];
#pragma unroll
  for (int t = 0; t < 24; t++) acc[t] = (f32x4){0.f, 0.f, 0.f, 0.f};
  const unsigned short* brow = Wib + (size_t)lrow * DM + lgrp * 8;
#pragma unroll
  for (int ks = 0; ks < 3; ks++) {
#pragma unroll
    for (int ot = 0; ot < 24; ot++) {
      bf16x8 bf = *reinterpret_cast<const bf16x8*>(brow + (size_t)ot * 16 * DM + ks * 32);
      acc[ot] = __builtin_amdgcn_mfma_f32_16x16x32_bf16(a[ks], bf, acc[ot], 0, 0, 0);
    }
  }
#pragma unroll
  for (int ot = 0; ot < 24; ot++) {
    int o = ot * 16 + lrow;
#pragma unroll
    for (int r = 0; r < 4; r++) {
      int pos = pos0 + lgrp * 4 + r;
      float v = acc[ot][r];
      if (o < DI) xi[(size_t)pos * DI + o] = v;
      else        zs[(size_t)pos * DI + (o - DI)] = siluf(v);
    }
  }
}

// ---------------- Kernel 2: depthwise conv -> bf16 (row-major + transposed) ----
__global__ __launch_bounds__(256) void k_conv(const float* __restrict__ xi,
                                              const float* __restrict__ cw,
                                              const float* __restrict__ cb,
                                              unsigned short* __restrict__ xcb,
                                              unsigned short* __restrict__ xcbT) {
  const int DH = DI / 2;
  int t = blockIdx.x * 256 + threadIdx.x;
  if (t >= NPOS * DH) return;
  int c2 = t % DH;
  int pos = t / DH;
  int p = pos % LT, b = pos / LT;
  int h = p / HW, w = p % HW;
  f32x2 acc = *reinterpret_cast<const f32x2*>(cb + c2 * 2);
  int base = b * LT * DI + c2 * 2;
#pragma unroll
  for (int dh = 0; dh < 3; dh++) {
    int hh = h + dh - 1;
    if (hh < 0 || hh >= HW) continue;
#pragma unroll
    for (int dw = 0; dw < 3; dw++) {
      int ww = w + dw - 1;
      if (ww < 0 || ww >= HW) continue;
      f32x2 wv = *reinterpret_cast<const f32x2*>(cw + (dh * 3 + dw) * DI + c2 * 2);
      f32x2 xv = *reinterpret_cast<const f32x2*>(xi + base + (hh * HW + ww) * DI);
      acc += wv * xv;
    }
  }
  unsigned int v = pack2(siluf(acc[0]), siluf(acc[1]));
  reinterpret_cast<unsigned int*>(xcb)[t] = v;
  int pt = w * HW + h;
  reinterpret_cast<unsigned int*>(xcbT)[(b * LT + pt) * DH + c2] = v;
}

// ---------------- Kernel 3: x_proj, K-split 4-wave MFMA -> dir-ordered streams --
// Block = 256 thr / 16 positions. Wave w: oh = w>>1 (9 n-tiles), kh = w&1 (3 ks).
__global__ __launch_bounds__(256) void k_xproj(const unsigned short* __restrict__ xcb,
                                               const unsigned short* __restrict__ Wpb,
                                               const float* __restrict__ A_logs,
                                               const float* __restrict__ dt_bias,
                                               float* __restrict__ dtS,
                                               unsigned short* __restrict__ BsH,
                                               unsigned short* __restrict__ CsH) {
  __shared__ float red[2][9][64][5];
  int tid = threadIdx.x;
  int wid = tid >> 6;
  int lane = tid & 63;
  int oh = wid >> 1, kh = wid & 1;
  int pos0 = blockIdx.x * 16;
  int lrow = lane & 15;
  int lgrp = lane >> 4;
  bf16x8 a[3];
  const unsigned short* arow = xcb + (size_t)(pos0 + lrow) * DI + kh * 96 + lgrp * 8;
#pragma unroll
  for (int ks = 0; ks < 3; ks++)
    a[ks] = *reinterpret_cast<const bf16x8*>(arow + ks * 32);
  f32x4 acc[9];
#pragma unroll
  for (int t = 0; t < 9; t++) acc[t] = (f32x4){0.f, 0.f, 0.f, 0.f};
  const unsigned short* brow = Wpb + (size_t)(oh * 144 + lrow) * DI + kh * 96 + lgrp * 8;
#pragma unroll
  for (int ks = 0; ks < 3; ks++) {
#pragma unroll
    for (int ot = 0; ot < 9; ot++) {
      bf16x8 bf = *reinterpret_cast<const bf16x8*>(brow + (size_t)ot * 16 * DI + ks * 32);
      acc[ot] = __builtin_amdgcn_mfma_f32_16x16x32_bf16(a[ks], bf, acc[ot], 0, 0, 0);
    }
  }
  if (kh == 1) {
#pragma unroll
    for (int ot = 0; ot < 9; ot++)
#pragma unroll
      for (int q = 0; q < 4; q++) red[oh][ot][lane][q] = acc[ot][q];
  }
  __syncthreads();
  if (kh == 1) return;
  int sp[4], spt[4], bb[4];
#pragma unroll
  for (int r = 0; r < 4; r++) {
    int pos = pos0 + lgrp * 4 + r;
    int b = pos / LT, p = pos - b * LT;
    int h = p / HW, w = p - h * HW;
    bb[r] = b; sp[r] = p; spt[r] = w * HW + h;
  }
#pragma unroll
  for (int ot = 0; ot < 9; ot++) {
    int o = (oh * 9 + ot) * 16 + lrow;
    if (o >= NO) continue;
    int k = o / 70, c = o % 70;
#pragma unroll
    for (int r = 0; r < 4; r++) {
      float v = acc[ot][r] + red[oh][ot][lane][r];
      int sidx = (k * NB + bb[r]) * LT + ((k & 1) ? spt[r] : sp[r]);
      if (c < RK) {
        float bias = dt_bias[k * RK + c];
        float s = v + bias;
        float dtv = (s > 20.f) ? s : log1pf(__expf(s));
        dtS[(size_t)sidx * RK + c] = dtv;
      } else if (c < RK + NS) {
        BsH[(size_t)sidx * NS + (c - RK)] = f2bf(v);
      } else {
        CsH[(size_t)sidx * NS + (c - RK - NS)] = f2bf(v);
      }
    }
  }
}

// ---------------- Kernel 4: MFMA states pass (S_end = X'.WB per chunk) --------
__global__ __launch_bounds__(384) void k_scanAm(const unsigned short* __restrict__ xcb,
                                                const unsigned short* __restrict__ xcbT,
                                                const float* __restrict__ dtS,
                                                const unsigned short* __restrict__ BsH,
                                                const float* __restrict__ A_logs,
                                                unsigned short* __restrict__ Send,
                                                float* __restrict__ Pend) {
  __shared__ unsigned short XT[DI][72];      // x chunk, channel-transposed [c][s]
  __shared__ unsigned short WB[6][32][72];   // per-wave: WBT[n][s]; later S[d][n]
  int bi = blockIdx.x;
  int chunk = bi % NC;
  int k = (bi / NC) & 3;
  int b = bi / (NC * KD);
  int seq = b * KD + k;
  int tid = threadIdx.x;
  int wid = tid >> 6;                        // r
  int lane = tid & 63;
  int lrow = lane & 15, lgrp = lane >> 4;
  int sb0 = (k * NB + b) * LT;
  int j0 = (k < 2) ? chunk * CH : (LT - 1 - chunk * CH);
  int dj = (k < 2) ? 1 : -1;
  const unsigned int* xs32 = reinterpret_cast<const unsigned int*>(
      ((k & 1) ? xcbT : xcb) + (size_t)b * LT * DI);
#pragma unroll
  for (int it = 0; it < 16; ++it) {
    int idx = it * 384 + tid;
    int s = idx / 96, cu = idx - s * 96;
    unsigned int v = xs32[(size_t)(j0 + s * dj) * 96 + cu];
    XT[2 * cu][s] = (unsigned short)(v & 0xffff);
    XT[2 * cu + 1][s] = (unsigned short)(v >> 16);
  }
  int r = wid;
  float Ar = -__expf(A_logs[k * RK + r]);
  float dt_l = dtS[(size_t)(sb0 + j0 + lane * dj) * RK + r];
  float Lam = dt_l * Ar;
#pragma unroll
  for (int off = 1; off < 64; off <<= 1) {
    float tv = __shfl_up(Lam, off, 64);
    Lam += (lane >= off) ? tv : 0.f;
  }
  float Lam63 = __shfl(Lam, 63, 64);
  float w = __expf(Lam63 - Lam) * dt_l;
  const unsigned int* brow32 = reinterpret_cast<const unsigned int*>(
      BsH + (size_t)(sb0 + j0 + lane * dj) * NS);
#pragma unroll
  for (int i = 0; i < 16; i++) {
    unsigned int v = brow32[i];
    WB[wid][2 * i][lane]     = f2bf(w * bf2f((unsigned short)(v & 0xffff)));
    WB[wid][2 * i + 1][lane] = f2bf(w * bf2f((unsigned short)(v >> 16)));
  }
  __syncthreads();
  f32x4 acc[2][2];
#pragma unroll
  for (int i = 0; i < 2; i++)
#pragma unroll
    for (int j = 0; j < 2; j++) acc[i][j] = (f32x4){0.f, 0.f, 0.f, 0.f};
#pragma unroll
  for (int ks = 0; ks < 2; ks++) {
#pragma unroll
    for (int dtile = 0; dtile < 2; dtile++) {
      bf16x8 av = *reinterpret_cast<const bf16x8*>(&XT[r * 32 + dtile * 16 + lrow][ks * 32 + lgrp * 8]);
#pragma unroll
      for (int ntile = 0; ntile < 2; ntile++) {
        bf16x8 bv = *reinterpret_cast<const bf16x8*>(&WB[wid][ntile * 16 + lrow][ks * 32 + lgrp * 8]);
        acc[dtile][ntile] = __builtin_amdgcn_mfma_f32_16x16x32_bf16(av, bv, acc[dtile][ntile], 0, 0, 0);
      }
    }
  }
#pragma unroll
  for (int dtile = 0; dtile < 2; dtile++)
#pragma unroll
    for (int ntile = 0; ntile < 2; ntile++)
#pragma unroll
      for (int q = 0; q < 4; q++)
        WB[wid][dtile * 16 + lgrp * 4 + q][ntile * 16 + lrow] = f2bf(acc[dtile][ntile][q]);
  if (lane == 0) Pend[(seq * NC + chunk) * RK + r] = __expf(Lam63);
  __syncthreads();
  unsigned int* dst = reinterpret_cast<unsigned int*>(Send + (size_t)(seq * NC + chunk) * ELEM);
  int e0 = tid * 16;
  int rr = e0 >> 10, dd = (e0 >> 5) & 31, nn = e0 & 31;
  const unsigned int* src = reinterpret_cast<const unsigned int*>(&WB[rr][dd][nn]);
#pragma unroll
  for (int i = 0; i < 8; i++) dst[tid * 8 + i] = src[i];
}

// ---------------- Kernel 5: chunk-state combine (bf16 in-place excl. prefix) ----
__global__ __launch_bounds__(256) void k_scanB(unsigned int* __restrict__ Send32,
                                               const float* __restrict__ Pend) {
  const int EU = ELEM / 2;
  int bi = blockIdx.x;
  int seq = bi / (EU / 256);
  int u = (bi % (EU / 256)) * 256 + threadIdx.x;
  int r = u >> 9;
  float run0 = 0.f, run1 = 0.f;
  for (int c = 0; c < NC; c++) {
    size_t idx = (size_t)(seq * NC + c) * EU + u;
    unsigned int v = Send32[idx];
    float t0 = bf2f((unsigned short)(v & 0xffff));
    float t1 = bf2f((unsigned short)(v >> 16));
    Send32[idx] = pack2(run0, run1);
    float pe = Pend[(seq * NC + c) * RK + r];
    run0 = run0 * pe + t0;
    run1 = run1 * pe + t1;
  }
}

// ---------------- Kernel 6: MFMA chunk scan (Y = G'X + e^Λ C·Sinit + D·x) -----
__global__ __launch_bounds__(384) void k_scanM(const unsigned short* __restrict__ xcb,
                                               const unsigned short* __restrict__ xcbT,
                                               const float* __restrict__ dtS,
                                               const unsigned short* __restrict__ BsH,
                                               const unsigned short* __restrict__ CsH,
                                               const float* __restrict__ A_logs,
                                               const float* __restrict__ Ds,
                                               const unsigned short* __restrict__ Sinit,
                                               unsigned short* __restrict__ ybh) {
  __shared__ unsigned short XT[DI][72];
  __shared__ unsigned short GB[6][32][72];
  int bi = blockIdx.x;
  int chunk = bi % NC;
  int k = (bi / NC) & 3;
  int b = bi / (NC * KD);
  int tid = threadIdx.x;
  int wid = tid >> 6;
  int lane = tid & 63;
  int lrow = lane & 15, lgrp = lane >> 4;
  int sb0 = (k * NB + b) * LT;
  int j0 = (k < 2) ? chunk * CH : (LT - 1 - chunk * CH);
  int dj = (k < 2) ? 1 : -1;
  const unsigned int* xs32 = reinterpret_cast<const unsigned int*>(
      ((k & 1) ? xcbT : xcb) + (size_t)b * LT * DI);
#pragma unroll
  for (int it = 0; it < 16; ++it) {
    int idx = it * 384 + tid;
    int s = idx / 96, cu = idx - s * 96;
    unsigned int v = xs32[(size_t)(j0 + s * dj) * 96 + cu];
    XT[2 * cu][s] = (unsigned short)(v & 0xffff);
    XT[2 * cu + 1][s] = (unsigned short)(v >> 16);
  }
  __syncthreads();
  int r = wid;
  float Ar = -__expf(A_logs[k * RK + r]);
  float dt_l = dtS[(size_t)(sb0 + j0 + lane * dj) * RK + r];
  float Lam = dt_l * Ar;
#pragma unroll
  for (int off = 1; off < 64; off <<= 1) {
    float tv = __shfl_up(Lam, off, 64);
    Lam += (lane >= off) ? tv : 0.f;
  }
  bf16x8 ct[4], bt[4];
#pragma unroll
  for (int i = 0; i < 4; i++) {
    int row = j0 + (i * 16 + lrow) * dj;
    ct[i] = *reinterpret_cast<const bf16x8*>(CsH + (size_t)(sb0 + row) * NS + lgrp * 8);
    bt[i] = *reinterpret_cast<const bf16x8*>(BsH + (size_t)(sb0 + row) * NS + lgrp * 8);
  }
  const unsigned short* sbase = Sinit + (size_t)((b * KD + k) * NC + chunk) * ELEM + r * NS * NS;
  bf16x8 sf[2];
#pragma unroll
  for (int djt = 0; djt < 2; djt++)
    sf[djt] = *reinterpret_cast<const bf16x8*>(sbase + (djt * 16 + lrow) * NS + lgrp * 8);
  f32x4 yi[4][2];
#pragma unroll
  for (int i = 0; i < 4; i++)
#pragma unroll
    for (int djt = 0; djt < 2; djt++)
      yi[i][djt] = __builtin_amdgcn_mfma_f32_16x16x32_bf16(ct[i], sf[djt],
                       (f32x4){0.f, 0.f, 0.f, 0.f}, 0, 0, 0);
  float dt_s4[4], Lam_s4[4];
#pragma unroll
  for (int j = 0; j < 4; j++) {
    dt_s4[j] = __shfl(dt_l, j * 16 + lrow, 64);
    Lam_s4[j] = __shfl(Lam, j * 16 + lrow, 64);
  }
  float Lam_t[4][4];
#pragma unroll
  for (int i = 0; i < 4; i++)
#pragma unroll
    for (int q = 0; q < 4; q++)
      Lam_t[i][q] = __shfl(Lam, i * 16 + lgrp * 4 + q, 64);
  f32x4 y[4][2];
#pragma unroll
  for (int i = 0; i < 4; i++)
#pragma unroll
    for (int djt = 0; djt < 2; djt++) y[i][djt] = (f32x4){0.f, 0.f, 0.f, 0.f};
#pragma unroll
  for (int h = 0; h < 2; h++) {
    int i0 = h * 2;
    int ncol = h ? 4 : 2;
#pragma unroll
    for (int it = 0; it < 2; it++) {
      int i = i0 + it;
#pragma unroll
      for (int j = 0; j < 4; j++) {
        if (j >= ncol) continue;
        f32x4 g = __builtin_amdgcn_mfma_f32_16x16x32_bf16(ct[i], bt[j],
                      (f32x4){0.f, 0.f, 0.f, 0.f}, 0, 0, 0);
        int s = j * 16 + lrow;
#pragma unroll
        for (int q = 0; q < 4; q++) {
          int t = i * 16 + lgrp * 4 + q;
          float wgt = (t >= s) ? __expf(Lam_t[i][q] - Lam_s4[j]) * dt_s4[j] : 0.f;
          GB[wid][it * 16 + lgrp * 4 + q][s] = f2bf(g[q] * wgt);
        }
      }
    }
    int nks = h ? 2 : 1;
#pragma unroll
    for (int it = 0; it < 2; it++) {
#pragma unroll
      for (int ks = 0; ks < nks; ks++) {
        bf16x8 ga = *reinterpret_cast<const bf16x8*>(&GB[wid][it * 16 + lrow][ks * 32 + lgrp * 8]);
#pragma unroll
        for (int djt = 0; djt < 2; djt++) {
          bf16x8 xb = *reinterpret_cast<const bf16x8*>(&XT[r * 32 + djt * 16 + lrow][ks * 32 + lgrp * 8]);
          y[i0 + it][djt] = __builtin_amdgcn_mfma_f32_16x16x32_bf16(ga, xb, y[i0 + it][djt], 0, 0, 0);
        }
      }
    }
  }
  float Dv[2];
#pragma unroll
  for (int djt = 0; djt < 2; djt++)
    Dv[djt] = Ds[(k * RK + r) * NS + djt * 16 + lrow];
  unsigned short* yb = ybh + (size_t)(k * NB + b) * LT * DI;
#pragma unroll
  for (int i = 0; i < 4; i++) {
#pragma unroll
    for (int q = 0; q < 4; q++) {
      int t = i * 16 + lgrp * 4 + q;
      float eL = __expf(Lam_t[i][q]);
      int jrow = j0 + t * dj;
#pragma unroll
      for (int djt = 0; djt < 2; djt++) {
        float xv = bf2f(XT[r * 32 + djt * 16 + lrow][t]);
        float val = y[i][djt][q] + eL * yi[i][djt][q] + Dv[djt] * xv;
        yb[(size_t)jrow * DI + r * 32 + djt * 16 + lrow] = f2bf(val);
      }
    }
  }
}

// ---------------- Kernel 7a: merge + LN + gelu + *silu(z) -> bf16 su ----------
__global__ __launch_bounds__(192) void k_ln(const unsigned short* __restrict__ ybh,
                                            const float* __restrict__ zs,
                                            const float* __restrict__ ln_g,
                                            const float* __restrict__ ln_b,
                                            unsigned short* __restrict__ sub) {
  const int PP = 4;
  int pos0 = blockIdx.x * PP;
  int b = pos0 / LT, p0 = pos0 % LT;
  int h0 = p0 / HW, w0 = p0 % HW;
  int pt0 = w0 * HW + h0;
  int tid = threadIdx.x;
  float v[PP], s1[PP], s2[PP];
#pragma unroll
  for (int q = 0; q < PP; q++) {
    int p = p0 + q;
    int pt = pt0 + q * HW;
    float acc = bf2f(ybh[((size_t)(0 * NB + b) * LT + p) * DI + tid])
              + bf2f(ybh[((size_t)(1 * NB + b) * LT + pt) * DI + tid])
              + bf2f(ybh[((size_t)(2 * NB + b) * LT + p) * DI + tid])
              + bf2f(ybh[((size_t)(3 * NB + b) * LT + pt) * DI + tid]);
    v[q] = acc; s1[q] = acc; s2[q] = acc * acc;
  }
#pragma unroll
  for (int off = 32; off; off >>= 1) {
#pragma unroll
    for (int q = 0; q < PP; q++) {
      s1[q] += __shfl_down(s1[q], off, 64);
      s2[q] += __shfl_down(s2[q], off, 64);
    }
  }
  __shared__ float rs1[3][PP], rs2[3][PP];
  int wave = tid >> 6, lane = tid & 63;
  if (lane == 0) {
#pragma unroll
    for (int q = 0; q < PP; q++) { rs1[wave][q] = s1[q]; rs2[wave][q] = s2[q]; }
  }
  __syncthreads();
  float g = ln_g[tid], be = ln_b[tid];
#pragma unroll
  for (int q = 0; q < PP; q++) {
    float mean = (rs1[0][q] + rs1[1][q] + rs1[2][q]) * (1.f / 192.f);
    float var = (rs2[0][q] + rs2[1][q] + rs2[2][q]) * (1.f / 192.f) - mean * mean;
    float rstd = rsqrtf(var + 1e-5f);
    float t = (v[q] - mean) * rstd * g + be;
    float ge = 0.5f * t * (1.f + erff(t * 0.70710678118f));
    sub[(size_t)(pos0 + q) * DI + tid] = f2bf(ge * zs[(size_t)(pos0 + q) * DI + tid]);
  }
}

// ---------------- Kernel 7b: out_proj via bf16 MFMA ----------------
// Wave = 16 positions; 6 n-tiles (96 outputs); K=192 in 6 steps.
__global__ __launch_bounds__(256) void k_oproj(const unsigned short* __restrict__ sub,
                                               const unsigned short* __restrict__ Wob,
                                               float* __restrict__ out) {
  int wid = threadIdx.x >> 6;
  int lane = threadIdx.x & 63;
  int pos0 = blockIdx.x * 64 + wid * 16;
  int lrow = lane & 15;
  int lgrp = lane >> 4;
  bf16x8 a[6];
  const unsigned short* arow = sub + (size_t)(pos0 + lrow) * DI + lgrp * 8;
#pragma unroll
  for (int ks = 0; ks < 6; ks++)
    a[ks] = *reinterpret_cast<const bf16x8*>(arow + ks * 32);
  f32x4 acc[6];
#pragma unroll
  for (int t = 0; t < 6; t++) acc[t] = (f32x4){0.f, 0.f, 0.f, 0.f};
  const unsigned short* brow = Wob + (size_t)lrow * DI + lgrp * 8;
#pragma unroll
  for (int ks = 0; ks < 6; ks++) {
#pragma unroll
    for (int ot = 0; ot < 6; ot++) {
      bf16x8 bf = *reinterpret_cast<const bf16x8*>(brow + (size_t)ot * 16 * DI + ks * 32);
      acc[ot] = __builtin_amdgcn_mfma_f32_16x16x32_bf16(a[ks], bf, acc[ot], 0, 0, 0);
    }
  }
#pragma unroll
  for (int ot = 0; ot < 6; ot++) {
    int o = ot * 16 + lrow;
#pragma unroll
    for (int r = 0; r < 4; r++) {
      int pos = pos0 + lgrp * 4 + r;
      out[(size_t)pos * DM + o] = acc[ot][r];
    }
  }
}

extern "C" void kernel_launch(void* const* d_in, const int* in_sizes, int n_in,
                              void* d_out, int out_size, void* d_ws, size_t ws_size,
                              hipStream_t stream) {
  const float* x       = (const float*)d_in[0];
  const float* Wi      = (const float*)d_in[1];
  const float* cw      = (const float*)d_in[2];
  const float* cb      = (const float*)d_in[3];
  const float* Wp      = (const float*)d_in[4];
  const float* Ds      = (const float*)d_in[5];
  const float* A_logs  = (const float*)d_in[6];
  const float* dt_bias = (const float*)d_in[7];
  const float* ln_g    = (const float*)d_in[8];
  const float* ln_b    = (const float*)d_in[9];
  const float* Wo      = (const float*)d_in[10];
  float* out = (float*)d_out;

  float* ws = (float*)d_ws;
  float* xi    = ws;                         // NPOS*DI f32
  float* zs    = xi + (size_t)NPOS * DI;     // NPOS*DI f32
  float* dtS   = zs + (size_t)NPOS * DI;     // KD*NB*LT*RK f32 (direction-ordered)
  float* Pend  = dtS + (size_t)NPOS * KD * RK;      // SEQ*NC*RK f32
  float* WpbF  = Pend + (size_t)SEQ * NC * RK;
  float* WibF  = WpbF + (size_t)NOP * DI / 2;
  float* WobF  = WibF + (size_t)NI * DM / 2;
  unsigned short* BsH  = (unsigned short*)(WobF + (size_t)DM * DI / 2); // KD*NPOS*NS bf16
  unsigned short* CsH  = BsH + (size_t)NPOS * KD * NS;
  unsigned short* xcb  = CsH + (size_t)NPOS * KD * NS;   // NPOS*DI bf16
  unsigned short* xcbT = xcb + (size_t)NPOS * DI;
  unsigned short* ybh  = xcbT + (size_t)NPOS * DI;        // KD*NPOS*DI bf16
  unsigned short* Send = ybh + (size_t)NPOS * KD * DI;    // SEQ*NC*ELEM bf16
  unsigned short* sub  = Send + (size_t)SEQ * NC * ELEM;  // NPOS*DI bf16
  unsigned short* Wpb = (unsigned short*)WpbF;
  unsigned short* Wib = (unsigned short*)WibF;
  unsigned short* Wob = (unsigned short*)WobF;

  k_wiprep<<<(NI * DM + 255) / 256, 256, 0, stream>>>(Wi, Wib);
  k_wprep<<<(NOP * DI + 255) / 256, 256, 0, stream>>>(Wp, Wpb);
  k_wob<<<(DM * DI + 255) / 256, 256, 0, stream>>>(Wo, Wob);
  k_inproj<<<NPOS / 64, 256, 0, stream>>>(x, Wib, xi, zs);
  k_conv<<<(NPOS * (DI / 2) + 255) / 256, 256, 0, stream>>>(xi, cw, cb, xcb, xcbT);
  k_xproj<<<NPOS / 16, 256, 0, stream>>>(xcb, Wpb, A_logs, dt_bias, dtS, BsH, CsH);
  k_scanAm<<<SEQ * NC, 384, 0, stream>>>(xcb, xcbT, dtS, BsH, A_logs, Send, Pend);
  k_scanB<<<SEQ * (ELEM / 512), 256, 0, stream>>>((unsigned int*)Send, Pend);
  k_scanM<<<SEQ * NC, 384, 0, stream>>>(xcb, xcbT, dtS, BsH, CsH, A_logs, Ds, Send, ybh);
  k_ln<<<NPOS / 4, 192, 0, stream>>>(ybh, zs, ln_g, ln_b, sub);
  k_oproj<<<NPOS / 64, 256, 0, stream>>>(sub, Wob, out);
}

// Round 15
// 185.483 us; speedup vs baseline: 1.5852x; 1.0917x over previous
//
#include <hip/hip_runtime.h>

// VMamba mixer forward, MI355X. bf16-MFMA in_proj / x_proj / chunk-scan /
// out_proj; bf16 prefix combine; direction-ordered streams; XOR-swizzled
// XT staging (bank-conflict-free transpose build).

constexpr int DM   = 96;     // D_MODEL
constexpr int DI   = 192;    // D_INNER
constexpr int RK   = 6;      // DT_RANK
constexpr int NS   = 32;     // D_STATE (== HEAD_D)
constexpr int KD   = 4;      // directions
constexpr int HW   = 56;
constexpr int LT   = 3136;   // L = 56*56
constexpr int NB   = 8;      // batch
constexpr int NPOS = NB * LT;   // 25088
constexpr int NC   = 49;     // chunks per sequence
constexpr int CH   = 64;     // chunk length (49*64 = 3136)
constexpr int SEQ = NB * KD; // 32 sequences
constexpr int ELEM = RK * NS * NS;  // 6144 state elements per sequence
constexpr int NO   = 280;    // x_proj outputs (4*70)
constexpr int NOP  = 288;    // padded to 18 MFMA n-tiles
constexpr int NI   = 384;    // in_proj outputs (2*DI)

typedef __attribute__((ext_vector_type(8))) __bf16 bf16x8;
typedef __attribute__((ext_vector_type(4))) float f32x4;
typedef __attribute__((ext_vector_type(2))) float f32x2;

__device__ __forceinline__ float siluf(float x) { return x / (1.f + __expf(-x)); }

__device__ __forceinline__ unsigned short f2bf(float f) {  // RNE, finite inputs
  unsigned int u = __float_as_uint(f);
  u = (u + 0x7fffu + ((u >> 16) & 1u)) >> 16;
  return (unsigned short)u;
}
__device__ __forceinline__ float bf2f(unsigned short h) {
  return __uint_as_float(((unsigned int)h) << 16);
}
__device__ __forceinline__ unsigned int pack2(float a, float b) {
  return (unsigned int)f2bf(a) | ((unsigned int)f2bf(b) << 16);
}
// XOR-swizzled XT column: row c, stream-step s. 16B-block granularity.
__device__ __forceinline__ int xts(int c, int s) {
  return (s & 7) + 8 * ((s >> 3) ^ ((c >> 1) & 7));
}
__device__ __forceinline__ int xtsb(int c, int sblk) {  // 8-short block index
  return (sblk ^ ((c >> 1) & 7)) * 8;
}

// ---------------- Kernel 0a: Wi -> bf16 ----------------
__global__ __launch_bounds__(256) void k_wiprep(const float* __restrict__ Wi,
                                                unsigned short* __restrict__ Wib) {
  int t = blockIdx.x * 256 + threadIdx.x;
  if (t >= NI * DM) return;
  Wib[t] = f2bf(Wi[t]);
}

// ---------------- Kernel 0b: Wp -> bf16, padded to 288 rows ----------------
__global__ __launch_bounds__(256) void k_wprep(const float* __restrict__ Wp,
                                               unsigned short* __restrict__ Wpb) {
  int t = blockIdx.x * 256 + threadIdx.x;
  if (t >= NOP * DI) return;
  int o = t / DI;
  Wpb[t] = (o < NO) ? f2bf(Wp[t]) : (unsigned short)0;
}

// ---------------- Kernel 0c: Wo -> bf16 (row-major, rows = outputs) ----------
__global__ __launch_bounds__(256) void k_wob(const float* __restrict__ Wo,
                                             unsigned short* __restrict__ Wob) {
  int t = blockIdx.x * 256 + threadIdx.x;
  if (t >= DM * DI) return;
  Wob[t] = f2bf(Wo[t]);
}

// ---------------- Kernel 1: in_proj via bf16 MFMA + split + silu(z) ----------
__global__ __launch_bounds__(256) void k_inproj(const float* __restrict__ x,
                                                const unsigned short* __restrict__ Wib,
                                                float* __restrict__ xi,
                                                float* __restrict__ zs) {
  int wid = threadIdx.x >> 6;
  int lane = threadIdx.x & 63;
  int pos0 = blockIdx.x * 64 + wid * 16;
  int lrow = lane & 15;
  int lgrp = lane >> 4;
  bf16x8 a[3];
  const float* arow = x + (size_t)(pos0 + lrow) * DM + lgrp * 8;
#pragma unroll
  for (int ks = 0; ks < 3; ks++) {
    f32x4 v0 = *reinterpret_cast<const f32x4*>(arow + ks * 32);
    f32x4 v1 = *reinterpret_cast<const f32x4*>(arow + ks * 32 + 4);
    union { unsigned short us[8]; bf16x8 v; } tmp;
#pragma unroll
    for (int j = 0; j < 4; j++) { tmp.us[j] = f2bf(v0[j]); tmp.us[4 + j] = f2bf(v1[j]); }
    a[ks] = tmp.v;
  }
  f32x4 acc[24];
#pragma unroll
  for (int t = 0; t < 24; t++) acc[t] = (f32x4){0.f, 0.f, 0.f, 0.f};
  const unsigned short* brow = Wib + (size_t)lrow * DM + lgrp * 8;
#pragma unroll
  for (int ks = 0; ks < 3; ks++) {
#pragma unroll
    for (int ot = 0; ot < 24; ot++) {
      bf16x8 bf = *reinterpret_cast<const bf16x8*>(brow + (size_t)ot * 16 * DM + ks * 32);
      acc[ot] = __builtin_amdgcn_mfma_f32_16x16x32_bf16(a[ks], bf, acc[ot], 0, 0, 0);
    }
  }
#pragma unroll
  for (int ot = 0; ot < 24; ot++) {
    int o = ot * 16 + lrow;
#pragma unroll
    for (int r = 0; r < 4; r++) {
      int pos = pos0 + lgrp * 4 + r;
      float v = acc[ot][r];
      if (o < DI) xi[(size_t)pos * DI + o] = v;
      else        zs[(size_t)pos * DI + (o - DI)] = siluf(v);
    }
  }
}

// ---------------- Kernel 2: depthwise conv -> bf16 (row-major + transposed) ----
__global__ __launch_bounds__(256) void k_conv(const float* __restrict__ xi,
                                              const float* __restrict__ cw,
                                              const float* __restrict__ cb,
                                              unsigned short* __restrict__ xcb,
                                              unsigned short* __restrict__ xcbT) {
  const int DH = DI / 2;
  int t = blockIdx.x * 256 + threadIdx.x;
  if (t >= NPOS * DH) return;
  int c2 = t % DH;
  int pos = t / DH;
  int p = pos % LT, b = pos / LT;
  int h = p / HW, w = p % HW;
  f32x2 acc = *reinterpret_cast<const f32x2*>(cb + c2 * 2);
  int base = b * LT * DI + c2 * 2;
#pragma unroll
  for (int dh = 0; dh < 3; dh++) {
    int hh = h + dh - 1;
    if (hh < 0 || hh >= HW) continue;
#pragma unroll
    for (int dw = 0; dw < 3; dw++) {
      int ww = w + dw - 1;
      if (ww < 0 || ww >= HW) continue;
      f32x2 wv = *reinterpret_cast<const f32x2*>(cw + (dh * 3 + dw) * DI + c2 * 2);
      f32x2 xv = *reinterpret_cast<const f32x2*>(xi + base + (hh * HW + ww) * DI);
      acc += wv * xv;
    }
  }
  unsigned int v = pack2(siluf(acc[0]), siluf(acc[1]));
  reinterpret_cast<unsigned int*>(xcb)[t] = v;
  int pt = w * HW + h;
  reinterpret_cast<unsigned int*>(xcbT)[(b * LT + pt) * DH + c2] = v;
}

// ---------------- Kernel 3: x_proj, K-split 4-wave MFMA -> dir-ordered streams --
__global__ __launch_bounds__(256) void k_xproj(const unsigned short* __restrict__ xcb,
                                               const unsigned short* __restrict__ Wpb,
                                               const float* __restrict__ A_logs,
                                               const float* __restrict__ dt_bias,
                                               float* __restrict__ dtS,
                                               unsigned short* __restrict__ BsH,
                                               unsigned short* __restrict__ CsH) {
  __shared__ float red[2][9][64][5];
  int tid = threadIdx.x;
  int wid = tid >> 6;
  int lane = tid & 63;
  int oh = wid >> 1, kh = wid & 1;
  int pos0 = blockIdx.x * 16;
  int lrow = lane & 15;
  int lgrp = lane >> 4;
  bf16x8 a[3];
  const unsigned short* arow = xcb + (size_t)(pos0 + lrow) * DI + kh * 96 + lgrp * 8;
#pragma unroll
  for (int ks = 0; ks < 3; ks++)
    a[ks] = *reinterpret_cast<const bf16x8*>(arow + ks * 32);
  f32x4 acc[9];
#pragma unroll
  for (int t = 0; t < 9; t++) acc[t] = (f32x4){0.f, 0.f, 0.f, 0.f};
  const unsigned short* brow = Wpb + (size_t)(oh * 144 + lrow) * DI + kh * 96 + lgrp * 8;
#pragma unroll
  for (int ks = 0; ks < 3; ks++) {
#pragma unroll
    for (int ot = 0; ot < 9; ot++) {
      bf16x8 bf = *reinterpret_cast<const bf16x8*>(brow + (size_t)ot * 16 * DI + ks * 32);
      acc[ot] = __builtin_amdgcn_mfma_f32_16x16x32_bf16(a[ks], bf, acc[ot], 0, 0, 0);
    }
  }
  if (kh == 1) {
#pragma unroll
    for (int ot = 0; ot < 9; ot++)
#pragma unroll
      for (int q = 0; q < 4; q++) red[oh][ot][lane][q] = acc[ot][q];
  }
  __syncthreads();
  if (kh == 1) return;
  int sp[4], spt[4], bb[4];
#pragma unroll
  for (int r = 0; r < 4; r++) {
    int pos = pos0 + lgrp * 4 + r;
    int b = pos / LT, p = pos - b * LT;
    int h = p / HW, w = p - h * HW;
    bb[r] = b; sp[r] = p; spt[r] = w * HW + h;
  }
#pragma unroll
  for (int ot = 0; ot < 9; ot++) {
    int o = (oh * 9 + ot) * 16 + lrow;
    if (o >= NO) continue;
    int k = o / 70, c = o % 70;
#pragma unroll
    for (int r = 0; r < 4; r++) {
      float v = acc[ot][r] + red[oh][ot][lane][r];
      int sidx = (k * NB + bb[r]) * LT + ((k & 1) ? spt[r] : sp[r]);
      if (c < RK) {
        float bias = dt_bias[k * RK + c];
        float s = v + bias;
        float dtv = (s > 20.f) ? s : log1pf(__expf(s));
        dtS[(size_t)sidx * RK + c] = dtv;
      } else if (c < RK + NS) {
        BsH[(size_t)sidx * NS + (c - RK)] = f2bf(v);
      } else {
        CsH[(size_t)sidx * NS + (c - RK - NS)] = f2bf(v);
      }
    }
  }
}

// ---------------- Kernel 4: MFMA states pass (S_end = X'.WB per chunk) --------
__global__ __launch_bounds__(384) void k_scanAm(const unsigned short* __restrict__ xcb,
                                                const unsigned short* __restrict__ xcbT,
                                                const float* __restrict__ dtS,
                                                const unsigned short* __restrict__ BsH,
                                                const float* __restrict__ A_logs,
                                                unsigned short* __restrict__ Send,
                                                float* __restrict__ Pend) {
  __shared__ unsigned short XT[DI][64];      // swizzled transpose [c][xts(c,s)]
  __shared__ unsigned short WB[6][32][72];   // per-wave: WBT[n][s]; later S[d][n]
  int bi = blockIdx.x;
  int chunk = bi % NC;
  int k = (bi / NC) & 3;
  int b = bi / (NC * KD);
  int seq = b * KD + k;
  int tid = threadIdx.x;
  int wid = tid >> 6;                        // r
  int lane = tid & 63;
  int lrow = lane & 15, lgrp = lane >> 4;
  int sb0 = (k * NB + b) * LT;
  int j0 = (k < 2) ? chunk * CH : (LT - 1 - chunk * CH);
  int dj = (k < 2) ? 1 : -1;
  const unsigned int* xs32 = reinterpret_cast<const unsigned int*>(
      ((k & 1) ? xcbT : xcb) + (size_t)b * LT * DI);
#pragma unroll
  for (int it = 0; it < 16; ++it) {
    int idx = it * 384 + tid;
    int s = idx / 96, cu = idx - s * 96;
    unsigned int v = xs32[(size_t)(j0 + s * dj) * 96 + cu];
    int col = xts(2 * cu, s);   // same for both rows (c>>1 == cu)
    XT[2 * cu][col] = (unsigned short)(v & 0xffff);
    XT[2 * cu + 1][col] = (unsigned short)(v >> 16);
  }
  int r = wid;
  float Ar = -__expf(A_logs[k * RK + r]);
  float dt_l = dtS[(size_t)(sb0 + j0 + lane * dj) * RK + r];
  float Lam = dt_l * Ar;
#pragma unroll
  for (int off = 1; off < 64; off <<= 1) {
    float tv = __shfl_up(Lam, off, 64);
    Lam += (lane >= off) ? tv : 0.f;
  }
  float Lam63 = __shfl(Lam, 63, 64);
  float w = __expf(Lam63 - Lam) * dt_l;
  const unsigned int* brow32 = reinterpret_cast<const unsigned int*>(
      BsH + (size_t)(sb0 + j0 + lane * dj) * NS);
#pragma unroll
  for (int i = 0; i < 16; i++) {
    unsigned int v = brow32[i];
    WB[wid][2 * i][lane]     = f2bf(w * bf2f((unsigned short)(v & 0xffff)));
    WB[wid][2 * i + 1][lane] = f2bf(w * bf2f((unsigned short)(v >> 16)));
  }
  __syncthreads();
  f32x4 acc[2][2];
#pragma unroll
  for (int i = 0; i < 2; i++)
#pragma unroll
    for (int j = 0; j < 2; j++) acc[i][j] = (f32x4){0.f, 0.f, 0.f, 0.f};
#pragma unroll
  for (int ks = 0; ks < 2; ks++) {
#pragma unroll
    for (int dtile = 0; dtile < 2; dtile++) {
      int R = r * 32 + dtile * 16 + lrow;
      bf16x8 av = *reinterpret_cast<const bf16x8*>(&XT[R][xtsb(R, ks * 4 + lgrp)]);
#pragma unroll
      for (int ntile = 0; ntile < 2; ntile++) {
        bf16x8 bv = *reinterpret_cast<const bf16x8*>(&WB[wid][ntile * 16 + lrow][ks * 32 + lgrp * 8]);
        acc[dtile][ntile] = __builtin_amdgcn_mfma_f32_16x16x32_bf16(av, bv, acc[dtile][ntile], 0, 0, 0);
      }
    }
  }
#pragma unroll
  for (int dtile = 0; dtile < 2; dtile++)
#pragma unroll
    for (int ntile = 0; ntile < 2; ntile++)
#pragma unroll
      for (int q = 0; q < 4; q++)
        WB[wid][dtile * 16 + lgrp * 4 + q][ntile * 16 + lrow] = f2bf(acc[dtile][ntile][q]);
  if (lane == 0) Pend[(seq * NC + chunk) * RK + r] = __expf(Lam63);
  __syncthreads();
  unsigned int* dst = reinterpret_cast<unsigned int*>(Send + (size_t)(seq * NC + chunk) * ELEM);
  int e0 = tid * 16;
  int rr = e0 >> 10, dd = (e0 >> 5) & 31, nn = e0 & 31;
  const unsigned int* src = reinterpret_cast<const unsigned int*>(&WB[rr][dd][nn]);
#pragma unroll
  for (int i = 0; i < 8; i++) dst[tid * 8 + i] = src[i];
}

// ---------------- Kernel 5: chunk-state combine (bf16 in-place excl. prefix) ----
__global__ __launch_bounds__(256) void k_scanB(unsigned int* __restrict__ Send32,
                                               const float* __restrict__ Pend) {
  const int EU = ELEM / 2;
  int bi = blockIdx.x;
  int seq = bi / (EU / 256);
  int u = (bi % (EU / 256)) * 256 + threadIdx.x;
  int r = u >> 9;
  float run0 = 0.f, run1 = 0.f;
  for (int c = 0; c < NC; c++) {
    size_t idx = (size_t)(seq * NC + c) * EU + u;
    unsigned int v = Send32[idx];
    float t0 = bf2f((unsigned short)(v & 0xffff));
    float t1 = bf2f((unsigned short)(v >> 16));
    Send32[idx] = pack2(run0, run1);
    float pe = Pend[(seq * NC + c) * RK + r];
    run0 = run0 * pe + t0;
    run1 = run1 * pe + t1;
  }
}

// ---------------- Kernel 6: MFMA chunk scan (Y = G'X + e^Λ C·Sinit + D·x) -----
__global__ __launch_bounds__(384) void k_scanM(const unsigned short* __restrict__ xcb,
                                               const unsigned short* __restrict__ xcbT,
                                               const float* __restrict__ dtS,
                                               const unsigned short* __restrict__ BsH,
                                               const unsigned short* __restrict__ CsH,
                                               const float* __restrict__ A_logs,
                                               const float* __restrict__ Ds,
                                               const unsigned short* __restrict__ Sinit,
                                               unsigned short* __restrict__ ybh) {
  __shared__ unsigned short XT[DI][64];      // swizzled transpose
  __shared__ unsigned short GB[6][32][72];
  int bi = blockIdx.x;
  int chunk = bi % NC;
  int k = (bi / NC) & 3;
  int b = bi / (NC * KD);
  int tid = threadIdx.x;
  int wid = tid >> 6;
  int lane = tid & 63;
  int lrow = lane & 15, lgrp = lane >> 4;
  int sb0 = (k * NB + b) * LT;
  int j0 = (k < 2) ? chunk * CH : (LT - 1 - chunk * CH);
  int dj = (k < 2) ? 1 : -1;
  const unsigned int* xs32 = reinterpret_cast<const unsigned int*>(
      ((k & 1) ? xcbT : xcb) + (size_t)b * LT * DI);
#pragma unroll
  for (int it = 0; it < 16; ++it) {
    int idx = it * 384 + tid;
    int s = idx / 96, cu = idx - s * 96;
    unsigned int v = xs32[(size_t)(j0 + s * dj) * 96 + cu];
    int col = xts(2 * cu, s);
    XT[2 * cu][col] = (unsigned short)(v & 0xffff);
    XT[2 * cu + 1][col] = (unsigned short)(v >> 16);
  }
  __syncthreads();
  int r = wid;
  float Ar = -__expf(A_logs[k * RK + r]);
  float dt_l = dtS[(size_t)(sb0 + j0 + lane * dj) * RK + r];
  float Lam = dt_l * Ar;
#pragma unroll
  for (int off = 1; off < 64; off <<= 1) {
    float tv = __shfl_up(Lam, off, 64);
    Lam += (lane >= off) ? tv : 0.f;
  }
  bf16x8 ct[4], bt[4];
#pragma unroll
  for (int i = 0; i < 4; i++) {
    int row = j0 + (i * 16 + lrow) * dj;
    ct[i] = *reinterpret_cast<const bf16x8*>(CsH + (size_t)(sb0 + row) * NS + lgrp * 8);
    bt[i] = *reinterpret_cast<const bf16x8*>(BsH + (size_t)(sb0 + row) * NS + lgrp * 8);
  }
  const unsigned short* sbase = Sinit + (size_t)((b * KD + k) * NC + chunk) * ELEM + r * NS * NS;
  bf16x8 sf[2];
#pragma unroll
  for (int djt = 0; djt < 2; djt++)
    sf[djt] = *reinterpret_cast<const bf16x8*>(sbase + (djt * 16 + lrow) * NS + lgrp * 8);
  f32x4 yi[4][2];
#pragma unroll
  for (int i = 0; i < 4; i++)
#pragma unroll
    for (int djt = 0; djt < 2; djt++)
      yi[i][djt] = __builtin_amdgcn_mfma_f32_16x16x32_bf16(ct[i], sf[djt],
                       (f32x4){0.f, 0.f, 0.f, 0.f}, 0, 0, 0);
  float dt_s4[4], Lam_s4[4];
#pragma unroll
  for (int j = 0; j < 4; j++) {
    dt_s4[j] = __shfl(dt_l, j * 16 + lrow, 64);
    Lam_s4[j] = __shfl(Lam, j * 16 + lrow, 64);
  }
  float Lam_t[4][4];
#pragma unroll
  for (int i = 0; i < 4; i++)
#pragma unroll
    for (int q = 0; q < 4; q++)
      Lam_t[i][q] = __shfl(Lam, i * 16 + lgrp * 4 + q, 64);
  f32x4 y[4][2];
#pragma unroll
  for (int i = 0; i < 4; i++)
#pragma unroll
    for (int djt = 0; djt < 2; djt++) y[i][djt] = (f32x4){0.f, 0.f, 0.f, 0.f};
#pragma unroll
  for (int h = 0; h < 2; h++) {
    int i0 = h * 2;
    int ncol = h ? 4 : 2;
#pragma unroll
    for (int it = 0; it < 2; it++) {
      int i = i0 + it;
#pragma unroll
      for (int j = 0; j < 4; j++) {
        if (j >= ncol) continue;
        f32x4 g = __builtin_amdgcn_mfma_f32_16x16x32_bf16(ct[i], bt[j],
                      (f32x4){0.f, 0.f, 0.f, 0.f}, 0, 0, 0);
        int s = j * 16 + lrow;
#pragma unroll
        for (int q = 0; q < 4; q++) {
          int t = i * 16 + lgrp * 4 + q;
          float wgt = (t >= s) ? __expf(Lam_t[i][q] - Lam_s4[j]) * dt_s4[j] : 0.f;
          GB[wid][it * 16 + lgrp * 4 + q][s] = f2bf(g[q] * wgt);
        }
      }
    }
    int nks = h ? 2 : 1;
#pragma unroll
    for (int it = 0; it < 2; it++) {
#pragma unroll
      for (int ks = 0; ks < nks; ks++) {
        bf16x8 ga = *reinterpret_cast<const bf16x8*>(&GB[wid][it * 16 + lrow][ks * 32 + lgrp * 8]);
#pragma unroll
        for (int djt = 0; djt < 2; djt++) {
          int R = r * 32 + djt * 16 + lrow;
          bf16x8 xb = *reinterpret_cast<const bf16x8*>(&XT[R][xtsb(R, ks * 4 + lgrp)]);
          y[i0 + it][djt] = __builtin_amdgcn_mfma_f32_16x16x32_bf16(ga, xb, y[i0 + it][djt], 0, 0, 0);
        }
      }
    }
  }
  float Dv[2];
#pragma unroll
  for (int djt = 0; djt < 2; djt++)
    Dv[djt] = Ds[(k * RK + r) * NS + djt * 16 + lrow];
  unsigned short* yb = ybh + (size_t)(k * NB + b) * LT * DI;
#pragma unroll
  for (int i = 0; i < 4; i++) {
#pragma unroll
    for (int q = 0; q < 4; q++) {
      int t = i * 16 + lgrp * 4 + q;
      float eL = __expf(Lam_t[i][q]);
      int jrow = j0 + t * dj;
#pragma unroll
      for (int djt = 0; djt < 2; djt++) {
        int R = r * 32 + djt * 16 + lrow;
        float xv = bf2f(XT[R][xts(R, t)]);
        float val = y[i][djt][q] + eL * yi[i][djt][q] + Dv[djt] * xv;
        yb[(size_t)jrow * DI + R] = f2bf(val);
      }
    }
  }
}

// ---------------- Kernel 7a: merge + LN + gelu + *silu(z) -> bf16 su ----------
__global__ __launch_bounds__(192) void k_ln(const unsigned short* __restrict__ ybh,
                                            const float* __restrict__ zs,
                                            const float* __restrict__ ln_g,
                                            const float* __restrict__ ln_b,
                                            unsigned short* __restrict__ sub) {
  const int PP = 4;
  int pos0 = blockIdx.x * PP;
  int b = pos0 / LT, p0 = pos0 % LT;
  int h0 = p0 / HW, w0 = p0 % HW;
  int pt0 = w0 * HW + h0;
  int tid = threadIdx.x;
  float v[PP], s1[PP], s2[PP];
#pragma unroll
  for (int q = 0; q < PP; q++) {
    int p = p0 + q;
    int pt = pt0 + q * HW;
    float acc = bf2f(ybh[((size_t)(0 * NB + b) * LT + p) * DI + tid])
              + bf2f(ybh[((size_t)(1 * NB + b) * LT + pt) * DI + tid])
              + bf2f(ybh[((size_t)(2 * NB + b) * LT + p) * DI + tid])
              + bf2f(ybh[((size_t)(3 * NB + b) * LT + pt) * DI + tid]);
    v[q] = acc; s1[q] = acc; s2[q] = acc * acc;
  }
#pragma unroll
  for (int off = 32; off; off >>= 1) {
#pragma unroll
    for (int q = 0; q < PP; q++) {
      s1[q] += __shfl_down(s1[q], off, 64);
      s2[q] += __shfl_down(s2[q], off, 64);
    }
  }
  __shared__ float rs1[3][PP], rs2[3][PP];
  int wave = tid >> 6, lane = tid & 63;
  if (lane == 0) {
#pragma unroll
    for (int q = 0; q < PP; q++) { rs1[wave][q] = s1[q]; rs2[wave][q] = s2[q]; }
  }
  __syncthreads();
  float g = ln_g[tid], be = ln_b[tid];
#pragma unroll
  for (int q = 0; q < PP; q++) {
    float mean = (rs1[0][q] + rs1[1][q] + rs1[2][q]) * (1.f / 192.f);
    float var = (rs2[0][q] + rs2[1][q] + rs2[2][q]) * (1.f / 192.f) - mean * mean;
    float rstd = rsqrtf(var + 1e-5f);
    float t = (v[q] - mean) * rstd * g + be;
    float ge = 0.5f * t * (1.f + erff(t * 0.70710678118f));
    sub[(size_t)(pos0 + q) * DI + tid] = f2bf(ge * zs[(size_t)(pos0 + q) * DI + tid]);
  }
}

// ---------------- Kernel 7b: out_proj via bf16 MFMA ----------------
__global__ __launch_bounds__(256) void k_oproj(const unsigned short* __restrict__ sub,
                                               const unsigned short* __restrict__ Wob,
                                               float* __restrict__ out) {
  int wid = threadIdx.x >> 6;
  int lane = threadIdx.x & 63;
  int pos0 = blockIdx.x * 64 + wid * 16;
  int lrow = lane & 15;
  int lgrp = lane >> 4;
  bf16x8 a[6];
  const unsigned short* arow = sub + (size_t)(pos0 + lrow) * DI + lgrp * 8;
#pragma unroll
  for (int ks = 0; ks < 6; ks++)
    a[ks] = *reinterpret_cast<const bf16x8*>(arow + ks * 32);
  f32x4 acc[6];
#pragma unroll
  for (int t = 0; t < 6; t++) acc[t] = (f32x4){0.f, 0.f, 0.f, 0.f};
  const unsigned short* brow = Wob + (size_t)lrow * DI + lgrp * 8;
#pragma unroll
  for (int ks = 0; ks < 6; ks++) {
#pragma unroll
    for (int ot = 0; ot < 6; ot++) {
      bf16x8 bf = *reinterpret_cast<const bf16x8*>(brow + (size_t)ot * 16 * DI + ks * 32);
      acc[ot] = __builtin_amdgcn_mfma_f32_16x16x32_bf16(a[ks], bf, acc[ot], 0, 0, 0);
    }
  }
#pragma unroll
  for (int ot = 0; ot < 6; ot++) {
    int o = ot * 16 + lrow;
#pragma unroll
    for (int r = 0; r < 4; r++) {
      int pos = pos0 + lgrp * 4 + r;
      out[(size_t)pos * DM + o] = acc[ot][r];
    }
  }
}

extern "C" void kernel_launch(void* const* d_in, const int* in_sizes, int n_in,
                              void* d_out, int out_size, void* d_ws, size_t ws_size,
                              hipStream_t stream) {
  const float* x       = (const float*)d_in[0];
  const float* Wi      = (const float*)d_in[1];
  const float* cw      = (const float*)d_in[2];
  const float* cb      = (const float*)d_in[3];
  const float* Wp      = (const float*)d_in[4];
  const float* Ds      = (const float*)d_in[5];
  const float* A_logs  = (const float*)d_in[6];
  const float* dt_bias = (const float*)d_in[7];
  const float* ln_g    = (const float*)d_in[8];
  const float* ln_b    = (const float*)d_in[9];
  const float* Wo      = (const float*)d_in[10];
  float* out = (float*)d_out;

  float* ws = (float*)d_ws;
  float* xi    = ws;                         // NPOS*DI f32
  float* zs    = xi + (size_t)NPOS * DI;     // NPOS*DI f32
  float* dtS   = zs + (size_t)NPOS * DI;     // KD*NB*LT*RK f32 (direction-ordered)
  float* Pend  = dtS + (size_t)NPOS * KD * RK;      // SEQ*NC*RK f32
  float* WpbF  = Pend + (size_t)SEQ * NC * RK;
  float* WibF  = WpbF + (size_t)NOP * DI / 2;
  float* WobF  = WibF + (size_t)NI * DM / 2;
  unsigned short* BsH  = (unsigned short*)(WobF + (size_t)DM * DI / 2); // KD*NPOS*NS bf16
  unsigned short* CsH  = BsH + (size_t)NPOS * KD * NS;
  unsigned short* xcb  = CsH + (size_t)NPOS * KD * NS;   // NPOS*DI bf16
  unsigned short* xcbT = xcb + (size_t)NPOS * DI;
  unsigned short* ybh  = xcbT + (size_t)NPOS * DI;        // KD*NPOS*DI bf16
  unsigned short* Send = ybh + (size_t)NPOS * KD * DI;    // SEQ*NC*ELEM bf16
  unsigned short* sub  = Send + (size_t)SEQ * NC * ELEM;  // NPOS*DI bf16
  unsigned short* Wpb = (unsigned short*)WpbF;
  unsigned short* Wib = (unsigned short*)WibF;
  unsigned short* Wob = (unsigned short*)WobF;

  k_wiprep<<<(NI * DM + 255) / 256, 256, 0, stream>>>(Wi, Wib);
  k_wprep<<<(NOP * DI + 255) / 256, 256, 0, stream>>>(Wp, Wpb);
  k_wob<<<(DM * DI + 255) / 256, 256, 0, stream>>>(Wo, Wob);
  k_inproj<<<NPOS / 64, 256, 0, stream>>>(x, Wib, xi, zs);
  k_conv<<<(NPOS * (DI / 2) + 255) / 256, 256, 0, stream>>>(xi, cw, cb, xcb, xcbT);
  k_xproj<<<NPOS / 16, 256, 0, stream>>>(xcb, Wpb, A_logs, dt_bias, dtS, BsH, CsH);
  k_scanAm<<<SEQ * NC, 384, 0, stream>>>(xcb, xcbT, dtS, BsH, A_logs, Send, Pend);
  k_scanB<<<SEQ * (ELEM / 512), 256, 0, stream>>>((unsigned int*)Send, Pend);
  k_scanM<<<SEQ * NC, 384, 0, stream>>>(xcb, xcbT, dtS, BsH, CsH, A_logs, Ds, Send, ybh);
  k_ln<<<NPOS / 4, 192, 0, stream>>>(ybh, zs, ln_g, ln_b, sub);
  k_oproj<<<NPOS / 64, 256, 0, stream>>>(sub, Wob, out);
}

// Round 16
// 176.325 us; speedup vs baseline: 1.6676x; 1.0519x over previous
//
#include <hip/hip_runtime.h>

// VMamba mixer forward, MI355X. bf16-MFMA in_proj / x_proj / chunk-scan /
// out_proj; bf16 prefix combine; direction-ordered streams; XOR-swizzled
// XT staging; LDS out-tile + coalesced stream stores in x_proj.

constexpr int DM   = 96;     // D_MODEL
constexpr int DI   = 192;    // D_INNER
constexpr int RK   = 6;      // DT_RANK
constexpr int NS   = 32;     // D_STATE (== HEAD_D)
constexpr int KD   = 4;      // directions
constexpr int HW   = 56;
constexpr int LT   = 3136;   // L = 56*56
constexpr int NB   = 8;      // batch
constexpr int NPOS = NB * LT;   // 25088
constexpr int NC   = 49;     // chunks per sequence
constexpr int CH   = 64;     // chunk length (49*64 = 3136)
constexpr int SEQ = NB * KD; // 32 sequences
constexpr int ELEM = RK * NS * NS;  // 6144 state elements per sequence
constexpr int NO   = 280;    // x_proj outputs (4*70)
constexpr int NOP  = 288;    // padded to 18 MFMA n-tiles
constexpr int NI   = 384;    // in_proj outputs (2*DI)

typedef __attribute__((ext_vector_type(8))) __bf16 bf16x8;
typedef __attribute__((ext_vector_type(4))) float f32x4;
typedef __attribute__((ext_vector_type(2))) float f32x2;

__device__ __forceinline__ float siluf(float x) { return x / (1.f + __expf(-x)); }

__device__ __forceinline__ unsigned short f2bf(float f) {  // RNE, finite inputs
  unsigned int u = __float_as_uint(f);
  u = (u + 0x7fffu + ((u >> 16) & 1u)) >> 16;
  return (unsigned short)u;
}
__device__ __forceinline__ float bf2f(unsigned short h) {
  return __uint_as_float(((unsigned int)h) << 16);
}
__device__ __forceinline__ unsigned int pack2(float a, float b) {
  return (unsigned int)f2bf(a) | ((unsigned int)f2bf(b) << 16);
}
// XOR-swizzled XT column: row c, stream-step s. 16B-block granularity.
__device__ __forceinline__ int xts(int c, int s) {
  return (s & 7) + 8 * ((s >> 3) ^ ((c >> 1) & 7));
}
__device__ __forceinline__ int xtsb(int c, int sblk) {  // 8-short block index
  return (sblk ^ ((c >> 1) & 7)) * 8;
}

// ---------------- Kernel 0a: Wi -> bf16 ----------------
__global__ __launch_bounds__(256) void k_wiprep(const float* __restrict__ Wi,
                                                unsigned short* __restrict__ Wib) {
  int t = blockIdx.x * 256 + threadIdx.x;
  if (t >= NI * DM) return;
  Wib[t] = f2bf(Wi[t]);
}

// ---------------- Kernel 0b: Wp -> bf16, padded to 288 rows ----------------
__global__ __launch_bounds__(256) void k_wprep(const float* __restrict__ Wp,
                                               unsigned short* __restrict__ Wpb) {
  int t = blockIdx.x * 256 + threadIdx.x;
  if (t >= NOP * DI) return;
  int o = t / DI;
  Wpb[t] = (o < NO) ? f2bf(Wp[t]) : (unsigned short)0;
}

// ---------------- Kernel 0c: Wo -> bf16 (row-major, rows = outputs) ----------
__global__ __launch_bounds__(256) void k_wob(const float* __restrict__ Wo,
                                             unsigned short* __restrict__ Wob) {
  int t = blockIdx.x * 256 + threadIdx.x;
  if (t >= DM * DI) return;
  Wob[t] = f2bf(Wo[t]);
}

// ---------------- Kernel 1: in_proj via bf16 MFMA + split + silu(z) ----------
__global__ __launch_bounds__(256) void k_inproj(const float* __restrict__ x,
                                                const unsigned short* __restrict__ Wib,
                                                float* __restrict__ xi,
                                                float* __restrict__ zs) {
  int wid = threadIdx.x >> 6;
  int lane = threadIdx.x & 63;
  int pos0 = blockIdx.x * 64 + wid * 16;
  int lrow = lane & 15;
  int lgrp = lane >> 4;
  bf16x8 a[3];
  const float* arow = x + (size_t)(pos0 + lrow) * DM + lgrp * 8;
#pragma unroll
  for (int ks = 0; ks < 3; ks++) {
    f32x4 v0 = *reinterpret_cast<const f32x4*>(arow + ks * 32);
    f32x4 v1 = *reinterpret_cast<const f32x4*>(arow + ks * 32 + 4);
    union { unsigned short us[8]; bf16x8 v; } tmp;
#pragma unroll
    for (int j = 0; j < 4; j++) { tmp.us[j] = f2bf(v0[j]); tmp.us[4 + j] = f2bf(v1[j]); }
    a[ks] = tmp.v;
  }
  f32x4 acc[24];
#pragma unroll
  for (int t = 0; t < 24; t++) acc[t] = (f32x4){0.f, 0.f, 0.f, 0.f};
  const unsigned short* brow = Wib + (size_t)lrow * DM + lgrp * 8;
#pragma unroll
  for (int ks = 0; ks < 3; ks++) {
#pragma unroll
    for (int ot = 0; ot < 24; ot++) {
      bf16x8 bf = *reinterpret_cast<const bf16x8*>(brow + (size_t)ot * 16 * DM + ks * 32);
      acc[ot] = __builtin_amdgcn_mfma_f32_16x16x32_bf16(a[ks], bf, acc[ot], 0, 0, 0);
    }
  }
#pragma unroll
  for (int ot = 0; ot < 24; ot++) {
    int o = ot * 16 + lrow;
#pragma unroll
    for (int r = 0; r < 4; r++) {
      int pos = pos0 + lgrp * 4 + r;
      float v = acc[ot][r];
      if (o < DI) xi[(size_t)pos * DI + o] = v;
      else        zs[(size_t)pos * DI + (o - DI)] = siluf(v);
    }
  }
}

// ---------------- Kernel 2: depthwise conv -> bf16 (row-major + transposed) ----
__global__ __launch_bounds__(256) void k_conv(const float* __restrict__ xi,
                                              const float* __restrict__ cw,
                                              const float* __restrict__ cb,
                                              unsigned short* __restrict__ xcb,
                                              unsigned short* __restrict__ xcbT) {
  const int DH = DI / 2;
  int t = blockIdx.x * 256 + threadIdx.x;
  if (t >= NPOS * DH) return;
  int c2 = t % DH;
  int pos = t / DH;
  int p = pos % LT, b = pos / LT;
  int h = p / HW, w = p % HW;
  f32x2 acc = *reinterpret_cast<const f32x2*>(cb + c2 * 2);
  int base = b * LT * DI + c2 * 2;
#pragma unroll
  for (int dh = 0; dh < 3; dh++) {
    int hh = h + dh - 1;
    if (hh < 0 || hh >= HW) continue;
#pragma unroll
    for (int dw = 0; dw < 3; dw++) {
      int ww = w + dw - 1;
      if (ww < 0 || ww >= HW) continue;
      f32x2 wv = *reinterpret_cast<const f32x2*>(cw + (dh * 3 + dw) * DI + c2 * 2);
      f32x2 xv = *reinterpret_cast<const f32x2*>(xi + base + (hh * HW + ww) * DI);
      acc += wv * xv;
    }
  }
  unsigned int v = pack2(siluf(acc[0]), siluf(acc[1]));
  reinterpret_cast<unsigned int*>(xcb)[t] = v;
  int pt = w * HW + h;
  reinterpret_cast<unsigned int*>(xcbT)[(b * LT + pt) * DH + c2] = v;
}

// ---------------- Kernel 3: x_proj, K-split 4-wave MFMA, LDS out-tile --------
// Block = 256 thr / 16 positions. Wave w: oh = w>>1 (9 n-tiles), kh = w&1 (3 ks).
// Epilogue: outT[288][17] in LDS, then cooperative coalesced stream stores.
__global__ __launch_bounds__(256) void k_xproj(const unsigned short* __restrict__ xcb,
                                               const unsigned short* __restrict__ Wpb,
                                               const float* __restrict__ dt_bias,
                                               float* __restrict__ dtS,
                                               unsigned short* __restrict__ BsH,
                                               unsigned short* __restrict__ CsH) {
  __shared__ float outT[NOP][17];  // [output o][position] (pad 17 -> <=2-way banks)
  int tid = threadIdx.x;
  int wid = tid >> 6;
  int lane = tid & 63;
  int oh = wid >> 1, kh = wid & 1;
  int pos0 = blockIdx.x * 16;
  int lrow = lane & 15;
  int lgrp = lane >> 4;
  bf16x8 a[3];
  const unsigned short* arow = xcb + (size_t)(pos0 + lrow) * DI + kh * 96 + lgrp * 8;
#pragma unroll
  for (int ks = 0; ks < 3; ks++)
    a[ks] = *reinterpret_cast<const bf16x8*>(arow + ks * 32);
  f32x4 acc[9];
#pragma unroll
  for (int t = 0; t < 9; t++) acc[t] = (f32x4){0.f, 0.f, 0.f, 0.f};
  const unsigned short* brow = Wpb + (size_t)(oh * 144 + lrow) * DI + kh * 96 + lgrp * 8;
#pragma unroll
  for (int ks = 0; ks < 3; ks++) {
#pragma unroll
    for (int ot = 0; ot < 9; ot++) {
      bf16x8 bf = *reinterpret_cast<const bf16x8*>(brow + (size_t)ot * 16 * DI + ks * 32);
      acc[ot] = __builtin_amdgcn_mfma_f32_16x16x32_bf16(a[ks], bf, acc[ot], 0, 0, 0);
    }
  }
  if (kh == 1) {
#pragma unroll
    for (int ot = 0; ot < 9; ot++)
#pragma unroll
      for (int q = 0; q < 4; q++)
        outT[oh * 144 + ot * 16 + lrow][lgrp * 4 + q] = acc[ot][q];
  }
  __syncthreads();
  if (kh == 0) {
#pragma unroll
    for (int ot = 0; ot < 9; ot++)
#pragma unroll
      for (int q = 0; q < 4; q++) {
        int o = oh * 144 + ot * 16 + lrow;
        outT[o][lgrp * 4 + q] += acc[ot][q];
      }
  }
  __syncthreads();
  // Phase 4: cooperative stream stores.
  int b = pos0 / LT;
  int p0 = pos0 - b * LT;
  int posl = tid >> 4, cu = tid & 15;
  int p = p0 + posl;
  int h = p / HW, w2 = p - h * HW;
  int pt = w2 * HW + h;
#pragma unroll
  for (int k = 0; k < KD; k++) {
    int sidx = (k * NB + b) * LT + ((k & 1) ? pt : p);
    int rowB = k * 70 + RK;
    int rowC = k * 70 + RK + NS;
    unsigned int vb = pack2(outT[rowB + 2 * cu][posl], outT[rowB + 2 * cu + 1][posl]);
    reinterpret_cast<unsigned int*>(BsH)[(size_t)sidx * 16 + cu] = vb;
    unsigned int vc = pack2(outT[rowC + 2 * cu][posl], outT[rowC + 2 * cu + 1][posl]);
    reinterpret_cast<unsigned int*>(CsH)[(size_t)sidx * 16 + cu] = vc;
  }
#pragma unroll
  for (int i = 0; i < 2; i++) {
    int idx = i * 256 + tid;
    if (idx < 16 * KD * RK) {
      int pp = idx / (KD * RK), rem = idx % (KD * RK);
      int k = rem / RK, c = rem % RK;
      int pg = p0 + pp;
      int hh = pg / HW, ww = pg - hh * HW;
      int ptg = ww * HW + hh;
      int sidx = (k * NB + b) * LT + ((k & 1) ? ptg : pg);
      float v = outT[k * 70 + c][pp] + dt_bias[k * RK + c];
      float dtv = (v > 20.f) ? v : log1pf(__expf(v));
      dtS[(size_t)sidx * RK + c] = dtv;
    }
  }
}

// ---------------- Kernel 4: MFMA states pass (S_end = X'.WB per chunk) --------
__global__ __launch_bounds__(384) void k_scanAm(const unsigned short* __restrict__ xcb,
                                                const unsigned short* __restrict__ xcbT,
                                                const float* __restrict__ dtS,
                                                const unsigned short* __restrict__ BsH,
                                                const float* __restrict__ A_logs,
                                                unsigned short* __restrict__ Send,
                                                float* __restrict__ Pend) {
  __shared__ unsigned short XT[DI][64];      // swizzled transpose [c][xts(c,s)]
  __shared__ unsigned short WB[6][32][72];   // per-wave: WBT[n][s]; later S[d][n]
  int bi = blockIdx.x;
  int chunk = bi % NC;
  int k = (bi / NC) & 3;
  int b = bi / (NC * KD);
  int seq = b * KD + k;
  int tid = threadIdx.x;
  int wid = tid >> 6;                        // r
  int lane = tid & 63;
  int lrow = lane & 15, lgrp = lane >> 4;
  int sb0 = (k * NB + b) * LT;
  int j0 = (k < 2) ? chunk * CH : (LT - 1 - chunk * CH);
  int dj = (k < 2) ? 1 : -1;
  const unsigned int* xs32 = reinterpret_cast<const unsigned int*>(
      ((k & 1) ? xcbT : xcb) + (size_t)b * LT * DI);
#pragma unroll
  for (int it = 0; it < 16; ++it) {
    int idx = it * 384 + tid;
    int s = idx / 96, cu = idx - s * 96;
    unsigned int v = xs32[(size_t)(j0 + s * dj) * 96 + cu];
    int col = xts(2 * cu, s);   // same for both rows (c>>1 == cu)
    XT[2 * cu][col] = (unsigned short)(v & 0xffff);
    XT[2 * cu + 1][col] = (unsigned short)(v >> 16);
  }
  int r = wid;
  float Ar = -__expf(A_logs[k * RK + r]);
  float dt_l = dtS[(size_t)(sb0 + j0 + lane * dj) * RK + r];
  float Lam = dt_l * Ar;
#pragma unroll
  for (int off = 1; off < 64; off <<= 1) {
    float tv = __shfl_up(Lam, off, 64);
    Lam += (lane >= off) ? tv : 0.f;
  }
  float Lam63 = __shfl(Lam, 63, 64);
  float w = __expf(Lam63 - Lam) * dt_l;
  const unsigned int* brow32 = reinterpret_cast<const unsigned int*>(
      BsH + (size_t)(sb0 + j0 + lane * dj) * NS);
#pragma unroll
  for (int i = 0; i < 16; i++) {
    unsigned int v = brow32[i];
    WB[wid][2 * i][lane]     = f2bf(w * bf2f((unsigned short)(v & 0xffff)));
    WB[wid][2 * i + 1][lane] = f2bf(w * bf2f((unsigned short)(v >> 16)));
  }
  __syncthreads();
  f32x4 acc[2][2];
#pragma unroll
  for (int i = 0; i < 2; i++)
#pragma unroll
    for (int j = 0; j < 2; j++) acc[i][j] = (f32x4){0.f, 0.f, 0.f, 0.f};
#pragma unroll
  for (int ks = 0; ks < 2; ks++) {
#pragma unroll
    for (int dtile = 0; dtile < 2; dtile++) {
      int R = r * 32 + dtile * 16 + lrow;
      bf16x8 av = *reinterpret_cast<const bf16x8*>(&XT[R][xtsb(R, ks * 4 + lgrp)]);
#pragma unroll
      for (int ntile = 0; ntile < 2; ntile++) {
        bf16x8 bv = *reinterpret_cast<const bf16x8*>(&WB[wid][ntile * 16 + lrow][ks * 32 + lgrp * 8]);
        acc[dtile][ntile] = __builtin_amdgcn_mfma_f32_16x16x32_bf16(av, bv, acc[dtile][ntile], 0, 0, 0);
      }
    }
  }
#pragma unroll
  for (int dtile = 0; dtile < 2; dtile++)
#pragma unroll
    for (int ntile = 0; ntile < 2; ntile++)
#pragma unroll
      for (int q = 0; q < 4; q++)
        WB[wid][dtile * 16 + lgrp * 4 + q][ntile * 16 + lrow] = f2bf(acc[dtile][ntile][q]);
  if (lane == 0) Pend[(seq * NC + chunk) * RK + r] = __expf(Lam63);
  __syncthreads();
  unsigned int* dst = reinterpret_cast<unsigned int*>(Send + (size_t)(seq * NC + chunk) * ELEM);
  int e0 = tid * 16;
  int rr = e0 >> 10, dd = (e0 >> 5) & 31, nn = e0 & 31;
  const unsigned int* src = reinterpret_cast<const unsigned int*>(&WB[rr][dd][nn]);
#pragma unroll
  for (int i = 0; i < 8; i++) dst[tid * 8 + i] = src[i];
}

// ---------------- Kernel 5: chunk-state combine (bf16 in-place excl. prefix) ----
__global__ __launch_bounds__(256) void k_scanB(unsigned int* __restrict__ Send32,
                                               const float* __restrict__ Pend) {
  const int EU = ELEM / 2;
  int bi = blockIdx.x;
  int seq = bi / (EU / 256);
  int u = (bi % (EU / 256)) * 256 + threadIdx.x;
  int r = u >> 9;
  float run0 = 0.f, run1 = 0.f;
  for (int c = 0; c < NC; c++) {
    size_t idx = (size_t)(seq * NC + c) * EU + u;
    unsigned int v = Send32[idx];
    float t0 = bf2f((unsigned short)(v & 0xffff));
    float t1 = bf2f((unsigned short)(v >> 16));
    Send32[idx] = pack2(run0, run1);
    float pe = Pend[(seq * NC + c) * RK + r];
    run0 = run0 * pe + t0;
    run1 = run1 * pe + t1;
  }
}

// ---------------- Kernel 6: MFMA chunk scan (Y = G'X + e^Λ C·Sinit + D·x) -----
__global__ __launch_bounds__(384) void k_scanM(const unsigned short* __restrict__ xcb,
                                               const unsigned short* __restrict__ xcbT,
                                               const float* __restrict__ dtS,
                                               const unsigned short* __restrict__ BsH,
                                               const unsigned short* __restrict__ CsH,
                                               const float* __restrict__ A_logs,
                                               const float* __restrict__ Ds,
                                               const unsigned short* __restrict__ Sinit,
                                               unsigned short* __restrict__ ybh) {
  __shared__ unsigned short XT[DI][64];      // swizzled transpose
  __shared__ unsigned short GB[6][32][72];
  int bi = blockIdx.x;
  int chunk = bi % NC;
  int k = (bi / NC) & 3;
  int b = bi / (NC * KD);
  int tid = threadIdx.x;
  int wid = tid >> 6;
  int lane = tid & 63;
  int lrow = lane & 15, lgrp = lane >> 4;
  int sb0 = (k * NB + b) * LT;
  int j0 = (k < 2) ? chunk * CH : (LT - 1 - chunk * CH);
  int dj = (k < 2) ? 1 : -1;
  const unsigned int* xs32 = reinterpret_cast<const unsigned int*>(
      ((k & 1) ? xcbT : xcb) + (size_t)b * LT * DI);
#pragma unroll
  for (int it = 0; it < 16; ++it) {
    int idx = it * 384 + tid;
    int s = idx / 96, cu = idx - s * 96;
    unsigned int v = xs32[(size_t)(j0 + s * dj) * 96 + cu];
    int col = xts(2 * cu, s);
    XT[2 * cu][col] = (unsigned short)(v & 0xffff);
    XT[2 * cu + 1][col] = (unsigned short)(v >> 16);
  }
  __syncthreads();
  int r = wid;
  float Ar = -__expf(A_logs[k * RK + r]);
  float dt_l = dtS[(size_t)(sb0 + j0 + lane * dj) * RK + r];
  float Lam = dt_l * Ar;
#pragma unroll
  for (int off = 1; off < 64; off <<= 1) {
    float tv = __shfl_up(Lam, off, 64);
    Lam += (lane >= off) ? tv : 0.f;
  }
  bf16x8 ct[4], bt[4];
#pragma unroll
  for (int i = 0; i < 4; i++) {
    int row = j0 + (i * 16 + lrow) * dj;
    ct[i] = *reinterpret_cast<const bf16x8*>(CsH + (size_t)(sb0 + row) * NS + lgrp * 8);
    bt[i] = *reinterpret_cast<const bf16x8*>(BsH + (size_t)(sb0 + row) * NS + lgrp * 8);
  }
  const unsigned short* sbase = Sinit + (size_t)((b * KD + k) * NC + chunk) * ELEM + r * NS * NS;
  bf16x8 sf[2];
#pragma unroll
  for (int djt = 0; djt < 2; djt++)
    sf[djt] = *reinterpret_cast<const bf16x8*>(sbase + (djt * 16 + lrow) * NS + lgrp * 8);
  f32x4 yi[4][2];
#pragma unroll
  for (int i = 0; i < 4; i++)
#pragma unroll
    for (int djt = 0; djt < 2; djt++)
      yi[i][djt] = __builtin_amdgcn_mfma_f32_16x16x32_bf16(ct[i], sf[djt],
                       (f32x4){0.f, 0.f, 0.f, 0.f}, 0, 0, 0);
  float dt_s4[4], Lam_s4[4];
#pragma unroll
  for (int j = 0; j < 4; j++) {
    dt_s4[j] = __shfl(dt_l, j * 16 + lrow, 64);
    Lam_s4[j] = __shfl(Lam, j * 16 + lrow, 64);
  }
  float Lam_t[4][4];
#pragma unroll
  for (int i = 0; i < 4; i++)
#pragma unroll
    for (int q = 0; q < 4; q++)
      Lam_t[i][q] = __shfl(Lam, i * 16 + lgrp * 4 + q, 64);
  f32x4 y[4][2];
#pragma unroll
  for (int i = 0; i < 4; i++)
#pragma unroll
    for (int djt = 0; djt < 2; djt++) y[i][djt] = (f32x4){0.f, 0.f, 0.f, 0.f};
#pragma unroll
  for (int h = 0; h < 2; h++) {
    int i0 = h * 2;
    int ncol = h ? 4 : 2;
#pragma unroll
    for (int it = 0; it < 2; it++) {
      int i = i0 + it;
#pragma unroll
      for (int j = 0; j < 4; j++) {
        if (j >= ncol) continue;
        f32x4 g = __builtin_amdgcn_mfma_f32_16x16x32_bf16(ct[i], bt[j],
                      (f32x4){0.f, 0.f, 0.f, 0.f}, 0, 0, 0);
        int s = j * 16 + lrow;
#pragma unroll
        for (int q = 0; q < 4; q++) {
          int t = i * 16 + lgrp * 4 + q;
          float wgt = (t >= s) ? __expf(Lam_t[i][q] - Lam_s4[j]) * dt_s4[j] : 0.f;
          GB[wid][it * 16 + lgrp * 4 + q][s] = f2bf(g[q] * wgt);
        }
      }
    }
    int nks = h ? 2 : 1;
#pragma unroll
    for (int it = 0; it < 2; it++) {
#pragma unroll
      for (int ks = 0; ks < nks; ks++) {
        bf16x8 ga = *reinterpret_cast<const bf16x8*>(&GB[wid][it * 16 + lrow][ks * 32 + lgrp * 8]);
#pragma unroll
        for (int djt = 0; djt < 2; djt++) {
          int R = r * 32 + djt * 16 + lrow;
          bf16x8 xb = *reinterpret_cast<const bf16x8*>(&XT[R][xtsb(R, ks * 4 + lgrp)]);
          y[i0 + it][djt] = __builtin_amdgcn_mfma_f32_16x16x32_bf16(ga, xb, y[i0 + it][djt], 0, 0, 0);
        }
      }
    }
  }
  float Dv[2];
#pragma unroll
  for (int djt = 0; djt < 2; djt++)
    Dv[djt] = Ds[(k * RK + r) * NS + djt * 16 + lrow];
  unsigned short* yb = ybh + (size_t)(k * NB + b) * LT * DI;
#pragma unroll
  for (int i = 0; i < 4; i++) {
#pragma unroll
    for (int q = 0; q < 4; q++) {
      int t = i * 16 + lgrp * 4 + q;
      float eL = __expf(Lam_t[i][q]);
      int jrow = j0 + t * dj;
#pragma unroll
      for (int djt = 0; djt < 2; djt++) {
        int R = r * 32 + djt * 16 + lrow;
        float xv = bf2f(XT[R][xts(R, t)]);
        float val = y[i][djt][q] + eL * yi[i][djt][q] + Dv[djt] * xv;
        yb[(size_t)jrow * DI + R] = f2bf(val);
      }
    }
  }
}

// ---------------- Kernel 7a: merge + LN + gelu + *silu(z) -> bf16 su ----------
__global__ __launch_bounds__(192) void k_ln(const unsigned short* __restrict__ ybh,
                                            const float* __restrict__ zs,
                                            const float* __restrict__ ln_g,
                                            const float* __restrict__ ln_b,
                                            unsigned short* __restrict__ sub) {
  const int PP = 4;
  int pos0 = blockIdx.x * PP;
  int b = pos0 / LT, p0 = pos0 % LT;
  int h0 = p0 / HW, w0 = p0 % HW;
  int pt0 = w0 * HW + h0;
  int tid = threadIdx.x;
  float v[PP], s1[PP], s2[PP];
#pragma unroll
  for (int q = 0; q < PP; q++) {
    int p = p0 + q;
    int pt = pt0 + q * HW;
    float acc = bf2f(ybh[((size_t)(0 * NB + b) * LT + p) * DI + tid])
              + bf2f(ybh[((size_t)(1 * NB + b) * LT + pt) * DI + tid])
              + bf2f(ybh[((size_t)(2 * NB + b) * LT + p) * DI + tid])
              + bf2f(ybh[((size_t)(3 * NB + b) * LT + pt) * DI + tid]);
    v[q] = acc; s1[q] = acc; s2[q] = acc * acc;
  }
#pragma unroll
  for (int off = 32; off; off >>= 1) {
#pragma unroll
    for (int q = 0; q < PP; q++) {
      s1[q] += __shfl_down(s1[q], off, 64);
      s2[q] += __shfl_down(s2[q], off, 64);
    }
  }
  __shared__ float rs1[3][PP], rs2[3][PP];
  int wave = tid >> 6, lane = tid & 63;
  if (lane == 0) {
#pragma unroll
    for (int q = 0; q < PP; q++) { rs1[wave][q] = s1[q]; rs2[wave][q] = s2[q]; }
  }
  __syncthreads();
  float g = ln_g[tid], be = ln_b[tid];
#pragma unroll
  for (int q = 0; q < PP; q++) {
    float mean = (rs1[0][q] + rs1[1][q] + rs1[2][q]) * (1.f / 192.f);
    float var = (rs2[0][q] + rs2[1][q] + rs2[2][q]) * (1.f / 192.f) - mean * mean;
    float rstd = rsqrtf(var + 1e-5f);
    float t = (v[q] - mean) * rstd * g + be;
    float ge = 0.5f * t * (1.f + erff(t * 0.70710678118f));
    sub[(size_t)(pos0 + q) * DI + tid] = f2bf(ge * zs[(size_t)(pos0 + q) * DI + tid]);
  }
}

// ---------------- Kernel 7b: out_proj via bf16 MFMA ----------------
__global__ __launch_bounds__(256) void k_oproj(const unsigned short* __restrict__ sub,
                                               const unsigned short* __restrict__ Wob,
                                               float* __restrict__ out) {
  int wid = threadIdx.x >> 6;
  int lane = threadIdx.x & 63;
  int pos0 = blockIdx.x * 64 + wid * 16;
  int lrow = lane & 15;
  int lgrp = lane >> 4;
  bf16x8 a[6];
  const unsigned short* arow = sub + (size_t)(pos0 + lrow) * DI + lgrp * 8;
#pragma unroll
  for (int ks = 0; ks < 6; ks++)
    a[ks] = *reinterpret_cast<const bf16x8*>(arow + ks * 32);
  f32x4 acc[6];
#pragma unroll
  for (int t = 0; t < 6; t++) acc[t] = (f32x4){0.f, 0.f, 0.f, 0.f};
  const unsigned short* brow = Wob + (size_t)lrow * DI + lgrp * 8;
#pragma unroll
  for (int ks = 0; ks < 6; ks++) {
#pragma unroll
    for (int ot = 0; ot < 6; ot++) {
      bf16x8 bf = *reinterpret_cast<const bf16x8*>(brow + (size_t)ot * 16 * DI + ks * 32);
      acc[ot] = __builtin_amdgcn_mfma_f32_16x16x32_bf16(a[ks], bf, acc[ot], 0, 0, 0);
    }
  }
#pragma unroll
  for (int ot = 0; ot < 6; ot++) {
    int o = ot * 16 + lrow;
#pragma unroll
    for (int r = 0; r < 4; r++) {
      int pos = pos0 + lgrp * 4 + r;
      out[(size_t)pos * DM + o] = acc[ot][r];
    }
  }
}

extern "C" void kernel_launch(void* const* d_in, const int* in_sizes, int n_in,
                              void* d_out, int out_size, void* d_ws, size_t ws_size,
                              hipStream_t stream) {
  const float* x       = (const float*)d_in[0];
  const float* Wi      = (const float*)d_in[1];
  const float* cw      = (const float*)d_in[2];
  const float* cb      = (const float*)d_in[3];
  const float* Wp      = (const float*)d_in[4];
  const float* Ds      = (const float*)d_in[5];
  const float* A_logs  = (const float*)d_in[6];
  const float* dt_bias = (const float*)d_in[7];
  const float* ln_g    = (const float*)d_in[8];
  const float* ln_b    = (const float*)d_in[9];
  const float* Wo      = (const float*)d_in[10];
  float* out = (float*)d_out;

  float* ws = (float*)d_ws;
  float* xi    = ws;                         // NPOS*DI f32
  float* zs    = xi + (size_t)NPOS * DI;     // NPOS*DI f32
  float* dtS   = zs + (size_t)NPOS * DI;     // KD*NB*LT*RK f32 (direction-ordered)
  float* Pend  = dtS + (size_t)NPOS * KD * RK;      // SEQ*NC*RK f32
  float* WpbF  = Pend + (size_t)SEQ * NC * RK;
  float* WibF  = WpbF + (size_t)NOP * DI / 2;
  float* WobF  = WibF + (size_t)NI * DM / 2;
  unsigned short* BsH  = (unsigned short*)(WobF + (size_t)DM * DI / 2); // KD*NPOS*NS bf16
  unsigned short* CsH  = BsH + (size_t)NPOS * KD * NS;
  unsigned short* xcb  = CsH + (size_t)NPOS * KD * NS;   // NPOS*DI bf16
  unsigned short* xcbT = xcb + (size_t)NPOS * DI;
  unsigned short* ybh  = xcbT + (size_t)NPOS * DI;        // KD*NPOS*DI bf16
  unsigned short* Send = ybh + (size_t)NPOS * KD * DI;    // SEQ*NC*ELEM bf16
  unsigned short* sub  = Send + (size_t)SEQ * NC * ELEM;  // NPOS*DI bf16
  unsigned short* Wpb = (unsigned short*)WpbF;
  unsigned short* Wib = (unsigned short*)WibF;
  unsigned short* Wob = (unsigned short*)WobF;

  k_wiprep<<<(NI * DM + 255) / 256, 256, 0, stream>>>(Wi, Wib);
  k_wprep<<<(NOP * DI + 255) / 256, 256, 0, stream>>>(Wp, Wpb);
  k_wob<<<(DM * DI + 255) / 256, 256, 0, stream>>>(Wo, Wob);
  k_inproj<<<NPOS / 64, 256, 0, stream>>>(x, Wib, xi, zs);
  k_conv<<<(NPOS * (DI / 2) + 255) / 256, 256, 0, stream>>>(xi, cw, cb, xcb, xcbT);
  k_xproj<<<NPOS / 16, 256, 0, stream>>>(xcb, Wpb, dt_bias, dtS, BsH, CsH);
  k_scanAm<<<SEQ * NC, 384, 0, stream>>>(xcb, xcbT, dtS, BsH, A_logs, Send, Pend);
  k_scanB<<<SEQ * (ELEM / 512), 256, 0, stream>>>((unsigned int*)Send, Pend);
  k_scanM<<<SEQ * NC, 384, 0, stream>>>(xcb, xcbT, dtS, BsH, CsH, A_logs, Ds, Send, ybh);
  k_ln<<<NPOS / 4, 192, 0, stream>>>(ybh, zs, ln_g, ln_b, sub);
  k_oproj<<<NPOS / 64, 256, 0, stream>>>(sub, Wob, out);
}

// Round 18
// 161.769 us; speedup vs baseline: 1.8176x; 1.0900x over previous
//
#include <hip/hip_runtime.h>

// VMamba mixer forward, MI355X. bf16-MFMA in_proj / x_proj / chunk-scan /
// fused LN+out_proj; bf16 streams throughout; XOR-swizzled XT staging.
// R17: fix k_lnop zs indexing (global position, was batch-relative).

constexpr int DM   = 96;     // D_MODEL
constexpr int DI   = 192;    // D_INNER
constexpr int RK   = 6;      // DT_RANK
constexpr int NS   = 32;     // D_STATE (== HEAD_D)
constexpr int KD   = 4;      // directions
constexpr int HW   = 56;
constexpr int LT   = 3136;   // L = 56*56
constexpr int NB   = 8;      // batch
constexpr int NPOS = NB * LT;   // 25088
constexpr int NC   = 49;     // chunks per sequence
constexpr int CH   = 64;     // chunk length (49*64 = 3136)
constexpr int SEQ = NB * KD; // 32 sequences
constexpr int ELEM = RK * NS * NS;  // 6144 state elements per sequence
constexpr int NO   = 280;    // x_proj outputs (4*70)
constexpr int NOP  = 288;    // padded to 18 MFMA n-tiles
constexpr int NI   = 384;    // in_proj outputs (2*DI)

typedef __attribute__((ext_vector_type(8))) __bf16 bf16x8;
typedef __attribute__((ext_vector_type(4))) float f32x4;
typedef __attribute__((ext_vector_type(2))) float f32x2;

__device__ __forceinline__ float siluf(float x) { return x / (1.f + __expf(-x)); }

__device__ __forceinline__ unsigned short f2bf(float f) {  // RNE, finite inputs
  unsigned int u = __float_as_uint(f);
  u = (u + 0x7fffu + ((u >> 16) & 1u)) >> 16;
  return (unsigned short)u;
}
__device__ __forceinline__ float bf2f(unsigned short h) {
  return __uint_as_float(((unsigned int)h) << 16);
}
__device__ __forceinline__ unsigned int pack2(float a, float b) {
  return (unsigned int)f2bf(a) | ((unsigned int)f2bf(b) << 16);
}
// XOR-swizzled XT column: row c, stream-step s. 16B-block granularity.
__device__ __forceinline__ int xts(int c, int s) {
  return (s & 7) + 8 * ((s >> 3) ^ ((c >> 1) & 7));
}
__device__ __forceinline__ int xtsb(int c, int sblk) {  // 8-short block index
  return (sblk ^ ((c >> 1) & 7)) * 8;
}

// ---------------- Kernel 0: all weight preps (Wi, Wp, Wo -> bf16) ----------
__global__ __launch_bounds__(256) void k_prep(const float* __restrict__ Wi,
                                              const float* __restrict__ Wp,
                                              const float* __restrict__ Wo,
                                              unsigned short* __restrict__ Wib,
                                              unsigned short* __restrict__ Wpb,
                                              unsigned short* __restrict__ Wob) {
  int t = blockIdx.x * 256 + threadIdx.x;
  if (t < NI * DM) { Wib[t] = f2bf(Wi[t]); return; }
  int t2 = t - NI * DM;
  if (t2 < NOP * DI) {
    int o = t2 / DI;
    Wpb[t2] = (o < NO) ? f2bf(Wp[t2]) : (unsigned short)0;
    return;
  }
  int t3 = t2 - NOP * DI;
  if (t3 < DM * DI) Wob[t3] = f2bf(Wo[t3]);
}

// ---------------- Kernel 1: in_proj via bf16 MFMA -> bf16 xi, bf16 silu(z) ----
__global__ __launch_bounds__(256) void k_inproj(const float* __restrict__ x,
                                                const unsigned short* __restrict__ Wib,
                                                unsigned short* __restrict__ xi,
                                                unsigned short* __restrict__ zs) {
  int wid = threadIdx.x >> 6;
  int lane = threadIdx.x & 63;
  int pos0 = blockIdx.x * 64 + wid * 16;
  int lrow = lane & 15;
  int lgrp = lane >> 4;
  bf16x8 a[3];
  const float* arow = x + (size_t)(pos0 + lrow) * DM + lgrp * 8;
#pragma unroll
  for (int ks = 0; ks < 3; ks++) {
    f32x4 v0 = *reinterpret_cast<const f32x4*>(arow + ks * 32);
    f32x4 v1 = *reinterpret_cast<const f32x4*>(arow + ks * 32 + 4);
    union { unsigned short us[8]; bf16x8 v; } tmp;
#pragma unroll
    for (int j = 0; j < 4; j++) { tmp.us[j] = f2bf(v0[j]); tmp.us[4 + j] = f2bf(v1[j]); }
    a[ks] = tmp.v;
  }
  f32x4 acc[24];
#pragma unroll
  for (int t = 0; t < 24; t++) acc[t] = (f32x4){0.f, 0.f, 0.f, 0.f};
  const unsigned short* brow = Wib + (size_t)lrow * DM + lgrp * 8;
#pragma unroll
  for (int ks = 0; ks < 3; ks++) {
#pragma unroll
    for (int ot = 0; ot < 24; ot++) {
      bf16x8 bf = *reinterpret_cast<const bf16x8*>(brow + (size_t)ot * 16 * DM + ks * 32);
      acc[ot] = __builtin_amdgcn_mfma_f32_16x16x32_bf16(a[ks], bf, acc[ot], 0, 0, 0);
    }
  }
#pragma unroll
  for (int ot = 0; ot < 24; ot++) {
    int o = ot * 16 + lrow;
#pragma unroll
    for (int r = 0; r < 4; r++) {
      int pos = pos0 + lgrp * 4 + r;
      float v = acc[ot][r];
      if (o < DI) xi[(size_t)pos * DI + o] = f2bf(v);
      else        zs[(size_t)pos * DI + (o - DI)] = f2bf(siluf(v));
    }
  }
}

// ---------------- Kernel 2: depthwise conv (bf16 in) -> bf16 (rm + transposed) --
__global__ __launch_bounds__(256) void k_conv(const unsigned short* __restrict__ xi,
                                              const float* __restrict__ cw,
                                              const float* __restrict__ cb,
                                              unsigned short* __restrict__ xcb,
                                              unsigned short* __restrict__ xcbT) {
  const int DH = DI / 2;
  int t = blockIdx.x * 256 + threadIdx.x;
  if (t >= NPOS * DH) return;
  int c2 = t % DH;
  int pos = t / DH;
  int p = pos % LT, b = pos / LT;
  int h = p / HW, w = p % HW;
  f32x2 acc = *reinterpret_cast<const f32x2*>(cb + c2 * 2);
  const unsigned int* x32 = reinterpret_cast<const unsigned int*>(xi);
  int base = b * LT * DH + c2;
#pragma unroll
  for (int dh = 0; dh < 3; dh++) {
    int hh = h + dh - 1;
    if (hh < 0 || hh >= HW) continue;
#pragma unroll
    for (int dw = 0; dw < 3; dw++) {
      int ww = w + dw - 1;
      if (ww < 0 || ww >= HW) continue;
      f32x2 wv = *reinterpret_cast<const f32x2*>(cw + (dh * 3 + dw) * DI + c2 * 2);
      unsigned int u = x32[base + (hh * HW + ww) * DH];
      f32x2 xv = {bf2f((unsigned short)(u & 0xffff)), bf2f((unsigned short)(u >> 16))};
      acc += wv * xv;
    }
  }
  unsigned int v = pack2(siluf(acc[0]), siluf(acc[1]));
  reinterpret_cast<unsigned int*>(xcb)[t] = v;
  int pt = w * HW + h;
  reinterpret_cast<unsigned int*>(xcbT)[(b * LT + pt) * DH + c2] = v;
}

// ---------------- Kernel 3: x_proj, K-split 4-wave MFMA, LDS out-tile --------
__global__ __launch_bounds__(256) void k_xproj(const unsigned short* __restrict__ xcb,
                                               const unsigned short* __restrict__ Wpb,
                                               const float* __restrict__ dt_bias,
                                               float* __restrict__ dtS,
                                               unsigned short* __restrict__ BsH,
                                               unsigned short* __restrict__ CsH) {
  __shared__ float outT[NOP][17];  // [output o][position]
  int tid = threadIdx.x;
  int wid = tid >> 6;
  int lane = tid & 63;
  int oh = wid >> 1, kh = wid & 1;
  int pos0 = blockIdx.x * 16;
  int lrow = lane & 15;
  int lgrp = lane >> 4;
  bf16x8 a[3];
  const unsigned short* arow = xcb + (size_t)(pos0 + lrow) * DI + kh * 96 + lgrp * 8;
#pragma unroll
  for (int ks = 0; ks < 3; ks++)
    a[ks] = *reinterpret_cast<const bf16x8*>(arow + ks * 32);
  f32x4 acc[9];
#pragma unroll
  for (int t = 0; t < 9; t++) acc[t] = (f32x4){0.f, 0.f, 0.f, 0.f};
  const unsigned short* brow = Wpb + (size_t)(oh * 144 + lrow) * DI + kh * 96 + lgrp * 8;
#pragma unroll
  for (int ks = 0; ks < 3; ks++) {
#pragma unroll
    for (int ot = 0; ot < 9; ot++) {
      bf16x8 bf = *reinterpret_cast<const bf16x8*>(brow + (size_t)ot * 16 * DI + ks * 32);
      acc[ot] = __builtin_amdgcn_mfma_f32_16x16x32_bf16(a[ks], bf, acc[ot], 0, 0, 0);
    }
  }
  if (kh == 1) {
#pragma unroll
    for (int ot = 0; ot < 9; ot++)
#pragma unroll
      for (int q = 0; q < 4; q++)
        outT[oh * 144 + ot * 16 + lrow][lgrp * 4 + q] = acc[ot][q];
  }
  __syncthreads();
  if (kh == 0) {
#pragma unroll
    for (int ot = 0; ot < 9; ot++)
#pragma unroll
      for (int q = 0; q < 4; q++) {
        int o = oh * 144 + ot * 16 + lrow;
        outT[o][lgrp * 4 + q] += acc[ot][q];
      }
  }
  __syncthreads();
  int b = pos0 / LT;
  int p0 = pos0 - b * LT;
  int posl = tid >> 4, cu = tid & 15;
  int p = p0 + posl;
  int h = p / HW, w2 = p - h * HW;
  int pt = w2 * HW + h;
#pragma unroll
  for (int k = 0; k < KD; k++) {
    int sidx = (k * NB + b) * LT + ((k & 1) ? pt : p);
    int rowB = k * 70 + RK;
    int rowC = k * 70 + RK + NS;
    unsigned int vb = pack2(outT[rowB + 2 * cu][posl], outT[rowB + 2 * cu + 1][posl]);
    reinterpret_cast<unsigned int*>(BsH)[(size_t)sidx * 16 + cu] = vb;
    unsigned int vc = pack2(outT[rowC + 2 * cu][posl], outT[rowC + 2 * cu + 1][posl]);
    reinterpret_cast<unsigned int*>(CsH)[(size_t)sidx * 16 + cu] = vc;
  }
#pragma unroll
  for (int i = 0; i < 2; i++) {
    int idx = i * 256 + tid;
    if (idx < 16 * KD * RK) {
      int pp = idx / (KD * RK), rem = idx % (KD * RK);
      int k = rem / RK, c = rem % RK;
      int pg = p0 + pp;
      int hh = pg / HW, ww = pg - hh * HW;
      int ptg = ww * HW + hh;
      int sidx = (k * NB + b) * LT + ((k & 1) ? ptg : pg);
      float v = outT[k * 70 + c][pp] + dt_bias[k * RK + c];
      float dtv = (v > 20.f) ? v : log1pf(__expf(v));
      dtS[(size_t)sidx * RK + c] = dtv;
    }
  }
}

// ---------------- Kernel 4: MFMA states pass (S_end = X'.WB per chunk) --------
__global__ __launch_bounds__(384) void k_scanAm(const unsigned short* __restrict__ xcb,
                                                const unsigned short* __restrict__ xcbT,
                                                const float* __restrict__ dtS,
                                                const unsigned short* __restrict__ BsH,
                                                const float* __restrict__ A_logs,
                                                unsigned short* __restrict__ Send,
                                                float* __restrict__ Pend) {
  __shared__ unsigned short XT[DI][64];
  __shared__ unsigned short WB[6][32][72];
  int bi = blockIdx.x;
  int chunk = bi % NC;
  int k = (bi / NC) & 3;
  int b = bi / (NC * KD);
  int seq = b * KD + k;
  int tid = threadIdx.x;
  int wid = tid >> 6;
  int lane = tid & 63;
  int lrow = lane & 15, lgrp = lane >> 4;
  int sb0 = (k * NB + b) * LT;
  int j0 = (k < 2) ? chunk * CH : (LT - 1 - chunk * CH);
  int dj = (k < 2) ? 1 : -1;
  const unsigned int* xs32 = reinterpret_cast<const unsigned int*>(
      ((k & 1) ? xcbT : xcb) + (size_t)b * LT * DI);
#pragma unroll
  for (int it = 0; it < 16; ++it) {
    int idx = it * 384 + tid;
    int s = idx / 96, cu = idx - s * 96;
    unsigned int v = xs32[(size_t)(j0 + s * dj) * 96 + cu];
    int col = xts(2 * cu, s);
    XT[2 * cu][col] = (unsigned short)(v & 0xffff);
    XT[2 * cu + 1][col] = (unsigned short)(v >> 16);
  }
  int r = wid;
  float Ar = -__expf(A_logs[k * RK + r]);
  float dt_l = dtS[(size_t)(sb0 + j0 + lane * dj) * RK + r];
  float Lam = dt_l * Ar;
#pragma unroll
  for (int off = 1; off < 64; off <<= 1) {
    float tv = __shfl_up(Lam, off, 64);
    Lam += (lane >= off) ? tv : 0.f;
  }
  float Lam63 = __shfl(Lam, 63, 64);
  float w = __expf(Lam63 - Lam) * dt_l;
  const unsigned int* brow32 = reinterpret_cast<const unsigned int*>(
      BsH + (size_t)(sb0 + j0 + lane * dj) * NS);
#pragma unroll
  for (int i = 0; i < 16; i++) {
    unsigned int v = brow32[i];
    WB[wid][2 * i][lane]     = f2bf(w * bf2f((unsigned short)(v & 0xffff)));
    WB[wid][2 * i + 1][lane] = f2bf(w * bf2f((unsigned short)(v >> 16)));
  }
  __syncthreads();
  f32x4 acc[2][2];
#pragma unroll
  for (int i = 0; i < 2; i++)
#pragma unroll
    for (int j = 0; j < 2; j++) acc[i][j] = (f32x4){0.f, 0.f, 0.f, 0.f};
#pragma unroll
  for (int ks = 0; ks < 2; ks++) {
#pragma unroll
    for (int dtile = 0; dtile < 2; dtile++) {
      int R = r * 32 + dtile * 16 + lrow;
      bf16x8 av = *reinterpret_cast<const bf16x8*>(&XT[R][xtsb(R, ks * 4 + lgrp)]);
#pragma unroll
      for (int ntile = 0; ntile < 2; ntile++) {
        bf16x8 bv = *reinterpret_cast<const bf16x8*>(&WB[wid][ntile * 16 + lrow][ks * 32 + lgrp * 8]);
        acc[dtile][ntile] = __builtin_amdgcn_mfma_f32_16x16x32_bf16(av, bv, acc[dtile][ntile], 0, 0, 0);
      }
    }
  }
#pragma unroll
  for (int dtile = 0; dtile < 2; dtile++)
#pragma unroll
    for (int ntile = 0; ntile < 2; ntile++)
#pragma unroll
      for (int q = 0; q < 4; q++)
        WB[wid][dtile * 16 + lgrp * 4 + q][ntile * 16 + lrow] = f2bf(acc[dtile][ntile][q]);
  if (lane == 0) Pend[(seq * NC + chunk) * RK + r] = __expf(Lam63);
  __syncthreads();
  unsigned int* dst = reinterpret_cast<unsigned int*>(Send + (size_t)(seq * NC + chunk) * ELEM);
  int e0 = tid * 16;
  int rr = e0 >> 10, dd = (e0 >> 5) & 31, nn = e0 & 31;
  const unsigned int* src = reinterpret_cast<const unsigned int*>(&WB[rr][dd][nn]);
#pragma unroll
  for (int i = 0; i < 8; i++) dst[tid * 8 + i] = src[i];
}

// ---------------- Kernel 5: chunk-state combine (bf16 in-place excl. prefix) ----
__global__ __launch_bounds__(256) void k_scanB(unsigned int* __restrict__ Send32,
                                               const float* __restrict__ Pend) {
  const int EU = ELEM / 2;
  int bi = blockIdx.x;
  int seq = bi / (EU / 256);
  int u = (bi % (EU / 256)) * 256 + threadIdx.x;
  int r = u >> 9;
  float run0 = 0.f, run1 = 0.f;
  for (int c = 0; c < NC; c++) {
    size_t idx = (size_t)(seq * NC + c) * EU + u;
    unsigned int v = Send32[idx];
    float t0 = bf2f((unsigned short)(v & 0xffff));
    float t1 = bf2f((unsigned short)(v >> 16));
    Send32[idx] = pack2(run0, run1);
    float pe = Pend[(seq * NC + c) * RK + r];
    run0 = run0 * pe + t0;
    run1 = run1 * pe + t1;
  }
}

// ---------------- Kernel 6: MFMA chunk scan (Y = G'X + e^Λ C·Sinit + D·x) -----
__global__ __launch_bounds__(384) void k_scanM(const unsigned short* __restrict__ xcb,
                                               const unsigned short* __restrict__ xcbT,
                                               const float* __restrict__ dtS,
                                               const unsigned short* __restrict__ BsH,
                                               const unsigned short* __restrict__ CsH,
                                               const float* __restrict__ A_logs,
                                               const float* __restrict__ Ds,
                                               const unsigned short* __restrict__ Sinit,
                                               unsigned short* __restrict__ ybh) {
  __shared__ unsigned short XT[DI][64];
  __shared__ unsigned short GB[6][32][72];
  int bi = blockIdx.x;
  int chunk = bi % NC;
  int k = (bi / NC) & 3;
  int b = bi / (NC * KD);
  int tid = threadIdx.x;
  int wid = tid >> 6;
  int lane = tid & 63;
  int lrow = lane & 15, lgrp = lane >> 4;
  int sb0 = (k * NB + b) * LT;
  int j0 = (k < 2) ? chunk * CH : (LT - 1 - chunk * CH);
  int dj = (k < 2) ? 1 : -1;
  const unsigned int* xs32 = reinterpret_cast<const unsigned int*>(
      ((k & 1) ? xcbT : xcb) + (size_t)b * LT * DI);
#pragma unroll
  for (int it = 0; it < 16; ++it) {
    int idx = it * 384 + tid;
    int s = idx / 96, cu = idx - s * 96;
    unsigned int v = xs32[(size_t)(j0 + s * dj) * 96 + cu];
    int col = xts(2 * cu, s);
    XT[2 * cu][col] = (unsigned short)(v & 0xffff);
    XT[2 * cu + 1][col] = (unsigned short)(v >> 16);
  }
  __syncthreads();
  int r = wid;
  float Ar = -__expf(A_logs[k * RK + r]);
  float dt_l = dtS[(size_t)(sb0 + j0 + lane * dj) * RK + r];
  float Lam = dt_l * Ar;
#pragma unroll
  for (int off = 1; off < 64; off <<= 1) {
    float tv = __shfl_up(Lam, off, 64);
    Lam += (lane >= off) ? tv : 0.f;
  }
  bf16x8 ct[4], bt[4];
#pragma unroll
  for (int i = 0; i < 4; i++) {
    int row = j0 + (i * 16 + lrow) * dj;
    ct[i] = *reinterpret_cast<const bf16x8*>(CsH + (size_t)(sb0 + row) * NS + lgrp * 8);
    bt[i] = *reinterpret_cast<const bf16x8*>(BsH + (size_t)(sb0 + row) * NS + lgrp * 8);
  }
  const unsigned short* sbase = Sinit + (size_t)((b * KD + k) * NC + chunk) * ELEM + r * NS * NS;
  bf16x8 sf[2];
#pragma unroll
  for (int djt = 0; djt < 2; djt++)
    sf[djt] = *reinterpret_cast<const bf16x8*>(sbase + (djt * 16 + lrow) * NS + lgrp * 8);
  f32x4 yi[4][2];
#pragma unroll
  for (int i = 0; i < 4; i++)
#pragma unroll
    for (int djt = 0; djt < 2; djt++)
      yi[i][djt] = __builtin_amdgcn_mfma_f32_16x16x32_bf16(ct[i], sf[djt],
                       (f32x4){0.f, 0.f, 0.f, 0.f}, 0, 0, 0);
  float dt_s4[4], Lam_s4[4];
#pragma unroll
  for (int j = 0; j < 4; j++) {
    dt_s4[j] = __shfl(dt_l, j * 16 + lrow, 64);
    Lam_s4[j] = __shfl(Lam, j * 16 + lrow, 64);
  }
  float Lam_t[4][4];
#pragma unroll
  for (int i = 0; i < 4; i++)
#pragma unroll
    for (int q = 0; q < 4; q++)
      Lam_t[i][q] = __shfl(Lam, i * 16 + lgrp * 4 + q, 64);
  f32x4 y[4][2];
#pragma unroll
  for (int i = 0; i < 4; i++)
#pragma unroll
    for (int djt = 0; djt < 2; djt++) y[i][djt] = (f32x4){0.f, 0.f, 0.f, 0.f};
#pragma unroll
  for (int h = 0; h < 2; h++) {
    int i0 = h * 2;
    int ncol = h ? 4 : 2;
#pragma unroll
    for (int it = 0; it < 2; it++) {
      int i = i0 + it;
#pragma unroll
      for (int j = 0; j < 4; j++) {
        if (j >= ncol) continue;
        f32x4 g = __builtin_amdgcn_mfma_f32_16x16x32_bf16(ct[i], bt[j],
                      (f32x4){0.f, 0.f, 0.f, 0.f}, 0, 0, 0);
        int s = j * 16 + lrow;
#pragma unroll
        for (int q = 0; q < 4; q++) {
          int t = i * 16 + lgrp * 4 + q;
          float wgt = (t >= s) ? __expf(Lam_t[i][q] - Lam_s4[j]) * dt_s4[j] : 0.f;
          GB[wid][it * 16 + lgrp * 4 + q][s] = f2bf(g[q] * wgt);
        }
      }
    }
    int nks = h ? 2 : 1;
#pragma unroll
    for (int it = 0; it < 2; it++) {
#pragma unroll
      for (int ks = 0; ks < nks; ks++) {
        bf16x8 ga = *reinterpret_cast<const bf16x8*>(&GB[wid][it * 16 + lrow][ks * 32 + lgrp * 8]);
#pragma unroll
        for (int djt = 0; djt < 2; djt++) {
          int R = r * 32 + djt * 16 + lrow;
          bf16x8 xb = *reinterpret_cast<const bf16x8*>(&XT[R][xtsb(R, ks * 4 + lgrp)]);
          y[i0 + it][djt] = __builtin_amdgcn_mfma_f32_16x16x32_bf16(ga, xb, y[i0 + it][djt], 0, 0, 0);
        }
      }
    }
  }
  float Dv[2];
#pragma unroll
  for (int djt = 0; djt < 2; djt++)
    Dv[djt] = Ds[(k * RK + r) * NS + djt * 16 + lrow];
  unsigned short* yb = ybh + (size_t)(k * NB + b) * LT * DI;
#pragma unroll
  for (int i = 0; i < 4; i++) {
#pragma unroll
    for (int q = 0; q < 4; q++) {
      int t = i * 16 + lgrp * 4 + q;
      float eL = __expf(Lam_t[i][q]);
      int jrow = j0 + t * dj;
#pragma unroll
      for (int djt = 0; djt < 2; djt++) {
        int R = r * 32 + djt * 16 + lrow;
        float xv = bf2f(XT[R][xts(R, t)]);
        float val = y[i][djt][q] + eL * yi[i][djt][q] + Dv[djt] * xv;
        yb[(size_t)jrow * DI + R] = f2bf(val);
      }
    }
  }
}

// ---------------- Kernel 7: fused merge+LN+gelu+*silu(z) + out_proj MFMA ------
__global__ __launch_bounds__(256) void k_lnop(const unsigned short* __restrict__ ybh,
                                              const unsigned short* __restrict__ zs,
                                              const float* __restrict__ ln_g,
                                              const float* __restrict__ ln_b,
                                              const unsigned short* __restrict__ Wob,
                                              float* __restrict__ out) {
  __shared__ unsigned short su[32][200];   // [pos local][channel]
  __shared__ float red[2][6][64][4];
  int tid = threadIdx.x;
  int wid = tid >> 6;
  int lane = tid & 63;
  int pos0 = blockIdx.x * 32;
  int b = pos0 / LT, p0 = pos0 % LT;
  float g[3], be[3];
#pragma unroll
  for (int j = 0; j < 3; j++) { g[j] = ln_g[lane + 64 * j]; be[j] = ln_b[lane + 64 * j]; }
#pragma unroll
  for (int q = 0; q < 8; q++) {
    int pl = wid * 8 + q;
    int p = p0 + pl;
    int h = p / HW, w2 = p - h * HW;
    int pt = w2 * HW + h;
    float v[3];
#pragma unroll
    for (int j = 0; j < 3; j++) {
      int c = lane + 64 * j;
      v[j] = bf2f(ybh[((size_t)(0 * NB + b) * LT + p) * DI + c])
           + bf2f(ybh[((size_t)(1 * NB + b) * LT + pt) * DI + c])
           + bf2f(ybh[((size_t)(2 * NB + b) * LT + p) * DI + c])
           + bf2f(ybh[((size_t)(3 * NB + b) * LT + pt) * DI + c]);
    }
    float s1 = v[0] + v[1] + v[2];
    float s2 = v[0] * v[0] + v[1] * v[1] + v[2] * v[2];
#pragma unroll
    for (int off = 32; off; off >>= 1) {
      s1 += __shfl_xor(s1, off, 64);
      s2 += __shfl_xor(s2, off, 64);
    }
    float mean = s1 * (1.f / 192.f);
    float var = s2 * (1.f / 192.f) - mean * mean;
    float rstd = rsqrtf(var + 1e-5f);
#pragma unroll
    for (int j = 0; j < 3; j++) {
      int c = lane + 64 * j;
      float t = (v[j] - mean) * rstd * g[j] + be[j];
      float ge = 0.5f * t * (1.f + erff(t * 0.70710678118f));
      su[pl][c] = f2bf(ge * bf2f(zs[((size_t)(b * LT + p)) * DI + c]));  // FIXED: global pos
    }
  }
  __syncthreads();
  int pg = wid >> 1, kh = wid & 1;
  int lrow = lane & 15, lgrp = lane >> 4;
  bf16x8 a[3];
#pragma unroll
  for (int ks = 0; ks < 3; ks++)
    a[ks] = *reinterpret_cast<const bf16x8*>(&su[pg * 16 + lrow][kh * 96 + ks * 32 + lgrp * 8]);
  f32x4 acc[6];
#pragma unroll
  for (int t = 0; t < 6; t++) acc[t] = (f32x4){0.f, 0.f, 0.f, 0.f};
  const unsigned short* brow = Wob + (size_t)lrow * DI + kh * 96 + lgrp * 8;
#pragma unroll
  for (int ks = 0; ks < 3; ks++) {
#pragma unroll
    for (int ot = 0; ot < 6; ot++) {
      bf16x8 bf = *reinterpret_cast<const bf16x8*>(brow + (size_t)ot * 16 * DI + ks * 32);
      acc[ot] = __builtin_amdgcn_mfma_f32_16x16x32_bf16(a[ks], bf, acc[ot], 0, 0, 0);
    }
  }
  if (kh == 1) {
#pragma unroll
    for (int ot = 0; ot < 6; ot++)
#pragma unroll
      for (int q = 0; q < 4; q++) red[pg][ot][lane][q] = acc[ot][q];
  }
  __syncthreads();
  if (kh == 0) {
#pragma unroll
    for (int ot = 0; ot < 6; ot++) {
      int o = ot * 16 + lrow;
#pragma unroll
      for (int q = 0; q < 4; q++) {
        int pos = pos0 + pg * 16 + lgrp * 4 + q;
        out[(size_t)pos * DM + o] = acc[ot][q] + red[pg][ot][lane][q];
      }
    }
  }
}

extern "C" void kernel_launch(void* const* d_in, const int* in_sizes, int n_in,
                              void* d_out, int out_size, void* d_ws, size_t ws_size,
                              hipStream_t stream) {
  const float* x       = (const float*)d_in[0];
  const float* Wi      = (const float*)d_in[1];
  const float* cw      = (const float*)d_in[2];
  const float* cb      = (const float*)d_in[3];
  const float* Wp      = (const float*)d_in[4];
  const float* Ds      = (const float*)d_in[5];
  const float* A_logs  = (const float*)d_in[6];
  const float* dt_bias = (const float*)d_in[7];
  const float* ln_g    = (const float*)d_in[8];
  const float* ln_b    = (const float*)d_in[9];
  const float* Wo      = (const float*)d_in[10];
  float* out = (float*)d_out;

  float* ws = (float*)d_ws;
  float* dtS   = ws;                              // KD*NB*LT*RK f32
  float* Pend  = dtS + (size_t)NPOS * KD * RK;    // SEQ*NC*RK f32
  unsigned short* Wib  = (unsigned short*)(Pend + (size_t)SEQ * NC * RK);
  unsigned short* Wpb  = Wib + (size_t)NI * DM;
  unsigned short* Wob  = Wpb + (size_t)NOP * DI;
  unsigned short* xi   = Wob + (size_t)DM * DI;    // NPOS*DI bf16
  unsigned short* zs   = xi + (size_t)NPOS * DI;   // NPOS*DI bf16
  unsigned short* BsH  = zs + (size_t)NPOS * DI;   // KD*NPOS*NS bf16
  unsigned short* CsH  = BsH + (size_t)NPOS * KD * NS;
  unsigned short* xcb  = CsH + (size_t)NPOS * KD * NS;
  unsigned short* xcbT = xcb + (size_t)NPOS * DI;
  unsigned short* ybh  = xcbT + (size_t)NPOS * DI; // KD*NPOS*DI bf16
  unsigned short* Send = ybh + (size_t)NPOS * KD * DI;

  int preptot = NI * DM + NOP * DI + DM * DI;
  k_prep<<<(preptot + 255) / 256, 256, 0, stream>>>(Wi, Wp, Wo, Wib, Wpb, Wob);
  k_inproj<<<NPOS / 64, 256, 0, stream>>>(x, Wib, xi, zs);
  k_conv<<<(NPOS * (DI / 2) + 255) / 256, 256, 0, stream>>>(xi, cw, cb, xcb, xcbT);
  k_xproj<<<NPOS / 16, 256, 0, stream>>>(xcb, Wpb, dt_bias, dtS, BsH, CsH);
  k_scanAm<<<SEQ * NC, 384, 0, stream>>>(xcb, xcbT, dtS, BsH, A_logs, Send, Pend);
  k_scanB<<<SEQ * (ELEM / 512), 256, 0, stream>>>((unsigned int*)Send, Pend);
  k_scanM<<<SEQ * NC, 384, 0, stream>>>(xcb, xcbT, dtS, BsH, CsH, A_logs, Ds, Send, ybh);
  k_lnop<<<NPOS / 32, 256, 0, stream>>>(ybh, zs, ln_g, ln_b, Wob, out);
}